// Round 4
// 403.976 us; speedup vs baseline: 1.1086x; 1.1086x over previous
//
#include <hip/hip_runtime.h>

typedef short s8v __attribute__((ext_vector_type(8)));
typedef int i2v __attribute__((ext_vector_type(2)));
typedef float f4v __attribute__((ext_vector_type(4)));

typedef const __attribute__((address_space(1))) char* gp1_t;
typedef __attribute__((address_space(3))) char* lp3_t;

__device__ __forceinline__ float bf2f(short s) {
    union { unsigned u; float f; } c;
    c.u = ((unsigned)(unsigned short)s) << 16;
    return c.f;
}
__device__ __forceinline__ short f2bf(float f) {
    union { float f; unsigned u; } c; c.f = f;
    unsigned r = (c.u + 0x7FFFu + ((c.u >> 16) & 1u)) >> 16;
    return (short)r;
}
__device__ __forceinline__ unsigned pk2(float a, float b) {
    return ((unsigned)(unsigned short)f2bf(a)) | (((unsigned)(unsigned short)f2bf(b)) << 16);
}
__device__ __forceinline__ s8v cvt8(const float* __restrict__ p) {
    f4v a = *(const f4v*)p;
    f4v b = *(const f4v*)(p + 4);
    s8v r;
    r[0] = f2bf(a[0]); r[1] = f2bf(a[1]); r[2] = f2bf(a[2]); r[3] = f2bf(a[3]);
    r[4] = f2bf(b[0]); r[5] = f2bf(b[1]); r[6] = f2bf(b[2]); r[7] = f2bf(b[3]);
    return r;
}

// ======================= FAST PATH (ws >= 64 MiB) =======================

// fp32 -> bf16 straight copy (x)
__global__ __launch_bounds__(256) void cvt_x(const float* __restrict__ x,
                                             short* __restrict__ xb) {
    long i = ((long)blockIdx.x * 256 + threadIdx.x) * 8;
    *(s8v*)&xb[i] = cvt8(&x[i]);
}

// W (2048 x N fp32) -> Wt rows [obase+n][k] bf16 (ld 2048)
__global__ __launch_bounds__(256) void cvt_wt(const float* __restrict__ W,
                                              short* __restrict__ Wt,
                                              int N, int obase) {
    __shared__ __align__(16) short tile[64 * 72];
    const int kt = blockIdx.y * 64, n0 = blockIdx.x * 64;
    const int t = threadIdx.x;
    const int r = t >> 4, c4 = (t & 15) * 4;
#pragma unroll
    for (int i = 0; i < 4; i++) {
        int kr = r + i * 16;
        f4v v = *(const f4v*)&W[(long)(kt + kr) * N + n0 + c4];
#pragma unroll
        for (int j = 0; j < 4; j++) tile[(c4 + j) * 72 + kr] = f2bf(v[j]);
    }
    __syncthreads();
    const int nr = t >> 3, kc = (t & 7) * 8;
#pragma unroll
    for (int i = 0; i < 2; i++) {
        int n = nr + i * 32;
        *(s8v*)&Wt[(long)(obase + n0 + n) * 2048 + kt + kc] = *(const s8v*)&tile[n * 72 + kc];
    }
}

// m97-style GEMM: A (M x K bf16, stride lda), Bt (N x K bf16, stride ldb),
// C (M x N, stride ldc; fp32 or bf16). 128x128 tile, BK=32,
// global_load_lds width=16 staging, unpadded LDS tiles.
template <bool CF32>
__global__ __launch_bounds__(256) void gemm_bt(const short* __restrict__ A,
                                               const short* __restrict__ Bt,
                                               void* __restrict__ Cv,
                                               int K, int lda, int ldb, int ldc) {
    __shared__ __align__(16) short As[128 * 32];
    __shared__ __align__(16) short Bs[128 * 32];
    const int tid = threadIdx.x;
    const int lane = tid & 63;
    const int wave = tid >> 6;
    const int quad = lane >> 4;
    const int l15 = lane & 15;
    const int m0 = blockIdx.y * 128;
    const int n0 = blockIdx.x * 128;
    const int wm = (wave & 1) * 64;
    const int wn = (wave >> 1) * 64;

    f4v acc[4][4];
#pragma unroll
    for (int i = 0; i < 4; i++)
#pragma unroll
        for (int j = 0; j < 4; j++) acc[i][j] = (f4v){0.f, 0.f, 0.f, 0.f};

    const int s0 = wave * 64 + lane, s1 = (4 + wave) * 64 + lane;
    const short* a0 = A + (long)(m0 + (s0 >> 2)) * lda + (s0 & 3) * 8;
    const short* a1 = A + (long)(m0 + (s1 >> 2)) * lda + (s1 & 3) * 8;
    const short* b0 = Bt + (long)(n0 + (s0 >> 2)) * ldb + (s0 & 3) * 8;
    const short* b1 = Bt + (long)(n0 + (s1 >> 2)) * ldb + (s1 & 3) * 8;
    char* lA0 = (char*)As + wave * 1024;
    char* lA1 = (char*)As + (4 + wave) * 1024;
    char* lB0 = (char*)Bs + wave * 1024;
    char* lB1 = (char*)Bs + (4 + wave) * 1024;

    for (int k0 = 0; k0 < K; k0 += 32) {
        __syncthreads();
        __builtin_amdgcn_global_load_lds((gp1_t)(a0 + k0), (lp3_t)lA0, 16, 0, 0);
        __builtin_amdgcn_global_load_lds((gp1_t)(a1 + k0), (lp3_t)lA1, 16, 0, 0);
        __builtin_amdgcn_global_load_lds((gp1_t)(b0 + k0), (lp3_t)lB0, 16, 0, 0);
        __builtin_amdgcn_global_load_lds((gp1_t)(b1 + k0), (lp3_t)lB1, 16, 0, 0);
        __syncthreads();
        s8v af[4], bfr[4];
#pragma unroll
        for (int mi = 0; mi < 4; mi++)
            af[mi] = *(const s8v*)(&As[(wm + mi * 16 + l15) * 32 + quad * 8]);
#pragma unroll
        for (int ni = 0; ni < 4; ni++)
            bfr[ni] = *(const s8v*)(&Bs[(wn + ni * 16 + l15) * 32 + quad * 8]);
#pragma unroll
        for (int mi = 0; mi < 4; mi++)
#pragma unroll
            for (int ni = 0; ni < 4; ni++)
                acc[mi][ni] = __builtin_amdgcn_mfma_f32_16x16x32_bf16(af[mi], bfr[ni], acc[mi][ni], 0, 0, 0);
    }
#pragma unroll
    for (int mi = 0; mi < 4; mi++)
#pragma unroll
        for (int ni = 0; ni < 4; ni++)
#pragma unroll
            for (int r = 0; r < 4; r++) {
                int row = m0 + wm + mi * 16 + quad * 4 + r;
                int col = n0 + wn + ni * 16 + l15;
                if (CF32) ((float*)Cv)[(long)row * ldc + col] = acc[mi][ni][r];
                else      ((short*)Cv)[(long)row * ldc + col] = f2bf(acc[mi][ni][r]);
            }
}

// RoPE in-place on qkv cols [0,2560)
__global__ __launch_bounds__(256) void rope_kernel(short* __restrict__ qkv) {
    int tid = blockIdx.x * 256 + threadIdx.x;
    int p = tid % 1280;
    int row = tid / 1280;
    int head = p >> 5;
    int j = p & 31;
    int s = row & 2047;
    int c1 = head * 64 + j;
    float freq = exp2f(-(float)j * 0.4152410118609203f); // log2(10000)/32
    float ang = (float)s * freq;
    float sn, cs;
    __sincosf(ang, &sn, &cs);
    long base = (long)row * 3072;
    float x1 = bf2f(qkv[base + c1]);
    float x2 = bf2f(qkv[base + c1 + 32]);
    qkv[base + c1]      = f2bf(x1 * cs - x2 * sn);
    qkv[base + c1 + 32] = f2bf(x2 * cs + x1 * sn);
}

// V transpose (round-0 verified): qkv v-region -> Vt_g[(b*8+kvh)*64 + d][key] (ld 2048)
__global__ __launch_bounds__(256) void vtrans(const short* __restrict__ qkv,
                                              short* __restrict__ Vt_g) {
    __shared__ __align__(16) short tile[64 * 72];
    const int kt = blockIdx.x * 64;
    const int kvh = blockIdx.y;
    const int b = blockIdx.z;
    const int t = threadIdx.x;
#pragma unroll
    for (int cc = 0; cc < 2; cc++) {
        int ch = t + cc * 256;
        int key = ch >> 3, d0 = (ch & 7) * 8;
        s8v v = *(const s8v*)&qkv[(long)(b * 2048 + kt + key) * 3072 + 2560 + kvh * 64 + d0];
#pragma unroll
        for (int i = 0; i < 8; i++) tile[(d0 + i) * 72 + key] = v[i];
    }
    __syncthreads();
#pragma unroll
    for (int cc = 0; cc < 2; cc++) {
        int ch = t + cc * 256;
        int d = ch >> 3, kc = (ch & 7) * 8;
        *(s8v*)&Vt_g[(long)((b * 8 + kvh) * 64 + d) * 2048 + kt + kc] = *(const s8v*)&tile[d * 72 + kc];
    }
}

// Flash attention v4 (bisect build):
//  - swapped QK^T (mfma(K,Q)) so each lane's P row is dense in keys
//  - P routed through per-wave LDS (b64 packed writes, b128 fragment reads)
//  - plain pretransposed V (round-0 vtrans), K/V double-buffered via
//    global_load_lds with XOR-pre-swizzled SOURCE (linear LDS dest),
//    one barrier per tile
//  - fixed-max exp2-domain softmax; rs broadcast via LDS after a barrier
//  - 4 waves x 32 q-rows (128 q/block); grid (16, 32, 2); in-place output.
__global__ __launch_bounds__(256, 3) void attn4(short* __restrict__ qkv,
                                                const short* __restrict__ Vt_g) {
    __shared__ __align__(16) short KV[2][2][4096];   // [buf][K/V][64*64]
    __shared__ __align__(16) short Ps[4][2][16 * 80];
    __shared__ float rsb[4][32];

    const int tid = threadIdx.x;
    const int lane = tid & 63;
    const int wave = tid >> 6;
    const int quad = lane >> 4;
    const int l15 = lane & 15;
    const int b = blockIdx.z;
    const int h = blockIdx.y;
    const int kvh = h >> 2;
    const int q0 = blockIdx.x * 128;

    const long kbase = ((long)b * 2048) * 3072 + 2048 + kvh * 64;
    const long vtbase = (long)(b * 8 + kvh) * 64 * 2048;

    // Q fragments direct from global (once per block); q rows wave*32+l15 and +16
    const long qrow = (long)b * 2048 + q0 + wave * 32 + l15;
    const short* qp = qkv + qrow * 3072 + h * 64 + quad * 8;
    const s8v qf00 = *(const s8v*)(qp);
    const s8v qf01 = *(const s8v*)(qp + 32);
    const s8v qf10 = *(const s8v*)(qp + 16 * 3072);
    const s8v qf11 = *(const s8v*)(qp + 16 * 3072 + 32);

    // staging: lane writes LDS row wave*8+(lane>>3), pos lane&7;
    // source chunk pre-swizzled: sslot = (lane&7) ^ (lane>>3)
    const int rA = wave * 8 + (lane >> 3);
    const int sslot = (lane & 7) ^ (lane >> 3);
    const short* kA = qkv + kbase + (long)rA * 3072 + sslot * 8;
    const short* kB = kA + (long)32 * 3072;
    const short* vA = Vt_g + vtbase + (long)rA * 2048 + sslot * 8;
    const short* vB = vA + (long)32 * 2048;

    // prologue: stage tile 0 into buf 0
    {
        char* kd = (char*)&KV[0][0][0] + wave * 1024;
        char* vd = (char*)&KV[0][1][0] + wave * 1024;
        __builtin_amdgcn_global_load_lds((gp1_t)kA, (lp3_t)kd, 16, 0, 0);
        __builtin_amdgcn_global_load_lds((gp1_t)kB, (lp3_t)(kd + 4096), 16, 0, 0);
        __builtin_amdgcn_global_load_lds((gp1_t)vA, (lp3_t)vd, 16, 0, 0);
        __builtin_amdgcn_global_load_lds((gp1_t)vB, (lp3_t)(vd + 4096), 16, 0, 0);
    }
    __syncthreads();

    // swizzled read offsets (shorts): LDS pos (quad^(row&7)) holds content chunk quad
    const int ks0 = ((quad ^ (l15 & 7)) << 3);
    const int ks1 = ks0 ^ 32;

    const float CS = 0.18033688011112042f;   // 0.125 * log2(e)

    float rs0 = 0.f, rs1 = 0.f;
    f4v o0[4], o1[4];
#pragma unroll
    for (int ni = 0; ni < 4; ni++) { o0[ni] = (f4v){0.f, 0.f, 0.f, 0.f}; o1[ni] = (f4v){0.f, 0.f, 0.f, 0.f}; }

    short* Pw0 = &Ps[wave][0][0];
    short* Pw1 = &Ps[wave][1][0];

    for (int t = 0; t < 32; ++t) {
        const short* Kb = &KV[t & 1][0][0];
        const short* Vb = &KV[t & 1][1][0];

        if (t < 31) {
            const long ko = (long)(t + 1) * (64 * 3072);
            const long vo = (long)(t + 1) * 64;
            char* kd = (char*)&KV[(t + 1) & 1][0][0] + wave * 1024;
            char* vd = (char*)&KV[(t + 1) & 1][1][0] + wave * 1024;
            __builtin_amdgcn_global_load_lds((gp1_t)(kA + ko), (lp3_t)kd, 16, 0, 0);
            __builtin_amdgcn_global_load_lds((gp1_t)(kB + ko), (lp3_t)(kd + 4096), 16, 0, 0);
            __builtin_amdgcn_global_load_lds((gp1_t)(vA + vo), (lp3_t)vd, 16, 0, 0);
            __builtin_amdgcn_global_load_lds((gp1_t)(vB + vo), (lp3_t)(vd + 4096), 16, 0, 0);
        }

        // QK^T swapped: lane (quad,l15) reg r holds S[key = ni*16+quad*4+r][q = l15]
#pragma unroll
        for (int ni = 0; ni < 4; ni++) {
            const int ro = (ni * 16 + l15) * 64;
            const s8v kf0 = *(const s8v*)&Kb[ro + ks0];
            const s8v kf1 = *(const s8v*)&Kb[ro + ks1];
            f4v a = (f4v){0.f, 0.f, 0.f, 0.f};
            a = __builtin_amdgcn_mfma_f32_16x16x32_bf16(kf0, qf00, a, 0, 0, 0);
            a = __builtin_amdgcn_mfma_f32_16x16x32_bf16(kf1, qf01, a, 0, 0, 0);
            {
                float p0 = exp2f(fmaf(a[0], CS, -24.f));
                float p1 = exp2f(fmaf(a[1], CS, -24.f));
                float p2 = exp2f(fmaf(a[2], CS, -24.f));
                float p3 = exp2f(fmaf(a[3], CS, -24.f));
                rs0 += (p0 + p1) + (p2 + p3);
                // P[q=l15][keys ni*16+quad*4 .. +3], packed pairs
                *(i2v*)&Pw0[l15 * 80 + ni * 16 + quad * 4] =
                    (i2v){(int)pk2(p0, p1), (int)pk2(p2, p3)};
            }
            f4v c = (f4v){0.f, 0.f, 0.f, 0.f};
            c = __builtin_amdgcn_mfma_f32_16x16x32_bf16(kf0, qf10, c, 0, 0, 0);
            c = __builtin_amdgcn_mfma_f32_16x16x32_bf16(kf1, qf11, c, 0, 0, 0);
            {
                float p0 = exp2f(fmaf(c[0], CS, -24.f));
                float p1 = exp2f(fmaf(c[1], CS, -24.f));
                float p2 = exp2f(fmaf(c[2], CS, -24.f));
                float p3 = exp2f(fmaf(c[3], CS, -24.f));
                rs1 += (p0 + p1) + (p2 + p3);
                *(i2v*)&Pw1[l15 * 80 + ni * 16 + quad * 4] =
                    (i2v){(int)pk2(p0, p1), (int)pk2(p2, p3)};
            }
        }

        // PV: A = P[q rows][keys] from LDS, B = V[key][dim] fragments
        const s8v pf00 = *(const s8v*)&Pw0[l15 * 80 + quad * 8];
        const s8v pf01 = *(const s8v*)&Pw0[l15 * 80 + 32 + quad * 8];
        const s8v pf10 = *(const s8v*)&Pw1[l15 * 80 + quad * 8];
        const s8v pf11 = *(const s8v*)&Pw1[l15 * 80 + 32 + quad * 8];
#pragma unroll
        for (int ni = 0; ni < 4; ni++) {
            const int ro = (ni * 16 + l15) * 64;
            const s8v vf0 = *(const s8v*)&Vb[ro + ks0];
            const s8v vf1 = *(const s8v*)&Vb[ro + ks1];
            o0[ni] = __builtin_amdgcn_mfma_f32_16x16x32_bf16(pf00, vf0, o0[ni], 0, 0, 0);
            o0[ni] = __builtin_amdgcn_mfma_f32_16x16x32_bf16(pf01, vf1, o0[ni], 0, 0, 0);
            o1[ni] = __builtin_amdgcn_mfma_f32_16x16x32_bf16(pf10, vf0, o1[ni], 0, 0, 0);
            o1[ni] = __builtin_amdgcn_mfma_f32_16x16x32_bf16(pf11, vf1, o1[ni], 0, 0, 0);
        }
        __syncthreads();
    }

    // rs: per-lane partial (16 keys) for q = l15; reduce over quads, broadcast via LDS
    rs0 += __shfl_xor(rs0, 16); rs0 += __shfl_xor(rs0, 32);
    rs1 += __shfl_xor(rs1, 16); rs1 += __shfl_xor(rs1, 32);
    if (quad == 0) { rsb[wave][l15] = rs0; rsb[wave][16 + l15] = rs1; }
    __syncthreads();

#pragma unroll
    for (int r = 0; r < 4; r++) {
        const float i0 = 1.0f / rsb[wave][quad * 4 + r];
        const float i1 = 1.0f / rsb[wave][16 + quad * 4 + r];
        const long ob0 = ((long)b * 2048 + q0 + wave * 32 + quad * 4 + r) * 3072 + h * 64;
        const long ob1 = ob0 + 16 * 3072;
#pragma unroll
        for (int ni = 0; ni < 4; ni++) {
            qkv[ob0 + ni * 16 + l15] = f2bf(o0[ni][r] * i0);
            qkv[ob1 + ni * 16 + l15] = f2bf(o1[ni][r] * i1);
        }
    }
}

// ======================= FALLBACK PATH (round-6, known-PASS) =======================

template <bool AF32, bool CF32>
__global__ __launch_bounds__(256) void gemm_bn(const void* __restrict__ Av,
                                               const float* __restrict__ B,
                                               void* __restrict__ Cv,
                                               int K, int N, int lda, int ldc) {
    __shared__ __align__(16) short As[128 * 40];
    __shared__ __align__(16) short Bs[128 * 40];
    const int tid = threadIdx.x;
    const int lane = tid & 63;
    const int wave = tid >> 6;
    const int quad = lane >> 4;
    const int l15 = lane & 15;
    const int m0 = blockIdx.y * 128;
    const int n0 = blockIdx.x * 128;
    const int wm = (wave & 1) * 64;
    const int wn = (wave >> 1) * 64;

    f4v acc[4][4];
#pragma unroll
    for (int i = 0; i < 4; i++)
#pragma unroll
        for (int j = 0; j < 4; j++) acc[i][j] = (f4v){0.f, 0.f, 0.f, 0.f};

    const int ar0 = tid >> 2, akc0 = (tid & 3) * 8;
    const int ar1 = (tid + 256) >> 2, akc1 = ((tid + 256) & 3) * 8;
    const int bk0 = tid >> 4, bnc0 = (tid & 15) * 8;
    const int bk1 = (tid + 256) >> 4, bnc1 = ((tid + 256) & 15) * 8;

    for (int k0 = 0; k0 < K; k0 += 32) {
        __syncthreads();
        if (AF32) {
            const float* A = (const float*)Av;
            *(s8v*)(&As[ar0 * 40 + akc0]) = cvt8(&A[(long)(m0 + ar0) * lda + k0 + akc0]);
            *(s8v*)(&As[ar1 * 40 + akc1]) = cvt8(&A[(long)(m0 + ar1) * lda + k0 + akc1]);
        } else {
            const short* A = (const short*)Av;
            *(s8v*)(&As[ar0 * 40 + akc0]) = *(const s8v*)(&A[(long)(m0 + ar0) * lda + k0 + akc0]);
            *(s8v*)(&As[ar1 * 40 + akc1]) = *(const s8v*)(&A[(long)(m0 + ar1) * lda + k0 + akc1]);
        }
        s8v b0 = cvt8(&B[(long)(k0 + bk0) * N + n0 + bnc0]);
        s8v b1 = cvt8(&B[(long)(k0 + bk1) * N + n0 + bnc1]);
#pragma unroll
        for (int i = 0; i < 8; i++) Bs[(bnc0 + i) * 40 + bk0] = b0[i];
#pragma unroll
        for (int i = 0; i < 8; i++) Bs[(bnc1 + i) * 40 + bk1] = b1[i];
        __syncthreads();
        s8v af[4], bfr[4];
#pragma unroll
        for (int mi = 0; mi < 4; mi++)
            af[mi] = *(const s8v*)(&As[(wm + mi * 16 + l15) * 40 + quad * 8]);
#pragma unroll
        for (int ni = 0; ni < 4; ni++)
            bfr[ni] = *(const s8v*)(&Bs[(wn + ni * 16 + l15) * 40 + quad * 8]);
#pragma unroll
        for (int mi = 0; mi < 4; mi++)
#pragma unroll
            for (int ni = 0; ni < 4; ni++)
                acc[mi][ni] = __builtin_amdgcn_mfma_f32_16x16x32_bf16(af[mi], bfr[ni], acc[mi][ni], 0, 0, 0);
    }
#pragma unroll
    for (int mi = 0; mi < 4; mi++)
#pragma unroll
        for (int ni = 0; ni < 4; ni++)
#pragma unroll
            for (int r = 0; r < 4; r++) {
                int row = m0 + wm + mi * 16 + quad * 4 + r;
                int col = n0 + wn + ni * 16 + l15;
                if (CF32) ((float*)Cv)[(long)row * ldc + col] = acc[mi][ni][r];
                else      ((short*)Cv)[(long)row * ldc + col] = f2bf(acc[mi][ni][r]);
            }
}

__global__ __launch_bounds__(256) void attn_kernel(short* __restrict__ qkv) {
    __shared__ __align__(16) short Qs[64 * 72];
    __shared__ __align__(16) short Ks[64 * 72];
    __shared__ __align__(16) short Vt[64 * 72];
    __shared__ __align__(16) short Ps[4][16 * 72];

    const int tid = threadIdx.x;
    const int lane = tid & 63;
    const int wave = tid >> 6;
    const int quad = lane >> 4;
    const int l15 = lane & 15;
    const int b = blockIdx.z;
    const int h = blockIdx.y;
    const int kvh = h >> 2;
    const int q0 = blockIdx.x * 64;

    const long qbase = ((long)b * 2048 + q0) * 3072 + h * 64;
    const long kbase = ((long)b * 2048) * 3072 + 2048 + kvh * 64;
    const long vbase = kbase + 512;

#pragma unroll
    for (int cc = 0; cc < 2; cc++) {
        int ch = tid + cc * 256;
        int r = ch >> 3, d0 = (ch & 7) * 8;
        *(s8v*)(&Qs[r * 72 + d0]) = *(const s8v*)(&qkv[qbase + (long)r * 3072 + d0]);
    }
    __syncthreads();
    s8v qf[2];
    qf[0] = *(const s8v*)(&Qs[(wave * 16 + l15) * 72 + quad * 8]);
    qf[1] = *(const s8v*)(&Qs[(wave * 16 + l15) * 72 + 32 + quad * 8]);

    float m_i[4], l_i[4];
    f4v o[4];
#pragma unroll
    for (int r = 0; r < 4; r++) { m_i[r] = -1e30f; l_i[r] = 0.0f; }
#pragma unroll
    for (int ni = 0; ni < 4; ni++) o[ni] = (f4v){0.f, 0.f, 0.f, 0.f};

    for (int kt = 0; kt < 2048; kt += 64) {
        __syncthreads();
#pragma unroll
        for (int cc = 0; cc < 2; cc++) {
            int ch = tid + cc * 256;
            int r = ch >> 3, d0 = (ch & 7) * 8;
            *(s8v*)(&Ks[r * 72 + d0]) = *(const s8v*)(&qkv[kbase + (long)(kt + r) * 3072 + d0]);
            s8v v = *(const s8v*)(&qkv[vbase + (long)(kt + r) * 3072 + d0]);
            int g = d0 >> 3;
            int chn = ((r >> 3) ^ g) * 8 + (r & 7);
#pragma unroll
            for (int i = 0; i < 8; i++) Vt[(d0 + i) * 72 + chn] = v[i];
        }
        __syncthreads();

        f4v sc[4];
#pragma unroll
        for (int ni = 0; ni < 4; ni++) {
            s8v kf0 = *(const s8v*)(&Ks[(ni * 16 + l15) * 72 + quad * 8]);
            s8v kf1 = *(const s8v*)(&Ks[(ni * 16 + l15) * 72 + 32 + quad * 8]);
            f4v a = (f4v){0.f, 0.f, 0.f, 0.f};
            a = __builtin_amdgcn_mfma_f32_16x16x32_bf16(qf[0], kf0, a, 0, 0, 0);
            a = __builtin_amdgcn_mfma_f32_16x16x32_bf16(qf[1], kf1, a, 0, 0, 0);
            sc[ni] = a * 0.125f;
        }
        float alpha[4], rs[4];
#pragma unroll
        for (int r = 0; r < 4; r++) {
            float v = fmaxf(fmaxf(sc[0][r], sc[1][r]), fmaxf(sc[2][r], sc[3][r]));
            v = fmaxf(v, __shfl_xor(v, 1));
            v = fmaxf(v, __shfl_xor(v, 2));
            v = fmaxf(v, __shfl_xor(v, 4));
            v = fmaxf(v, __shfl_xor(v, 8));
            float mn = fmaxf(m_i[r], v);
            alpha[r] = __expf(m_i[r] - mn);
            m_i[r] = mn;
            rs[r] = 0.f;
        }
#pragma unroll
        for (int ni = 0; ni < 4; ni++)
#pragma unroll
            for (int r = 0; r < 4; r++) {
                float pv = __expf(sc[ni][r] - m_i[r]);
                sc[ni][r] = pv;
                rs[r] += pv;
            }
#pragma unroll
        for (int r = 0; r < 4; r++) {
            float v = rs[r];
            v += __shfl_xor(v, 1);
            v += __shfl_xor(v, 2);
            v += __shfl_xor(v, 4);
            v += __shfl_xor(v, 8);
            l_i[r] = l_i[r] * alpha[r] + v;
        }
#pragma unroll
        for (int ni = 0; ni < 4; ni++)
#pragma unroll
            for (int r = 0; r < 4; r++) {
                int row = quad * 4 + r;
                int key = ni * 16 + l15;
                int chn = ((key >> 3) ^ (row >> 3)) * 8 + (key & 7);
                Ps[wave][row * 72 + chn] = f2bf(sc[ni][r]);
            }
        __syncthreads();
#pragma unroll
        for (int ni = 0; ni < 4; ni++) {
            f4v t = o[ni];
            t[0] *= alpha[0]; t[1] *= alpha[1]; t[2] *= alpha[2]; t[3] *= alpha[3];
            o[ni] = t;
        }
        s8v pf0 = *(const s8v*)(&Ps[wave][l15 * 72 + ((quad ^ (l15 >> 3)) * 8)]);
        s8v pf1 = *(const s8v*)(&Ps[wave][l15 * 72 + (((4 + quad) ^ (l15 >> 3)) * 8)]);
#pragma unroll
        for (int ni = 0; ni < 4; ni++) {
            int d = ni * 16 + l15;
            s8v vf0 = *(const s8v*)(&Vt[d * 72 + ((quad ^ (d >> 3)) * 8)]);
            s8v vf1 = *(const s8v*)(&Vt[d * 72 + (((4 + quad) ^ (d >> 3)) * 8)]);
            o[ni] = __builtin_amdgcn_mfma_f32_16x16x32_bf16(pf0, vf0, o[ni], 0, 0, 0);
            o[ni] = __builtin_amdgcn_mfma_f32_16x16x32_bf16(pf1, vf1, o[ni], 0, 0, 0);
        }
    }
#pragma unroll
    for (int r = 0; r < 4; r++) {
        float inv = 1.0f / l_i[r];
        int srow = q0 + wave * 16 + quad * 4 + r;
        long obase = ((long)b * 2048 + srow) * 3072 + h * 64;
#pragma unroll
        for (int ni = 0; ni < 4; ni++)
            qkv[obase + ni * 16 + l15] = f2bf(o[ni][r] * inv);
    }
}

extern "C" void kernel_launch(void* const* d_in, const int* in_sizes, int n_in,
                              void* d_out, int out_size, void* d_ws, size_t ws_size,
                              hipStream_t stream) {
    (void)in_sizes; (void)n_in; (void)out_size;
    const float* x  = (const float*)d_in[0];
    const float* Wq = (const float*)d_in[1];
    const float* Wk = (const float*)d_in[2];
    const float* Wv = (const float*)d_in[3];
    const float* Wo = (const float*)d_in[4];

    const size_t need = 67108864ULL; // 64 MiB
    if (ws_size >= need) {
        short* xb    = (short*)d_ws;              // 4096x2048
        short* Wqkvt = xb + 8388608;              // 3072x2048
        short* Wot   = Wqkvt + 6291456;           // 2048x2048
        short* qkv   = Wot + 4194304;             // 4096x3072
        short* Vt_g  = qkv + 12582912;            // 16x64x2048

        cvt_x<<<4096, 256, 0, stream>>>(x, xb);
        cvt_wt<<<dim3(32, 32), 256, 0, stream>>>(Wq, Wqkvt, 2048, 0);
        cvt_wt<<<dim3(8, 32), 256, 0, stream>>>(Wk, Wqkvt, 512, 2048);
        cvt_wt<<<dim3(8, 32), 256, 0, stream>>>(Wv, Wqkvt, 512, 2560);
        cvt_wt<<<dim3(32, 32), 256, 0, stream>>>(Wo, Wot, 2048, 0);
        gemm_bt<false><<<dim3(24, 32), 256, 0, stream>>>(xb, Wqkvt, qkv, 2048, 2048, 2048, 3072);
        rope_kernel<<<dim3(20480), 256, 0, stream>>>(qkv);
        vtrans<<<dim3(32, 8, 2), 256, 0, stream>>>(qkv, Vt_g);
        attn4<<<dim3(16, 32, 2), 256, 0, stream>>>(qkv, Vt_g);
        gemm_bt<true><<<dim3(16, 32), 256, 0, stream>>>(qkv, Wot, d_out, 2048, 3072, 2048, 2048);
    } else {
        short* qkv = (short*)d_ws;
        gemm_bn<true, false><<<dim3(16, 32), 256, 0, stream>>>(x, Wq, qkv,        2048, 2048, 2048, 3072);
        gemm_bn<true, false><<<dim3(4, 32), 256, 0, stream>>>(x, Wk, qkv + 2048, 2048,  512, 2048, 3072);
        gemm_bn<true, false><<<dim3(4, 32), 256, 0, stream>>>(x, Wv, qkv + 2560, 2048,  512, 2048, 3072);
        rope_kernel<<<dim3(20480), 256, 0, stream>>>(qkv);
        attn_kernel<<<dim3(32, 32, 2), 256, 0, stream>>>(qkv);
        gemm_bn<false, true><<<dim3(16, 32), 256, 0, stream>>>(qkv, Wo, d_out, 2048, 2048, 3072, 2048);
    }
}

// Round 5
// 376.045 us; speedup vs baseline: 1.1910x; 1.0743x over previous
//
#include <hip/hip_runtime.h>

typedef short s8v __attribute__((ext_vector_type(8)));
typedef int i2v __attribute__((ext_vector_type(2)));
typedef float f4v __attribute__((ext_vector_type(4)));

typedef const __attribute__((address_space(1))) char* gp1_t;
typedef __attribute__((address_space(3))) char* lp3_t;

__device__ __forceinline__ float bf2f(short s) {
    union { unsigned u; float f; } c;
    c.u = ((unsigned)(unsigned short)s) << 16;
    return c.f;
}
__device__ __forceinline__ short f2bf(float f) {
    union { float f; unsigned u; } c; c.f = f;
    unsigned r = (c.u + 0x7FFFu + ((c.u >> 16) & 1u)) >> 16;
    return (short)r;
}
__device__ __forceinline__ unsigned cvt_pk_bf16(float a, float b) {
    unsigned r;
    asm("v_cvt_pk_bf16_f32 %0, %1, %2" : "=v"(r) : "v"(a), "v"(b));
    return r;
}
__device__ __forceinline__ s8v cvt8(const float* __restrict__ p) {
    f4v a = *(const f4v*)p;
    f4v b = *(const f4v*)(p + 4);
    s8v r;
    r[0] = f2bf(a[0]); r[1] = f2bf(a[1]); r[2] = f2bf(a[2]); r[3] = f2bf(a[3]);
    r[4] = f2bf(b[0]); r[5] = f2bf(b[1]); r[6] = f2bf(b[2]); r[7] = f2bf(b[3]);
    return r;
}

// ======================= FAST PATH (ws >= 64 MiB) =======================

// fp32 -> bf16 straight copy (x)
__global__ __launch_bounds__(256) void cvt_x(const float* __restrict__ x,
                                             short* __restrict__ xb) {
    long i = ((long)blockIdx.x * 256 + threadIdx.x) * 8;
    *(s8v*)&xb[i] = cvt8(&x[i]);
}

// W (2048 x N fp32) -> Wt rows [obase+n][k] bf16 (ld 2048)
__global__ __launch_bounds__(256) void cvt_wt(const float* __restrict__ W,
                                              short* __restrict__ Wt,
                                              int N, int obase) {
    __shared__ __align__(16) short tile[64 * 72];
    const int kt = blockIdx.y * 64, n0 = blockIdx.x * 64;
    const int t = threadIdx.x;
    const int r = t >> 4, c4 = (t & 15) * 4;
#pragma unroll
    for (int i = 0; i < 4; i++) {
        int kr = r + i * 16;
        f4v v = *(const f4v*)&W[(long)(kt + kr) * N + n0 + c4];
#pragma unroll
        for (int j = 0; j < 4; j++) tile[(c4 + j) * 72 + kr] = f2bf(v[j]);
    }
    __syncthreads();
    const int nr = t >> 3, kc = (t & 7) * 8;
#pragma unroll
    for (int i = 0; i < 2; i++) {
        int n = nr + i * 32;
        *(s8v*)&Wt[(long)(obase + n0 + n) * 2048 + kt + kc] = *(const s8v*)&tile[n * 72 + kc];
    }
}

// m97-style GEMM: A (M x K bf16, stride lda), Bt (N x K bf16, stride ldb),
// C (M x N, stride ldc; fp32 or bf16). 128x128 tile, BK=32,
// global_load_lds width=16 staging, unpadded LDS tiles.
template <bool CF32>
__global__ __launch_bounds__(256) void gemm_bt(const short* __restrict__ A,
                                               const short* __restrict__ Bt,
                                               void* __restrict__ Cv,
                                               int K, int lda, int ldb, int ldc) {
    __shared__ __align__(16) short As[128 * 32];
    __shared__ __align__(16) short Bs[128 * 32];
    const int tid = threadIdx.x;
    const int lane = tid & 63;
    const int wave = tid >> 6;
    const int quad = lane >> 4;
    const int l15 = lane & 15;
    const int m0 = blockIdx.y * 128;
    const int n0 = blockIdx.x * 128;
    const int wm = (wave & 1) * 64;
    const int wn = (wave >> 1) * 64;

    f4v acc[4][4];
#pragma unroll
    for (int i = 0; i < 4; i++)
#pragma unroll
        for (int j = 0; j < 4; j++) acc[i][j] = (f4v){0.f, 0.f, 0.f, 0.f};

    const int s0 = wave * 64 + lane, s1 = (4 + wave) * 64 + lane;
    const short* a0 = A + (long)(m0 + (s0 >> 2)) * lda + (s0 & 3) * 8;
    const short* a1 = A + (long)(m0 + (s1 >> 2)) * lda + (s1 & 3) * 8;
    const short* b0 = Bt + (long)(n0 + (s0 >> 2)) * ldb + (s0 & 3) * 8;
    const short* b1 = Bt + (long)(n0 + (s1 >> 2)) * ldb + (s1 & 3) * 8;
    char* lA0 = (char*)As + wave * 1024;
    char* lA1 = (char*)As + (4 + wave) * 1024;
    char* lB0 = (char*)Bs + wave * 1024;
    char* lB1 = (char*)Bs + (4 + wave) * 1024;

    for (int k0 = 0; k0 < K; k0 += 32) {
        __syncthreads();
        __builtin_amdgcn_global_load_lds((gp1_t)(a0 + k0), (lp3_t)lA0, 16, 0, 0);
        __builtin_amdgcn_global_load_lds((gp1_t)(a1 + k0), (lp3_t)lA1, 16, 0, 0);
        __builtin_amdgcn_global_load_lds((gp1_t)(b0 + k0), (lp3_t)lB0, 16, 0, 0);
        __builtin_amdgcn_global_load_lds((gp1_t)(b1 + k0), (lp3_t)lB1, 16, 0, 0);
        __syncthreads();
        s8v af[4], bfr[4];
#pragma unroll
        for (int mi = 0; mi < 4; mi++)
            af[mi] = *(const s8v*)(&As[(wm + mi * 16 + l15) * 32 + quad * 8]);
#pragma unroll
        for (int ni = 0; ni < 4; ni++)
            bfr[ni] = *(const s8v*)(&Bs[(wn + ni * 16 + l15) * 32 + quad * 8]);
#pragma unroll
        for (int mi = 0; mi < 4; mi++)
#pragma unroll
            for (int ni = 0; ni < 4; ni++)
                acc[mi][ni] = __builtin_amdgcn_mfma_f32_16x16x32_bf16(af[mi], bfr[ni], acc[mi][ni], 0, 0, 0);
    }
#pragma unroll
    for (int mi = 0; mi < 4; mi++)
#pragma unroll
        for (int ni = 0; ni < 4; ni++)
#pragma unroll
            for (int r = 0; r < 4; r++) {
                int row = m0 + wm + mi * 16 + quad * 4 + r;
                int col = n0 + wn + ni * 16 + l15;
                if (CF32) ((float*)Cv)[(long)row * ldc + col] = acc[mi][ni][r];
                else      ((short*)Cv)[(long)row * ldc + col] = f2bf(acc[mi][ni][r]);
            }
}

// RoPE in-place on qkv cols [0,2560)
__global__ __launch_bounds__(256) void rope_kernel(short* __restrict__ qkv) {
    int tid = blockIdx.x * 256 + threadIdx.x;
    int p = tid % 1280;
    int row = tid / 1280;
    int head = p >> 5;
    int j = p & 31;
    int s = row & 2047;
    int c1 = head * 64 + j;
    float freq = exp2f(-(float)j * 0.4152410118609203f); // log2(10000)/32
    float ang = (float)s * freq;
    float sn, cs;
    __sincosf(ang, &sn, &cs);
    long base = (long)row * 3072;
    float x1 = bf2f(qkv[base + c1]);
    float x2 = bf2f(qkv[base + c1 + 32]);
    qkv[base + c1]      = f2bf(x1 * cs - x2 * sn);
    qkv[base + c1 + 32] = f2bf(x2 * cs + x1 * sn);
}

// V transpose (round-0 verified): qkv v-region -> Vt_g[(b*8+kvh)*64 + d][key] (ld 2048)
__global__ __launch_bounds__(256) void vtrans(const short* __restrict__ qkv,
                                              short* __restrict__ Vt_g) {
    __shared__ __align__(16) short tile[64 * 72];
    const int kt = blockIdx.x * 64;
    const int kvh = blockIdx.y;
    const int b = blockIdx.z;
    const int t = threadIdx.x;
#pragma unroll
    for (int cc = 0; cc < 2; cc++) {
        int ch = t + cc * 256;
        int key = ch >> 3, d0 = (ch & 7) * 8;
        s8v v = *(const s8v*)&qkv[(long)(b * 2048 + kt + key) * 3072 + 2560 + kvh * 64 + d0];
#pragma unroll
        for (int i = 0; i < 8; i++) tile[(d0 + i) * 72 + key] = v[i];
    }
    __syncthreads();
#pragma unroll
    for (int cc = 0; cc < 2; cc++) {
        int ch = t + cc * 256;
        int d = ch >> 3, kc = (ch & 7) * 8;
        *(s8v*)&Vt_g[(long)((b * 8 + kvh) * 64 + d) * 2048 + kt + kc] = *(const s8v*)&tile[d * 72 + kc];
    }
}

// Flash attention v4.1:
//  - swapped QK^T (mfma(K,Q)); P packed via v_cvt_pk_bf16_f32, routed through
//    per-wave LDS (b64 writes, b128 fragment reads), stride 72 (2-way free)
//  - plain pretransposed V, K/V double-buffered via global_load_lds with
//    XOR-pre-swizzled SOURCE (linear LDS dest), one barrier per tile
//  - fixed-max exp2-domain softmax; rs broadcast via LDS
//  - 4 waves x 32 q-rows (128 q/block); grid (16, 32, 2); in-place output.
__global__ __launch_bounds__(256, 3) void attn4(short* __restrict__ qkv,
                                                const short* __restrict__ Vt_g) {
    __shared__ __align__(16) short KV[2][2][4096];   // [buf][K/V][64*64]
    __shared__ __align__(16) short Ps[4][2][16 * 72];
    __shared__ float rsb[4][32];

    const int tid = threadIdx.x;
    const int lane = tid & 63;
    const int wave = tid >> 6;
    const int quad = lane >> 4;
    const int l15 = lane & 15;
    const int b = blockIdx.z;
    const int h = blockIdx.y;
    const int kvh = h >> 2;
    const int q0 = blockIdx.x * 128;

    const long kbase = ((long)b * 2048) * 3072 + 2048 + kvh * 64;
    const long vtbase = (long)(b * 8 + kvh) * 64 * 2048;

    // Q fragments direct from global (once per block); q rows wave*32+l15 and +16
    const long qrow = (long)b * 2048 + q0 + wave * 32 + l15;
    const short* qp = qkv + qrow * 3072 + h * 64 + quad * 8;
    const s8v qf00 = *(const s8v*)(qp);
    const s8v qf01 = *(const s8v*)(qp + 32);
    const s8v qf10 = *(const s8v*)(qp + 16 * 3072);
    const s8v qf11 = *(const s8v*)(qp + 16 * 3072 + 32);

    // staging: lane writes LDS row wave*8+(lane>>3), pos lane&7;
    // source chunk pre-swizzled: sslot = (lane&7) ^ (lane>>3)
    const int rA = wave * 8 + (lane >> 3);
    const int sslot = (lane & 7) ^ (lane >> 3);
    const short* kA = qkv + kbase + (long)rA * 3072 + sslot * 8;
    const short* kB = kA + (long)32 * 3072;
    const short* vA = Vt_g + vtbase + (long)rA * 2048 + sslot * 8;
    const short* vB = vA + (long)32 * 2048;

    // prologue: stage tile 0 into buf 0
    {
        char* kd = (char*)&KV[0][0][0] + wave * 1024;
        char* vd = (char*)&KV[0][1][0] + wave * 1024;
        __builtin_amdgcn_global_load_lds((gp1_t)kA, (lp3_t)kd, 16, 0, 0);
        __builtin_amdgcn_global_load_lds((gp1_t)kB, (lp3_t)(kd + 4096), 16, 0, 0);
        __builtin_amdgcn_global_load_lds((gp1_t)vA, (lp3_t)vd, 16, 0, 0);
        __builtin_amdgcn_global_load_lds((gp1_t)vB, (lp3_t)(vd + 4096), 16, 0, 0);
    }
    __syncthreads();

    // swizzled read offsets (shorts): LDS pos (quad^(row&7)) holds content chunk quad
    const int ks0 = ((quad ^ (l15 & 7)) << 3);
    const int ks1 = ks0 ^ 32;

    const float CS = 0.18033688011112042f;   // 0.125 * log2(e)

    float rs0 = 0.f, rs1 = 0.f;
    f4v o0[4], o1[4];
#pragma unroll
    for (int ni = 0; ni < 4; ni++) { o0[ni] = (f4v){0.f, 0.f, 0.f, 0.f}; o1[ni] = (f4v){0.f, 0.f, 0.f, 0.f}; }

    short* Pw0 = &Ps[wave][0][0];
    short* Pw1 = &Ps[wave][1][0];

    for (int t = 0; t < 32; ++t) {
        const short* Kb = &KV[t & 1][0][0];
        const short* Vb = &KV[t & 1][1][0];

        if (t < 31) {
            const long ko = (long)(t + 1) * (64 * 3072);
            const long vo = (long)(t + 1) * 64;
            char* kd = (char*)&KV[(t + 1) & 1][0][0] + wave * 1024;
            char* vd = (char*)&KV[(t + 1) & 1][1][0] + wave * 1024;
            __builtin_amdgcn_global_load_lds((gp1_t)(kA + ko), (lp3_t)kd, 16, 0, 0);
            __builtin_amdgcn_global_load_lds((gp1_t)(kB + ko), (lp3_t)(kd + 4096), 16, 0, 0);
            __builtin_amdgcn_global_load_lds((gp1_t)(vA + vo), (lp3_t)vd, 16, 0, 0);
            __builtin_amdgcn_global_load_lds((gp1_t)(vB + vo), (lp3_t)(vd + 4096), 16, 0, 0);
        }

        // QK^T swapped: lane (quad,l15) reg r holds S[key = ni*16+quad*4+r][q = l15]
#pragma unroll
        for (int ni = 0; ni < 4; ni++) {
            const int ro = (ni * 16 + l15) * 64;
            const s8v kf0 = *(const s8v*)&Kb[ro + ks0];
            const s8v kf1 = *(const s8v*)&Kb[ro + ks1];
            f4v a = (f4v){0.f, 0.f, 0.f, 0.f};
            a = __builtin_amdgcn_mfma_f32_16x16x32_bf16(kf0, qf00, a, 0, 0, 0);
            a = __builtin_amdgcn_mfma_f32_16x16x32_bf16(kf1, qf01, a, 0, 0, 0);
            {
                float p0 = exp2f(fmaf(a[0], CS, -24.f));
                float p1 = exp2f(fmaf(a[1], CS, -24.f));
                float p2 = exp2f(fmaf(a[2], CS, -24.f));
                float p3 = exp2f(fmaf(a[3], CS, -24.f));
                rs0 += (p0 + p1) + (p2 + p3);
                // P[q=l15][keys ni*16+quad*4 .. +3], packed pairs
                *(i2v*)&Pw0[l15 * 72 + ni * 16 + quad * 4] =
                    (i2v){(int)cvt_pk_bf16(p0, p1), (int)cvt_pk_bf16(p2, p3)};
            }
            f4v c = (f4v){0.f, 0.f, 0.f, 0.f};
            c = __builtin_amdgcn_mfma_f32_16x16x32_bf16(kf0, qf10, c, 0, 0, 0);
            c = __builtin_amdgcn_mfma_f32_16x16x32_bf16(kf1, qf11, c, 0, 0, 0);
            {
                float p0 = exp2f(fmaf(c[0], CS, -24.f));
                float p1 = exp2f(fmaf(c[1], CS, -24.f));
                float p2 = exp2f(fmaf(c[2], CS, -24.f));
                float p3 = exp2f(fmaf(c[3], CS, -24.f));
                rs1 += (p0 + p1) + (p2 + p3);
                *(i2v*)&Pw1[l15 * 72 + ni * 16 + quad * 4] =
                    (i2v){(int)cvt_pk_bf16(p0, p1), (int)cvt_pk_bf16(p2, p3)};
            }
        }

        // PV: A = P[q rows][keys] from LDS, B = V[key][dim] fragments
        const s8v pf00 = *(const s8v*)&Pw0[l15 * 72 + quad * 8];
        const s8v pf01 = *(const s8v*)&Pw0[l15 * 72 + 32 + quad * 8];
        const s8v pf10 = *(const s8v*)&Pw1[l15 * 72 + quad * 8];
        const s8v pf11 = *(const s8v*)&Pw1[l15 * 72 + 32 + quad * 8];
#pragma unroll
        for (int ni = 0; ni < 4; ni++) {
            const int ro = (ni * 16 + l15) * 64;
            const s8v vf0 = *(const s8v*)&Vb[ro + ks0];
            const s8v vf1 = *(const s8v*)&Vb[ro + ks1];
            o0[ni] = __builtin_amdgcn_mfma_f32_16x16x32_bf16(pf00, vf0, o0[ni], 0, 0, 0);
            o0[ni] = __builtin_amdgcn_mfma_f32_16x16x32_bf16(pf01, vf1, o0[ni], 0, 0, 0);
            o1[ni] = __builtin_amdgcn_mfma_f32_16x16x32_bf16(pf10, vf0, o1[ni], 0, 0, 0);
            o1[ni] = __builtin_amdgcn_mfma_f32_16x16x32_bf16(pf11, vf1, o1[ni], 0, 0, 0);
        }
        __syncthreads();
    }

    // rs: per-lane partial (16 keys) for q = l15; reduce over quads, broadcast via LDS
    rs0 += __shfl_xor(rs0, 16); rs0 += __shfl_xor(rs0, 32);
    rs1 += __shfl_xor(rs1, 16); rs1 += __shfl_xor(rs1, 32);
    if (quad == 0) { rsb[wave][l15] = rs0; rsb[wave][16 + l15] = rs1; }
    __syncthreads();

#pragma unroll
    for (int r = 0; r < 4; r++) {
        const float i0 = 1.0f / rsb[wave][quad * 4 + r];
        const float i1 = 1.0f / rsb[wave][16 + quad * 4 + r];
        const long ob0 = ((long)b * 2048 + q0 + wave * 32 + quad * 4 + r) * 3072 + h * 64;
        const long ob1 = ob0 + 16 * 3072;
#pragma unroll
        for (int ni = 0; ni < 4; ni++) {
            qkv[ob0 + ni * 16 + l15] = f2bf(o0[ni][r] * i0);
            qkv[ob1 + ni * 16 + l15] = f2bf(o1[ni][r] * i1);
        }
    }
}

// ======================= FALLBACK PATH (round-6, known-PASS) =======================

template <bool AF32, bool CF32>
__global__ __launch_bounds__(256) void gemm_bn(const void* __restrict__ Av,
                                               const float* __restrict__ B,
                                               void* __restrict__ Cv,
                                               int K, int N, int lda, int ldc) {
    __shared__ __align__(16) short As[128 * 40];
    __shared__ __align__(16) short Bs[128 * 40];
    const int tid = threadIdx.x;
    const int lane = tid & 63;
    const int wave = tid >> 6;
    const int quad = lane >> 4;
    const int l15 = lane & 15;
    const int m0 = blockIdx.y * 128;
    const int n0 = blockIdx.x * 128;
    const int wm = (wave & 1) * 64;
    const int wn = (wave >> 1) * 64;

    f4v acc[4][4];
#pragma unroll
    for (int i = 0; i < 4; i++)
#pragma unroll
        for (int j = 0; j < 4; j++) acc[i][j] = (f4v){0.f, 0.f, 0.f, 0.f};

    const int ar0 = tid >> 2, akc0 = (tid & 3) * 8;
    const int ar1 = (tid + 256) >> 2, akc1 = ((tid + 256) & 3) * 8;
    const int bk0 = tid >> 4, bnc0 = (tid & 15) * 8;
    const int bk1 = (tid + 256) >> 4, bnc1 = ((tid + 256) & 15) * 8;

    for (int k0 = 0; k0 < K; k0 += 32) {
        __syncthreads();
        if (AF32) {
            const float* A = (const float*)Av;
            *(s8v*)(&As[ar0 * 40 + akc0]) = cvt8(&A[(long)(m0 + ar0) * lda + k0 + akc0]);
            *(s8v*)(&As[ar1 * 40 + akc1]) = cvt8(&A[(long)(m0 + ar1) * lda + k0 + akc1]);
        } else {
            const short* A = (const short*)Av;
            *(s8v*)(&As[ar0 * 40 + akc0]) = *(const s8v*)(&A[(long)(m0 + ar0) * lda + k0 + akc0]);
            *(s8v*)(&As[ar1 * 40 + akc1]) = *(const s8v*)(&A[(long)(m0 + ar1) * lda + k0 + akc1]);
        }
        s8v b0 = cvt8(&B[(long)(k0 + bk0) * N + n0 + bnc0]);
        s8v b1 = cvt8(&B[(long)(k0 + bk1) * N + n0 + bnc1]);
#pragma unroll
        for (int i = 0; i < 8; i++) Bs[(bnc0 + i) * 40 + bk0] = b0[i];
#pragma unroll
        for (int i = 0; i < 8; i++) Bs[(bnc1 + i) * 40 + bk1] = b1[i];
        __syncthreads();
        s8v af[4], bfr[4];
#pragma unroll
        for (int mi = 0; mi < 4; mi++)
            af[mi] = *(const s8v*)(&As[(wm + mi * 16 + l15) * 40 + quad * 8]);
#pragma unroll
        for (int ni = 0; ni < 4; ni++)
            bfr[ni] = *(const s8v*)(&Bs[(wn + ni * 16 + l15) * 40 + quad * 8]);
#pragma unroll
        for (int mi = 0; mi < 4; mi++)
#pragma unroll
            for (int ni = 0; ni < 4; ni++)
                acc[mi][ni] = __builtin_amdgcn_mfma_f32_16x16x32_bf16(af[mi], bfr[ni], acc[mi][ni], 0, 0, 0);
    }
#pragma unroll
    for (int mi = 0; mi < 4; mi++)
#pragma unroll
        for (int ni = 0; ni < 4; ni++)
#pragma unroll
            for (int r = 0; r < 4; r++) {
                int row = m0 + wm + mi * 16 + quad * 4 + r;
                int col = n0 + wn + ni * 16 + l15;
                if (CF32) ((float*)Cv)[(long)row * ldc + col] = acc[mi][ni][r];
                else      ((short*)Cv)[(long)row * ldc + col] = f2bf(acc[mi][ni][r]);
            }
}

__global__ __launch_bounds__(256) void attn_kernel(short* __restrict__ qkv) {
    __shared__ __align__(16) short Qs[64 * 72];
    __shared__ __align__(16) short Ks[64 * 72];
    __shared__ __align__(16) short Vt[64 * 72];
    __shared__ __align__(16) short Ps[4][16 * 72];

    const int tid = threadIdx.x;
    const int lane = tid & 63;
    const int wave = tid >> 6;
    const int quad = lane >> 4;
    const int l15 = lane & 15;
    const int b = blockIdx.z;
    const int h = blockIdx.y;
    const int kvh = h >> 2;
    const int q0 = blockIdx.x * 64;

    const long qbase = ((long)b * 2048 + q0) * 3072 + h * 64;
    const long kbase = ((long)b * 2048) * 3072 + 2048 + kvh * 64;
    const long vbase = kbase + 512;

#pragma unroll
    for (int cc = 0; cc < 2; cc++) {
        int ch = tid + cc * 256;
        int r = ch >> 3, d0 = (ch & 7) * 8;
        *(s8v*)(&Qs[r * 72 + d0]) = *(const s8v*)(&qkv[qbase + (long)r * 3072 + d0]);
    }
    __syncthreads();
    s8v qf[2];
    qf[0] = *(const s8v*)(&Qs[(wave * 16 + l15) * 72 + quad * 8]);
    qf[1] = *(const s8v*)(&Qs[(wave * 16 + l15) * 72 + 32 + quad * 8]);

    float m_i[4], l_i[4];
    f4v o[4];
#pragma unroll
    for (int r = 0; r < 4; r++) { m_i[r] = -1e30f; l_i[r] = 0.0f; }
#pragma unroll
    for (int ni = 0; ni < 4; ni++) o[ni] = (f4v){0.f, 0.f, 0.f, 0.f};

    for (int kt = 0; kt < 2048; kt += 64) {
        __syncthreads();
#pragma unroll
        for (int cc = 0; cc < 2; cc++) {
            int ch = tid + cc * 256;
            int r = ch >> 3, d0 = (ch & 7) * 8;
            *(s8v*)(&Ks[r * 72 + d0]) = *(const s8v*)(&qkv[kbase + (long)(kt + r) * 3072 + d0]);
            s8v v = *(const s8v*)(&qkv[vbase + (long)(kt + r) * 3072 + d0]);
            int g = d0 >> 3;
            int chn = ((r >> 3) ^ g) * 8 + (r & 7);
#pragma unroll
            for (int i = 0; i < 8; i++) Vt[(d0 + i) * 72 + chn] = v[i];
        }
        __syncthreads();

        f4v sc[4];
#pragma unroll
        for (int ni = 0; ni < 4; ni++) {
            s8v kf0 = *(const s8v*)(&Ks[(ni * 16 + l15) * 72 + quad * 8]);
            s8v kf1 = *(const s8v*)(&Ks[(ni * 16 + l15) * 72 + 32 + quad * 8]);
            f4v a = (f4v){0.f, 0.f, 0.f, 0.f};
            a = __builtin_amdgcn_mfma_f32_16x16x32_bf16(qf[0], kf0, a, 0, 0, 0);
            a = __builtin_amdgcn_mfma_f32_16x16x32_bf16(qf[1], kf1, a, 0, 0, 0);
            sc[ni] = a * 0.125f;
        }
        float alpha[4], rs[4];
#pragma unroll
        for (int r = 0; r < 4; r++) {
            float v = fmaxf(fmaxf(sc[0][r], sc[1][r]), fmaxf(sc[2][r], sc[3][r]));
            v = fmaxf(v, __shfl_xor(v, 1));
            v = fmaxf(v, __shfl_xor(v, 2));
            v = fmaxf(v, __shfl_xor(v, 4));
            v = fmaxf(v, __shfl_xor(v, 8));
            float mn = fmaxf(m_i[r], v);
            alpha[r] = __expf(m_i[r] - mn);
            m_i[r] = mn;
            rs[r] = 0.f;
        }
#pragma unroll
        for (int ni = 0; ni < 4; ni++)
#pragma unroll
            for (int r = 0; r < 4; r++) {
                float pv = __expf(sc[ni][r] - m_i[r]);
                sc[ni][r] = pv;
                rs[r] += pv;
            }
#pragma unroll
        for (int r = 0; r < 4; r++) {
            float v = rs[r];
            v += __shfl_xor(v, 1);
            v += __shfl_xor(v, 2);
            v += __shfl_xor(v, 4);
            v += __shfl_xor(v, 8);
            l_i[r] = l_i[r] * alpha[r] + v;
        }
#pragma unroll
        for (int ni = 0; ni < 4; ni++)
#pragma unroll
            for (int r = 0; r < 4; r++) {
                int row = quad * 4 + r;
                int key = ni * 16 + l15;
                int chn = ((key >> 3) ^ (row >> 3)) * 8 + (key & 7);
                Ps[wave][row * 72 + chn] = f2bf(sc[ni][r]);
            }
        __syncthreads();
#pragma unroll
        for (int ni = 0; ni < 4; ni++) {
            f4v t = o[ni];
            t[0] *= alpha[0]; t[1] *= alpha[1]; t[2] *= alpha[2]; t[3] *= alpha[3];
            o[ni] = t;
        }
        s8v pf0 = *(const s8v*)(&Ps[wave][l15 * 72 + ((quad ^ (l15 >> 3)) * 8)]);
        s8v pf1 = *(const s8v*)(&Ps[wave][l15 * 72 + (((4 + quad) ^ (l15 >> 3)) * 8)]);
#pragma unroll
        for (int ni = 0; ni < 4; ni++) {
            int d = ni * 16 + l15;
            s8v vf0 = *(const s8v*)(&Vt[d * 72 + ((quad ^ (d >> 3)) * 8)]);
            s8v vf1 = *(const s8v*)(&Vt[d * 72 + (((4 + quad) ^ (d >> 3)) * 8)]);
            o[ni] = __builtin_amdgcn_mfma_f32_16x16x32_bf16(pf0, vf0, o[ni], 0, 0, 0);
            o[ni] = __builtin_amdgcn_mfma_f32_16x16x32_bf16(pf1, vf1, o[ni], 0, 0, 0);
        }
    }
#pragma unroll
    for (int r = 0; r < 4; r++) {
        float inv = 1.0f / l_i[r];
        int srow = q0 + wave * 16 + quad * 4 + r;
        long obase = ((long)b * 2048 + srow) * 3072 + h * 64;
#pragma unroll
        for (int ni = 0; ni < 4; ni++)
            qkv[obase + ni * 16 + l15] = f2bf(o[ni][r] * inv);
    }
}

extern "C" void kernel_launch(void* const* d_in, const int* in_sizes, int n_in,
                              void* d_out, int out_size, void* d_ws, size_t ws_size,
                              hipStream_t stream) {
    (void)in_sizes; (void)n_in; (void)out_size;
    const float* x  = (const float*)d_in[0];
    const float* Wq = (const float*)d_in[1];
    const float* Wk = (const float*)d_in[2];
    const float* Wv = (const float*)d_in[3];
    const float* Wo = (const float*)d_in[4];

    const size_t need = 67108864ULL; // 64 MiB
    if (ws_size >= need) {
        short* xb    = (short*)d_ws;              // 4096x2048
        short* Wqkvt = xb + 8388608;              // 3072x2048
        short* Wot   = Wqkvt + 6291456;           // 2048x2048
        short* qkv   = Wot + 4194304;             // 4096x3072
        short* Vt_g  = qkv + 12582912;            // 16x64x2048

        cvt_x<<<4096, 256, 0, stream>>>(x, xb);
        cvt_wt<<<dim3(32, 32), 256, 0, stream>>>(Wq, Wqkvt, 2048, 0);
        cvt_wt<<<dim3(8, 32), 256, 0, stream>>>(Wk, Wqkvt, 512, 2048);
        cvt_wt<<<dim3(8, 32), 256, 0, stream>>>(Wv, Wqkvt, 512, 2560);
        cvt_wt<<<dim3(32, 32), 256, 0, stream>>>(Wo, Wot, 2048, 0);
        gemm_bt<false><<<dim3(24, 32), 256, 0, stream>>>(xb, Wqkvt, qkv, 2048, 2048, 2048, 3072);
        rope_kernel<<<dim3(20480), 256, 0, stream>>>(qkv);
        vtrans<<<dim3(32, 8, 2), 256, 0, stream>>>(qkv, Vt_g);
        attn4<<<dim3(16, 32, 2), 256, 0, stream>>>(qkv, Vt_g);
        gemm_bt<true><<<dim3(16, 32), 256, 0, stream>>>(qkv, Wot, d_out, 2048, 3072, 2048, 2048);
    } else {
        short* qkv = (short*)d_ws;
        gemm_bn<true, false><<<dim3(16, 32), 256, 0, stream>>>(x, Wq, qkv,        2048, 2048, 2048, 3072);
        gemm_bn<true, false><<<dim3(4, 32), 256, 0, stream>>>(x, Wk, qkv + 2048, 2048,  512, 2048, 3072);
        gemm_bn<true, false><<<dim3(4, 32), 256, 0, stream>>>(x, Wv, qkv + 2560, 2048,  512, 2048, 3072);
        rope_kernel<<<dim3(20480), 256, 0, stream>>>(qkv);
        attn_kernel<<<dim3(32, 32, 2), 256, 0, stream>>>(qkv);
        gemm_bn<false, true><<<dim3(16, 32), 256, 0, stream>>>(qkv, Wo, d_out, 2048, 2048, 3072, 2048);
    }
}

// Round 6
// 364.729 us; speedup vs baseline: 1.2279x; 1.0310x over previous
//
#include <hip/hip_runtime.h>

typedef short s8v __attribute__((ext_vector_type(8)));
typedef int i2v __attribute__((ext_vector_type(2)));
typedef float f2v __attribute__((ext_vector_type(2)));
typedef float f4v __attribute__((ext_vector_type(4)));

typedef const __attribute__((address_space(1))) char* gp1_t;
typedef __attribute__((address_space(3))) char* lp3_t;

__device__ __forceinline__ float bf2f(short s) {
    union { unsigned u; float f; } c;
    c.u = ((unsigned)(unsigned short)s) << 16;
    return c.f;
}
__device__ __forceinline__ short f2bf(float f) {
    union { float f; unsigned u; } c; c.f = f;
    unsigned r = (c.u + 0x7FFFu + ((c.u >> 16) & 1u)) >> 16;
    return (short)r;
}
__device__ __forceinline__ unsigned cvt_pk_bf16(float a, float b) {
    unsigned r;
    asm("v_cvt_pk_bf16_f32 %0, %1, %2" : "=v"(r) : "v"(a), "v"(b));
    return r;
}
__device__ __forceinline__ s8v cvt8(const float* __restrict__ p) {
    f4v a = *(const f4v*)p;
    f4v b = *(const f4v*)(p + 4);
    s8v r;
    r[0] = f2bf(a[0]); r[1] = f2bf(a[1]); r[2] = f2bf(a[2]); r[3] = f2bf(a[3]);
    r[4] = f2bf(b[0]); r[5] = f2bf(b[1]); r[6] = f2bf(b[2]); r[7] = f2bf(b[3]);
    return r;
}

// ======================= FAST PATH (ws >= 64 MiB) =======================

// fp32 -> bf16 straight copy (x)
__global__ __launch_bounds__(256) void cvt_x(const float* __restrict__ x,
                                             short* __restrict__ xb) {
    long i = ((long)blockIdx.x * 256 + threadIdx.x) * 8;
    *(s8v*)&xb[i] = cvt8(&x[i]);
}

// W (2048 x N fp32) -> Wt rows [obase+n][k] bf16 (ld 2048), scaled by `scale`
// (scale folds the attention 1/8 * log2(e) into Wk; rotation in RoPE commutes
// with scaling so k columns stay consistent).
__global__ __launch_bounds__(256) void cvt_wt(const float* __restrict__ W,
                                              short* __restrict__ Wt,
                                              int N, int obase, float scale) {
    __shared__ __align__(16) short tile[64 * 72];
    const int kt = blockIdx.y * 64, n0 = blockIdx.x * 64;
    const int t = threadIdx.x;
    const int r = t >> 4, c4 = (t & 15) * 4;
#pragma unroll
    for (int i = 0; i < 4; i++) {
        int kr = r + i * 16;
        f4v v = *(const f4v*)&W[(long)(kt + kr) * N + n0 + c4];
#pragma unroll
        for (int j = 0; j < 4; j++) tile[(c4 + j) * 72 + kr] = f2bf(v[j] * scale);
    }
    __syncthreads();
    const int nr = t >> 3, kc = (t & 7) * 8;
#pragma unroll
    for (int i = 0; i < 2; i++) {
        int n = nr + i * 32;
        *(s8v*)&Wt[(long)(obase + n0 + n) * 2048 + kt + kc] = *(const s8v*)&tile[n * 72 + kc];
    }
}

// m97-style GEMM: A (M x K bf16, stride lda), Bt (N x K bf16, stride ldb),
// C (M x N, stride ldc; fp32 or bf16). 128x128 tile, BK=32,
// global_load_lds width=16 staging, unpadded LDS tiles.
// XCD-bijective block swizzle (grid size divisible by 8).
template <bool CF32>
__global__ __launch_bounds__(256) void gemm_bt(const short* __restrict__ A,
                                               const short* __restrict__ Bt,
                                               void* __restrict__ Cv,
                                               int K, int lda, int ldb, int ldc) {
    __shared__ __align__(16) short As[128 * 32];
    __shared__ __align__(16) short Bs[128 * 32];
    const int tid = threadIdx.x;
    const int lane = tid & 63;
    const int wave = tid >> 6;
    const int quad = lane >> 4;
    const int l15 = lane & 15;

    // XCD swizzle: XCD x owns a contiguous chunk of tile ids
    const int nwg = gridDim.x * gridDim.y;
    int f = blockIdx.y * gridDim.x + blockIdx.x;
    if ((nwg & 7) == 0) f = (f & 7) * (nwg >> 3) + (f >> 3);
    const int m0 = (f / gridDim.x) * 128;
    const int n0 = (f % gridDim.x) * 128;

    const int wm = (wave & 1) * 64;
    const int wn = (wave >> 1) * 64;

    f4v acc[4][4];
#pragma unroll
    for (int i = 0; i < 4; i++)
#pragma unroll
        for (int j = 0; j < 4; j++) acc[i][j] = (f4v){0.f, 0.f, 0.f, 0.f};

    const int s0 = wave * 64 + lane, s1 = (4 + wave) * 64 + lane;
    const short* a0 = A + (long)(m0 + (s0 >> 2)) * lda + (s0 & 3) * 8;
    const short* a1 = A + (long)(m0 + (s1 >> 2)) * lda + (s1 & 3) * 8;
    const short* b0 = Bt + (long)(n0 + (s0 >> 2)) * ldb + (s0 & 3) * 8;
    const short* b1 = Bt + (long)(n0 + (s1 >> 2)) * ldb + (s1 & 3) * 8;
    char* lA0 = (char*)As + wave * 1024;
    char* lA1 = (char*)As + (4 + wave) * 1024;
    char* lB0 = (char*)Bs + wave * 1024;
    char* lB1 = (char*)Bs + (4 + wave) * 1024;

    for (int k0 = 0; k0 < K; k0 += 32) {
        __syncthreads();
        __builtin_amdgcn_global_load_lds((gp1_t)(a0 + k0), (lp3_t)lA0, 16, 0, 0);
        __builtin_amdgcn_global_load_lds((gp1_t)(a1 + k0), (lp3_t)lA1, 16, 0, 0);
        __builtin_amdgcn_global_load_lds((gp1_t)(b0 + k0), (lp3_t)lB0, 16, 0, 0);
        __builtin_amdgcn_global_load_lds((gp1_t)(b1 + k0), (lp3_t)lB1, 16, 0, 0);
        __syncthreads();
        s8v af[4], bfr[4];
#pragma unroll
        for (int mi = 0; mi < 4; mi++)
            af[mi] = *(const s8v*)(&As[(wm + mi * 16 + l15) * 32 + quad * 8]);
#pragma unroll
        for (int ni = 0; ni < 4; ni++)
            bfr[ni] = *(const s8v*)(&Bs[(wn + ni * 16 + l15) * 32 + quad * 8]);
#pragma unroll
        for (int mi = 0; mi < 4; mi++)
#pragma unroll
            for (int ni = 0; ni < 4; ni++)
                acc[mi][ni] = __builtin_amdgcn_mfma_f32_16x16x32_bf16(af[mi], bfr[ni], acc[mi][ni], 0, 0, 0);
    }
#pragma unroll
    for (int mi = 0; mi < 4; mi++)
#pragma unroll
        for (int ni = 0; ni < 4; ni++)
#pragma unroll
            for (int r = 0; r < 4; r++) {
                int row = m0 + wm + mi * 16 + quad * 4 + r;
                int col = n0 + wn + ni * 16 + l15;
                if (CF32) ((float*)Cv)[(long)row * ldc + col] = acc[mi][ni][r];
                else      ((short*)Cv)[(long)row * ldc + col] = f2bf(acc[mi][ni][r]);
            }
}

// RoPE in-place on qkv cols [0,2560)
__global__ __launch_bounds__(256) void rope_kernel(short* __restrict__ qkv) {
    int tid = blockIdx.x * 256 + threadIdx.x;
    int p = tid % 1280;
    int row = tid / 1280;
    int head = p >> 5;
    int j = p & 31;
    int s = row & 2047;
    int c1 = head * 64 + j;
    float freq = exp2f(-(float)j * 0.4152410118609203f); // log2(10000)/32
    float ang = (float)s * freq;
    float sn, cs;
    __sincosf(ang, &sn, &cs);
    long base = (long)row * 3072;
    float x1 = bf2f(qkv[base + c1]);
    float x2 = bf2f(qkv[base + c1 + 32]);
    qkv[base + c1]      = f2bf(x1 * cs - x2 * sn);
    qkv[base + c1 + 32] = f2bf(x2 * cs + x1 * sn);
}

// V transpose (round-0 verified): qkv v-region -> Vt_g[(b*8+kvh)*64 + d][key] (ld 2048)
__global__ __launch_bounds__(256) void vtrans(const short* __restrict__ qkv,
                                              short* __restrict__ Vt_g) {
    __shared__ __align__(16) short tile[64 * 72];
    const int kt = blockIdx.x * 64;
    const int kvh = blockIdx.y;
    const int b = blockIdx.z;
    const int t = threadIdx.x;
#pragma unroll
    for (int cc = 0; cc < 2; cc++) {
        int ch = t + cc * 256;
        int key = ch >> 3, d0 = (ch & 7) * 8;
        s8v v = *(const s8v*)&qkv[(long)(b * 2048 + kt + key) * 3072 + 2560 + kvh * 64 + d0];
#pragma unroll
        for (int i = 0; i < 8; i++) tile[(d0 + i) * 72 + key] = v[i];
    }
    __syncthreads();
#pragma unroll
    for (int cc = 0; cc < 2; cc++) {
        int ch = t + cc * 256;
        int d = ch >> 3, kc = (ch & 7) * 8;
        *(s8v*)&Vt_g[(long)((b * 8 + kvh) * 64 + d) * 2048 + kt + kc] = *(const s8v*)&tile[d * 72 + kc];
    }
}

// Flash attention v4.2:
//  - K pre-scaled by 0.125*log2(e) (folded into Wk); QK^T accumulator
//    initialized to -24 so p = exp2f(score) directly (no fma in the loop)
//  - swapped QK^T (mfma(K,Q)); P packed via v_cvt_pk_bf16_f32, routed through
//    per-wave LDS (b64 writes, b128 fragment reads), stride 72
//  - plain pretransposed V, K/V double-buffered via global_load_lds with
//    XOR-pre-swizzled SOURCE (linear LDS dest), one barrier per tile
//  - rs accumulated as float2 (v_pk_add_f32), broadcast via LDS
//  - 4 waves x 32 q-rows (128 q/block); XCD-swizzled grid (16, 32, 2).
__global__ __launch_bounds__(256, 3) void attn4(short* __restrict__ qkv,
                                                const short* __restrict__ Vt_g) {
    __shared__ __align__(16) short KV[2][2][4096];   // [buf][K/V][64*64]
    __shared__ __align__(16) short Ps[4][2][16 * 72];
    __shared__ float rsb[4][32];

    const int tid = threadIdx.x;
    const int lane = tid & 63;
    const int wave = tid >> 6;
    const int quad = lane >> 4;
    const int l15 = lane & 15;

    // XCD swizzle: 1024 blocks; XCD x owns 128 consecutive flat ids
    // (z-major flat id => 64-block (b,kvh) groups stay on one XCD's L2)
    int f = (blockIdx.z * 32 + blockIdx.y) * 16 + blockIdx.x;
    f = (f & 7) * 128 + (f >> 3);
    const int b = f >> 9;
    const int h = (f >> 4) & 31;
    const int kvh = h >> 2;
    const int q0 = (f & 15) * 128;

    const long kbase = ((long)b * 2048) * 3072 + 2048 + kvh * 64;
    const long vtbase = (long)(b * 8 + kvh) * 64 * 2048;

    // Q fragments direct from global (once per block); q rows wave*32+l15 and +16
    const long qrow = (long)b * 2048 + q0 + wave * 32 + l15;
    const short* qp = qkv + qrow * 3072 + h * 64 + quad * 8;
    const s8v qf00 = *(const s8v*)(qp);
    const s8v qf01 = *(const s8v*)(qp + 32);
    const s8v qf10 = *(const s8v*)(qp + 16 * 3072);
    const s8v qf11 = *(const s8v*)(qp + 16 * 3072 + 32);

    // staging: lane writes LDS row wave*8+(lane>>3), pos lane&7;
    // source chunk pre-swizzled: sslot = (lane&7) ^ (lane>>3)
    const int rA = wave * 8 + (lane >> 3);
    const int sslot = (lane & 7) ^ (lane >> 3);
    const short* kA = qkv + kbase + (long)rA * 3072 + sslot * 8;
    const short* kB = kA + (long)32 * 3072;
    const short* vA = Vt_g + vtbase + (long)rA * 2048 + sslot * 8;
    const short* vB = vA + (long)32 * 2048;

    // prologue: stage tile 0 into buf 0
    {
        char* kd = (char*)&KV[0][0][0] + wave * 1024;
        char* vd = (char*)&KV[0][1][0] + wave * 1024;
        __builtin_amdgcn_global_load_lds((gp1_t)kA, (lp3_t)kd, 16, 0, 0);
        __builtin_amdgcn_global_load_lds((gp1_t)kB, (lp3_t)(kd + 4096), 16, 0, 0);
        __builtin_amdgcn_global_load_lds((gp1_t)vA, (lp3_t)vd, 16, 0, 0);
        __builtin_amdgcn_global_load_lds((gp1_t)vB, (lp3_t)(vd + 4096), 16, 0, 0);
    }
    __syncthreads();

    // swizzled read offsets (shorts): LDS pos (quad^(row&7)) holds content chunk quad
    const int ks0 = ((quad ^ (l15 & 7)) << 3);
    const int ks1 = ks0 ^ 32;

    f2v rs0v = (f2v){0.f, 0.f}, rs1v = (f2v){0.f, 0.f};
    f4v o0[4], o1[4];
#pragma unroll
    for (int ni = 0; ni < 4; ni++) { o0[ni] = (f4v){0.f, 0.f, 0.f, 0.f}; o1[ni] = (f4v){0.f, 0.f, 0.f, 0.f}; }

    short* Pw0 = &Ps[wave][0][0];
    short* Pw1 = &Ps[wave][1][0];

    for (int t = 0; t < 32; ++t) {
        const short* Kb = &KV[t & 1][0][0];
        const short* Vb = &KV[t & 1][1][0];

        if (t < 31) {
            const long ko = (long)(t + 1) * (64 * 3072);
            const long vo = (long)(t + 1) * 64;
            char* kd = (char*)&KV[(t + 1) & 1][0][0] + wave * 1024;
            char* vd = (char*)&KV[(t + 1) & 1][1][0] + wave * 1024;
            __builtin_amdgcn_global_load_lds((gp1_t)(kA + ko), (lp3_t)kd, 16, 0, 0);
            __builtin_amdgcn_global_load_lds((gp1_t)(kB + ko), (lp3_t)(kd + 4096), 16, 0, 0);
            __builtin_amdgcn_global_load_lds((gp1_t)(vA + vo), (lp3_t)vd, 16, 0, 0);
            __builtin_amdgcn_global_load_lds((gp1_t)(vB + vo), (lp3_t)(vd + 4096), 16, 0, 0);
        }

        // QK^T swapped: lane (quad,l15) reg r holds CS*S - 24 for
        // key = ni*16+quad*4+r, q = l15 (K pre-scaled, acc pre-biased)
#pragma unroll
        for (int ni = 0; ni < 4; ni++) {
            const int ro = (ni * 16 + l15) * 64;
            const s8v kf0 = *(const s8v*)&Kb[ro + ks0];
            const s8v kf1 = *(const s8v*)&Kb[ro + ks1];
            f4v a = (f4v){-24.f, -24.f, -24.f, -24.f};
            a = __builtin_amdgcn_mfma_f32_16x16x32_bf16(kf0, qf00, a, 0, 0, 0);
            a = __builtin_amdgcn_mfma_f32_16x16x32_bf16(kf1, qf01, a, 0, 0, 0);
            {
                float p0 = exp2f(a[0]);
                float p1 = exp2f(a[1]);
                float p2 = exp2f(a[2]);
                float p3 = exp2f(a[3]);
                rs0v += (f2v){p0, p1};
                rs0v += (f2v){p2, p3};
                *(i2v*)&Pw0[l15 * 72 + ni * 16 + quad * 4] =
                    (i2v){(int)cvt_pk_bf16(p0, p1), (int)cvt_pk_bf16(p2, p3)};
            }
            f4v c = (f4v){-24.f, -24.f, -24.f, -24.f};
            c = __builtin_amdgcn_mfma_f32_16x16x32_bf16(kf0, qf10, c, 0, 0, 0);
            c = __builtin_amdgcn_mfma_f32_16x16x32_bf16(kf1, qf11, c, 0, 0, 0);
            {
                float p0 = exp2f(c[0]);
                float p1 = exp2f(c[1]);
                float p2 = exp2f(c[2]);
                float p3 = exp2f(c[3]);
                rs1v += (f2v){p0, p1};
                rs1v += (f2v){p2, p3};
                *(i2v*)&Pw1[l15 * 72 + ni * 16 + quad * 4] =
                    (i2v){(int)cvt_pk_bf16(p0, p1), (int)cvt_pk_bf16(p2, p3)};
            }
        }

        // PV: A = P[q rows][keys] from LDS, B = V[key][dim] fragments
        const s8v pf00 = *(const s8v*)&Pw0[l15 * 72 + quad * 8];
        const s8v pf01 = *(const s8v*)&Pw0[l15 * 72 + 32 + quad * 8];
        const s8v pf10 = *(const s8v*)&Pw1[l15 * 72 + quad * 8];
        const s8v pf11 = *(const s8v*)&Pw1[l15 * 72 + 32 + quad * 8];
#pragma unroll
        for (int ni = 0; ni < 4; ni++) {
            const int ro = (ni * 16 + l15) * 64;
            const s8v vf0 = *(const s8v*)&Vb[ro + ks0];
            const s8v vf1 = *(const s8v*)&Vb[ro + ks1];
            o0[ni] = __builtin_amdgcn_mfma_f32_16x16x32_bf16(pf00, vf0, o0[ni], 0, 0, 0);
            o0[ni] = __builtin_amdgcn_mfma_f32_16x16x32_bf16(pf01, vf1, o0[ni], 0, 0, 0);
            o1[ni] = __builtin_amdgcn_mfma_f32_16x16x32_bf16(pf10, vf0, o1[ni], 0, 0, 0);
            o1[ni] = __builtin_amdgcn_mfma_f32_16x16x32_bf16(pf11, vf1, o1[ni], 0, 0, 0);
        }
        __syncthreads();
    }

    // rs: per-lane partial (16 keys) for q = l15; reduce over quads, broadcast via LDS
    float rs0 = rs0v[0] + rs0v[1];
    float rs1 = rs1v[0] + rs1v[1];
    rs0 += __shfl_xor(rs0, 16); rs0 += __shfl_xor(rs0, 32);
    rs1 += __shfl_xor(rs1, 16); rs1 += __shfl_xor(rs1, 32);
    if (quad == 0) { rsb[wave][l15] = rs0; rsb[wave][16 + l15] = rs1; }
    __syncthreads();

#pragma unroll
    for (int r = 0; r < 4; r++) {
        const float i0 = 1.0f / rsb[wave][quad * 4 + r];
        const float i1 = 1.0f / rsb[wave][16 + quad * 4 + r];
        const long ob0 = ((long)b * 2048 + q0 + wave * 32 + quad * 4 + r) * 3072 + h * 64;
        const long ob1 = ob0 + 16 * 3072;
#pragma unroll
        for (int ni = 0; ni < 4; ni++) {
            qkv[ob0 + ni * 16 + l15] = f2bf(o0[ni][r] * i0);
            qkv[ob1 + ni * 16 + l15] = f2bf(o1[ni][r] * i1);
        }
    }
}

// ======================= FALLBACK PATH (round-6, known-PASS) =======================

template <bool AF32, bool CF32>
__global__ __launch_bounds__(256) void gemm_bn(const void* __restrict__ Av,
                                               const float* __restrict__ B,
                                               void* __restrict__ Cv,
                                               int K, int N, int lda, int ldc) {
    __shared__ __align__(16) short As[128 * 40];
    __shared__ __align__(16) short Bs[128 * 40];
    const int tid = threadIdx.x;
    const int lane = tid & 63;
    const int wave = tid >> 6;
    const int quad = lane >> 4;
    const int l15 = lane & 15;
    const int m0 = blockIdx.y * 128;
    const int n0 = blockIdx.x * 128;
    const int wm = (wave & 1) * 64;
    const int wn = (wave >> 1) * 64;

    f4v acc[4][4];
#pragma unroll
    for (int i = 0; i < 4; i++)
#pragma unroll
        for (int j = 0; j < 4; j++) acc[i][j] = (f4v){0.f, 0.f, 0.f, 0.f};

    const int ar0 = tid >> 2, akc0 = (tid & 3) * 8;
    const int ar1 = (tid + 256) >> 2, akc1 = ((tid + 256) & 3) * 8;
    const int bk0 = tid >> 4, bnc0 = (tid & 15) * 8;
    const int bk1 = (tid + 256) >> 4, bnc1 = ((tid + 256) & 15) * 8;

    for (int k0 = 0; k0 < K; k0 += 32) {
        __syncthreads();
        if (AF32) {
            const float* A = (const float*)Av;
            *(s8v*)(&As[ar0 * 40 + akc0]) = cvt8(&A[(long)(m0 + ar0) * lda + k0 + akc0]);
            *(s8v*)(&As[ar1 * 40 + akc1]) = cvt8(&A[(long)(m0 + ar1) * lda + k0 + akc1]);
        } else {
            const short* A = (const short*)Av;
            *(s8v*)(&As[ar0 * 40 + akc0]) = *(const s8v*)(&A[(long)(m0 + ar0) * lda + k0 + akc0]);
            *(s8v*)(&As[ar1 * 40 + akc1]) = *(const s8v*)(&A[(long)(m0 + ar1) * lda + k0 + akc1]);
        }
        s8v b0 = cvt8(&B[(long)(k0 + bk0) * N + n0 + bnc0]);
        s8v b1 = cvt8(&B[(long)(k0 + bk1) * N + n0 + bnc1]);
#pragma unroll
        for (int i = 0; i < 8; i++) Bs[(bnc0 + i) * 40 + bk0] = b0[i];
#pragma unroll
        for (int i = 0; i < 8; i++) Bs[(bnc1 + i) * 40 + bk1] = b1[i];
        __syncthreads();
        s8v af[4], bfr[4];
#pragma unroll
        for (int mi = 0; mi < 4; mi++)
            af[mi] = *(const s8v*)(&As[(wm + mi * 16 + l15) * 40 + quad * 8]);
#pragma unroll
        for (int ni = 0; ni < 4; ni++)
            bfr[ni] = *(const s8v*)(&Bs[(wn + ni * 16 + l15) * 40 + quad * 8]);
#pragma unroll
        for (int mi = 0; mi < 4; mi++)
#pragma unroll
            for (int ni = 0; ni < 4; ni++)
                acc[mi][ni] = __builtin_amdgcn_mfma_f32_16x16x32_bf16(af[mi], bfr[ni], acc[mi][ni], 0, 0, 0);
    }
#pragma unroll
    for (int mi = 0; mi < 4; mi++)
#pragma unroll
        for (int ni = 0; ni < 4; ni++)
#pragma unroll
            for (int r = 0; r < 4; r++) {
                int row = m0 + wm + mi * 16 + quad * 4 + r;
                int col = n0 + wn + ni * 16 + l15;
                if (CF32) ((float*)Cv)[(long)row * ldc + col] = acc[mi][ni][r];
                else      ((short*)Cv)[(long)row * ldc + col] = f2bf(acc[mi][ni][r]);
            }
}

__global__ __launch_bounds__(256) void attn_kernel(short* __restrict__ qkv) {
    __shared__ __align__(16) short Qs[64 * 72];
    __shared__ __align__(16) short Ks[64 * 72];
    __shared__ __align__(16) short Vt[64 * 72];
    __shared__ __align__(16) short Ps[4][16 * 72];

    const int tid = threadIdx.x;
    const int lane = tid & 63;
    const int wave = tid >> 6;
    const int quad = lane >> 4;
    const int l15 = lane & 15;
    const int b = blockIdx.z;
    const int h = blockIdx.y;
    const int kvh = h >> 2;
    const int q0 = blockIdx.x * 64;

    const long qbase = ((long)b * 2048 + q0) * 3072 + h * 64;
    const long kbase = ((long)b * 2048) * 3072 + 2048 + kvh * 64;
    const long vbase = kbase + 512;

#pragma unroll
    for (int cc = 0; cc < 2; cc++) {
        int ch = tid + cc * 256;
        int r = ch >> 3, d0 = (ch & 7) * 8;
        *(s8v*)(&Qs[r * 72 + d0]) = *(const s8v*)(&qkv[qbase + (long)r * 3072 + d0]);
    }
    __syncthreads();
    s8v qf[2];
    qf[0] = *(const s8v*)(&Qs[(wave * 16 + l15) * 72 + quad * 8]);
    qf[1] = *(const s8v*)(&Qs[(wave * 16 + l15) * 72 + 32 + quad * 8]);

    float m_i[4], l_i[4];
    f4v o[4];
#pragma unroll
    for (int r = 0; r < 4; r++) { m_i[r] = -1e30f; l_i[r] = 0.0f; }
#pragma unroll
    for (int ni = 0; ni < 4; ni++) o[ni] = (f4v){0.f, 0.f, 0.f, 0.f};

    for (int kt = 0; kt < 2048; kt += 64) {
        __syncthreads();
#pragma unroll
        for (int cc = 0; cc < 2; cc++) {
            int ch = tid + cc * 256;
            int r = ch >> 3, d0 = (ch & 7) * 8;
            *(s8v*)(&Ks[r * 72 + d0]) = *(const s8v*)(&qkv[kbase + (long)(kt + r) * 3072 + d0]);
            s8v v = *(const s8v*)(&qkv[vbase + (long)(kt + r) * 3072 + d0]);
            int g = d0 >> 3;
            int chn = ((r >> 3) ^ g) * 8 + (r & 7);
#pragma unroll
            for (int i = 0; i < 8; i++) Vt[(d0 + i) * 72 + chn] = v[i];
        }
        __syncthreads();

        f4v sc[4];
#pragma unroll
        for (int ni = 0; ni < 4; ni++) {
            s8v kf0 = *(const s8v*)(&Ks[(ni * 16 + l15) * 72 + quad * 8]);
            s8v kf1 = *(const s8v*)(&Ks[(ni * 16 + l15) * 72 + 32 + quad * 8]);
            f4v a = (f4v){0.f, 0.f, 0.f, 0.f};
            a = __builtin_amdgcn_mfma_f32_16x16x32_bf16(qf[0], kf0, a, 0, 0, 0);
            a = __builtin_amdgcn_mfma_f32_16x16x32_bf16(qf[1], kf1, a, 0, 0, 0);
            sc[ni] = a * 0.125f;
        }
        float alpha[4], rs[4];
#pragma unroll
        for (int r = 0; r < 4; r++) {
            float v = fmaxf(fmaxf(sc[0][r], sc[1][r]), fmaxf(sc[2][r], sc[3][r]));
            v = fmaxf(v, __shfl_xor(v, 1));
            v = fmaxf(v, __shfl_xor(v, 2));
            v = fmaxf(v, __shfl_xor(v, 4));
            v = fmaxf(v, __shfl_xor(v, 8));
            float mn = fmaxf(m_i[r], v);
            alpha[r] = __expf(m_i[r] - mn);
            m_i[r] = mn;
            rs[r] = 0.f;
        }
#pragma unroll
        for (int ni = 0; ni < 4; ni++)
#pragma unroll
            for (int r = 0; r < 4; r++) {
                float pv = __expf(sc[ni][r] - m_i[r]);
                sc[ni][r] = pv;
                rs[r] += pv;
            }
#pragma unroll
        for (int r = 0; r < 4; r++) {
            float v = rs[r];
            v += __shfl_xor(v, 1);
            v += __shfl_xor(v, 2);
            v += __shfl_xor(v, 4);
            v += __shfl_xor(v, 8);
            l_i[r] = l_i[r] * alpha[r] + v;
        }
#pragma unroll
        for (int ni = 0; ni < 4; ni++)
#pragma unroll
            for (int r = 0; r < 4; r++) {
                int row = quad * 4 + r;
                int key = ni * 16 + l15;
                int chn = ((key >> 3) ^ (row >> 3)) * 8 + (key & 7);
                Ps[wave][row * 72 + chn] = f2bf(sc[ni][r]);
            }
        __syncthreads();
#pragma unroll
        for (int ni = 0; ni < 4; ni++) {
            f4v t = o[ni];
            t[0] *= alpha[0]; t[1] *= alpha[1]; t[2] *= alpha[2]; t[3] *= alpha[3];
            o[ni] = t;
        }
        s8v pf0 = *(const s8v*)(&Ps[wave][l15 * 72 + ((quad ^ (l15 >> 3)) * 8)]);
        s8v pf1 = *(const s8v*)(&Ps[wave][l15 * 72 + (((4 + quad) ^ (l15 >> 3)) * 8)]);
#pragma unroll
        for (int ni = 0; ni < 4; ni++) {
            int d = ni * 16 + l15;
            s8v vf0 = *(const s8v*)(&Vt[d * 72 + ((quad ^ (d >> 3)) * 8)]);
            s8v vf1 = *(const s8v*)(&Vt[d * 72 + (((4 + quad) ^ (d >> 3)) * 8)]);
            o[ni] = __builtin_amdgcn_mfma_f32_16x16x32_bf16(pf0, vf0, o[ni], 0, 0, 0);
            o[ni] = __builtin_amdgcn_mfma_f32_16x16x32_bf16(pf1, vf1, o[ni], 0, 0, 0);
        }
    }
#pragma unroll
    for (int r = 0; r < 4; r++) {
        float inv = 1.0f / l_i[r];
        int srow = q0 + wave * 16 + quad * 4 + r;
        long obase = ((long)b * 2048 + srow) * 3072 + h * 64;
#pragma unroll
        for (int ni = 0; ni < 4; ni++)
            qkv[obase + ni * 16 + l15] = f2bf(o[ni][r] * inv);
    }
}

extern "C" void kernel_launch(void* const* d_in, const int* in_sizes, int n_in,
                              void* d_out, int out_size, void* d_ws, size_t ws_size,
                              hipStream_t stream) {
    (void)in_sizes; (void)n_in; (void)out_size;
    const float* x  = (const float*)d_in[0];
    const float* Wq = (const float*)d_in[1];
    const float* Wk = (const float*)d_in[2];
    const float* Wv = (const float*)d_in[3];
    const float* Wo = (const float*)d_in[4];

    const float CS = 0.18033688011112042f;   // 0.125 * log2(e), folded into Wk
    const size_t need = 67108864ULL; // 64 MiB
    if (ws_size >= need) {
        short* xb    = (short*)d_ws;              // 4096x2048
        short* Wqkvt = xb + 8388608;              // 3072x2048
        short* Wot   = Wqkvt + 6291456;           // 2048x2048
        short* qkv   = Wot + 4194304;             // 4096x3072
        short* Vt_g  = qkv + 12582912;            // 16x64x2048

        cvt_x<<<4096, 256, 0, stream>>>(x, xb);
        cvt_wt<<<dim3(32, 32), 256, 0, stream>>>(Wq, Wqkvt, 2048, 0, 1.0f);
        cvt_wt<<<dim3(8, 32), 256, 0, stream>>>(Wk, Wqkvt, 512, 2048, CS);
        cvt_wt<<<dim3(8, 32), 256, 0, stream>>>(Wv, Wqkvt, 512, 2560, 1.0f);
        cvt_wt<<<dim3(32, 32), 256, 0, stream>>>(Wo, Wot, 2048, 0, 1.0f);
        gemm_bt<false><<<dim3(24, 32), 256, 0, stream>>>(xb, Wqkvt, qkv, 2048, 2048, 2048, 3072);
        rope_kernel<<<dim3(20480), 256, 0, stream>>>(qkv);
        vtrans<<<dim3(32, 8, 2), 256, 0, stream>>>(qkv, Vt_g);
        attn4<<<dim3(16, 32, 2), 256, 0, stream>>>(qkv, Vt_g);
        gemm_bt<true><<<dim3(16, 32), 256, 0, stream>>>(qkv, Wot, d_out, 2048, 3072, 2048, 2048);
    } else {
        short* qkv = (short*)d_ws;
        gemm_bn<true, false><<<dim3(16, 32), 256, 0, stream>>>(x, Wq, qkv,        2048, 2048, 2048, 3072);
        gemm_bn<true, false><<<dim3(4, 32), 256, 0, stream>>>(x, Wk, qkv + 2048, 2048,  512, 2048, 3072);
        gemm_bn<true, false><<<dim3(4, 32), 256, 0, stream>>>(x, Wv, qkv + 2560, 2048,  512, 2048, 3072);
        rope_kernel<<<dim3(20480), 256, 0, stream>>>(qkv);
        attn_kernel<<<dim3(32, 32, 2), 256, 0, stream>>>(qkv);
        gemm_bn<false, true><<<dim3(16, 32), 256, 0, stream>>>(qkv, Wo, d_out, 2048, 2048, 3072, 2048);
    }
}

// Round 8
// 357.257 us; speedup vs baseline: 1.2536x; 1.0209x over previous
//
#include <hip/hip_runtime.h>

typedef short s8v __attribute__((ext_vector_type(8)));
typedef int i2v __attribute__((ext_vector_type(2)));
typedef float f2v __attribute__((ext_vector_type(2)));
typedef float f4v __attribute__((ext_vector_type(4)));

typedef const __attribute__((address_space(1))) char* gp1_t;
typedef __attribute__((address_space(3))) char* lp3_t;

__device__ __forceinline__ float bf2f(short s) {
    union { unsigned u; float f; } c;
    c.u = ((unsigned)(unsigned short)s) << 16;
    return c.f;
}
__device__ __forceinline__ short f2bf(float f) {
    union { float f; unsigned u; } c; c.f = f;
    unsigned r = (c.u + 0x7FFFu + ((c.u >> 16) & 1u)) >> 16;
    return (short)r;
}
__device__ __forceinline__ unsigned cvt_pk_bf16(float a, float b) {
    unsigned r;
    asm("v_cvt_pk_bf16_f32 %0, %1, %2" : "=v"(r) : "v"(a), "v"(b));
    return r;
}
__device__ __forceinline__ s8v cvt8(const float* __restrict__ p) {
    f4v a = *(const f4v*)p;
    f4v b = *(const f4v*)(p + 4);
    s8v r;
    r[0] = f2bf(a[0]); r[1] = f2bf(a[1]); r[2] = f2bf(a[2]); r[3] = f2bf(a[3]);
    r[4] = f2bf(b[0]); r[5] = f2bf(b[1]); r[6] = f2bf(b[2]); r[7] = f2bf(b[3]);
    return r;
}

// ======================= FAST PATH (ws >= 64 MiB) =======================

// fp32 -> bf16 straight copy (x)
__global__ __launch_bounds__(256) void cvt_x(const float* __restrict__ x,
                                             short* __restrict__ xb) {
    long i = ((long)blockIdx.x * 256 + threadIdx.x) * 8;
    *(s8v*)&xb[i] = cvt8(&x[i]);
}

// W (2048 x N fp32) -> Wt rows [obase+n][k] bf16 (ld 2048), scaled by `scale`
__global__ __launch_bounds__(256) void cvt_wt(const float* __restrict__ W,
                                              short* __restrict__ Wt,
                                              int N, int obase, float scale) {
    __shared__ __align__(16) short tile[64 * 72];
    const int kt = blockIdx.y * 64, n0 = blockIdx.x * 64;
    const int t = threadIdx.x;
    const int r = t >> 4, c4 = (t & 15) * 4;
#pragma unroll
    for (int i = 0; i < 4; i++) {
        int kr = r + i * 16;
        f4v v = *(const f4v*)&W[(long)(kt + kr) * N + n0 + c4];
#pragma unroll
        for (int j = 0; j < 4; j++) tile[(c4 + j) * 72 + kr] = f2bf(v[j] * scale);
    }
    __syncthreads();
    const int nr = t >> 3, kc = (t & 7) * 8;
#pragma unroll
    for (int i = 0; i < 2; i++) {
        int n = nr + i * 32;
        *(s8v*)&Wt[(long)(obase + n0 + n) * 2048 + kt + kc] = *(const s8v*)&tile[n * 72 + kc];
    }
}

// ================== 256x256 8-phase GEMM (T2+T3+T4+T5) ==================
// A (M x K bf16, stride lda), Bt (N x K bf16, stride ldb), C (M x N).
// BK=64, 512 threads (8 waves, 2M x 4N), per-wave 128x64 output.
// LDS 128 KiB: A/B tiles [256][64] double-buffered, slot^(row&7) swizzle
// with pre-swizzled global source (linear LDS dest).
// Schedule per K-tile t (reading buf[t&1]):
//   phase1: ds_read A(qm0)+B(qn0); issue T(t+1).A1 (buf nxt); 16 MFMA; bar
//   phase2: ds_read B(qn1);                                   16 MFMA; bar
//   phase3: ds_read A(qm1); issue T(t+2).B0 (buf cur, B reads done ph2);
//                                                             16 MFMA; bar
//   phase4: issue T(t+2).B1 + T(t+2).A0 (A reads done ph3);   16 MFMA;
//           vmcnt(6) [3 half-tiles in flight] (vmcnt(0) before last tile); bar
// NT must be >= 2.
template <bool CF32>
__global__ __launch_bounds__(512, 2) void gemm_bt8(const short* __restrict__ A,
                                                   const short* __restrict__ Bt,
                                                   void* __restrict__ Cv,
                                                   int K, int lda, int ldb, int ldc) {
    __shared__ __align__(16) short Ab[2][16384];   // [buf][256*64]
    __shared__ __align__(16) short Bb[2][16384];

    const int tid = threadIdx.x;
    const int lane = tid & 63;
    const int wave = tid >> 6;
    const int quad = lane >> 4;
    const int l15 = lane & 15;

    // XCD-bijective block swizzle (grid %8 == 0)
    const int nwg = gridDim.x * gridDim.y;
    int f = blockIdx.y * gridDim.x + blockIdx.x;
    if ((nwg & 7) == 0) f = (f & 7) * (nwg >> 3) + (f >> 3);
    const int m0 = (f / gridDim.x) * 256;
    const int n0 = (f % gridDim.x) * 256;

    const int wm = (wave >> 2) * 128;   // 0 or 128
    const int wn = (wave & 3) * 64;     // 0,64,128,192

    // staging geometry: lane covers row base + (lane>>3), stored slot lane&7,
    // source slot pre-swizzled so LDS pos p of row r holds chunk p^(r&7)
    const int rsub = lane >> 3;
    const int sslot = (lane & 7) ^ rsub;
    const short* aS[2][2];
    const short* bS[2][2];
#pragma unroll
    for (int h = 0; h < 2; h++)
#pragma unroll
        for (int i = 0; i < 2; i++) {
            int row = h * 128 + wave * 16 + i * 8 + rsub;
            aS[h][i] = A  + (long)(m0 + row) * lda + sslot * 8;
            bS[h][i] = Bt + (long)(n0 + row) * ldb + sslot * 8;
        }

    auto stageA = [&](int buf, int h, int kt) {
        char* d = (char*)&Ab[buf][0] + h * 16384 + wave * 2048;
        __builtin_amdgcn_global_load_lds((gp1_t)(aS[h][0] + (long)kt * 64), (lp3_t)d, 16, 0, 0);
        __builtin_amdgcn_global_load_lds((gp1_t)(aS[h][1] + (long)kt * 64), (lp3_t)(d + 1024), 16, 0, 0);
    };
    auto stageB = [&](int buf, int h, int kt) {
        char* d = (char*)&Bb[buf][0] + h * 16384 + wave * 2048;
        __builtin_amdgcn_global_load_lds((gp1_t)(bS[h][0] + (long)kt * 64), (lp3_t)d, 16, 0, 0);
        __builtin_amdgcn_global_load_lds((gp1_t)(bS[h][1] + (long)kt * 64), (lp3_t)(d + 1024), 16, 0, 0);
    };

    // swizzled read slots (shorts offset): chunk c at pos c^(row&7), row&7 = l15&7
    const int ks0 = (quad ^ (l15 & 7)) * 8;
    const int ks1 = ks0 ^ 32;

    f4v acc[2][4][2][2];   // [qm][mi][qn][ni]
#pragma unroll
    for (int a = 0; a < 2; a++)
#pragma unroll
        for (int b = 0; b < 4; b++)
#pragma unroll
            for (int c = 0; c < 2; c++)
#pragma unroll
                for (int d = 0; d < 2; d++) acc[a][b][c][d] = (f4v){0.f, 0.f, 0.f, 0.f};

    const int NT = K >> 6;

    // prologue: T0 fully (buf0), T1 minus A1 (buf1); drain T0, keep 6 in flight
    stageB(0, 0, 0); stageB(0, 1, 0); stageA(0, 0, 0); stageA(0, 1, 0);
    stageB(1, 0, 1); stageB(1, 1, 1); stageA(1, 0, 1);
    asm volatile("s_waitcnt vmcnt(6)" ::: "memory");
    __builtin_amdgcn_s_barrier();

    for (int t = 0; t < NT; ++t) {
        const short* Ac = &Ab[t & 1][0];
        const short* Bc = &Bb[t & 1][0];
        const int nb = (t + 1) & 1;
        s8v af[4][2], bf0[2][2], bf1[2][2];

        // ---- phase 1: A(qm=0) + B(qn=0), MFMA quadrant (0,0)
#pragma unroll
        for (int mi = 0; mi < 4; mi++) {
            const int row = wm + mi * 16 + l15;
            af[mi][0] = *(const s8v*)&Ac[row * 64 + ks0];
            af[mi][1] = *(const s8v*)&Ac[row * 64 + ks1];
        }
#pragma unroll
        for (int ni = 0; ni < 2; ni++) {
            const int row = wn + ni * 16 + l15;
            bf0[ni][0] = *(const s8v*)&Bc[row * 64 + ks0];
            bf0[ni][1] = *(const s8v*)&Bc[row * 64 + ks1];
        }
        if (t + 1 < NT) stageA(nb, 1, t + 1);
        __builtin_amdgcn_s_setprio(1);
#pragma unroll
        for (int mi = 0; mi < 4; mi++)
#pragma unroll
            for (int ni = 0; ni < 2; ni++) {
                acc[0][mi][0][ni] = __builtin_amdgcn_mfma_f32_16x16x32_bf16(af[mi][0], bf0[ni][0], acc[0][mi][0][ni], 0, 0, 0);
                acc[0][mi][0][ni] = __builtin_amdgcn_mfma_f32_16x16x32_bf16(af[mi][1], bf0[ni][1], acc[0][mi][0][ni], 0, 0, 0);
            }
        __builtin_amdgcn_s_setprio(0);
        __builtin_amdgcn_s_barrier();

        // ---- phase 2: B(qn=1), MFMA quadrant (0,1)
#pragma unroll
        for (int ni = 0; ni < 2; ni++) {
            const int row = wn + 32 + ni * 16 + l15;
            bf1[ni][0] = *(const s8v*)&Bc[row * 64 + ks0];
            bf1[ni][1] = *(const s8v*)&Bc[row * 64 + ks1];
        }
        __builtin_amdgcn_s_setprio(1);
#pragma unroll
        for (int mi = 0; mi < 4; mi++)
#pragma unroll
            for (int ni = 0; ni < 2; ni++) {
                acc[0][mi][1][ni] = __builtin_amdgcn_mfma_f32_16x16x32_bf16(af[mi][0], bf1[ni][0], acc[0][mi][1][ni], 0, 0, 0);
                acc[0][mi][1][ni] = __builtin_amdgcn_mfma_f32_16x16x32_bf16(af[mi][1], bf1[ni][1], acc[0][mi][1][ni], 0, 0, 0);
            }
        __builtin_amdgcn_s_setprio(0);
        __builtin_amdgcn_s_barrier();

        // ---- phase 3: A(qm=1), MFMA quadrant (1,0); stage T(t+2).B0 into cur buf
#pragma unroll
        for (int mi = 0; mi < 4; mi++) {
            const int row = wm + 64 + mi * 16 + l15;
            af[mi][0] = *(const s8v*)&Ac[row * 64 + ks0];
            af[mi][1] = *(const s8v*)&Ac[row * 64 + ks1];
        }
        if (t + 2 < NT) stageB(t & 1, 0, t + 2);
        __builtin_amdgcn_s_setprio(1);
#pragma unroll
        for (int mi = 0; mi < 4; mi++)
#pragma unroll
            for (int ni = 0; ni < 2; ni++) {
                acc[1][mi][0][ni] = __builtin_amdgcn_mfma_f32_16x16x32_bf16(af[mi][0], bf0[ni][0], acc[1][mi][0][ni], 0, 0, 0);
                acc[1][mi][0][ni] = __builtin_amdgcn_mfma_f32_16x16x32_bf16(af[mi][1], bf0[ni][1], acc[1][mi][0][ni], 0, 0, 0);
            }
        __builtin_amdgcn_s_setprio(0);
        __builtin_amdgcn_s_barrier();

        // ---- phase 4: MFMA quadrant (1,1); stage T(t+2).B1 + A0; boundary sync
        if (t + 2 < NT) { stageB(t & 1, 1, t + 2); stageA(t & 1, 0, t + 2); }
        __builtin_amdgcn_s_setprio(1);
#pragma unroll
        for (int mi = 0; mi < 4; mi++)
#pragma unroll
            for (int ni = 0; ni < 2; ni++) {
                acc[1][mi][1][ni] = __builtin_amdgcn_mfma_f32_16x16x32_bf16(af[mi][0], bf1[ni][0], acc[1][mi][1][ni], 0, 0, 0);
                acc[1][mi][1][ni] = __builtin_amdgcn_mfma_f32_16x16x32_bf16(af[mi][1], bf1[ni][1], acc[1][mi][1][ni], 0, 0, 0);
            }
        __builtin_amdgcn_s_setprio(0);
        if (t + 1 < NT) {
            if (t + 1 == NT - 1) asm volatile("s_waitcnt vmcnt(0)" ::: "memory");
            else                 asm volatile("s_waitcnt vmcnt(6)" ::: "memory");
            __builtin_amdgcn_s_barrier();
        }
    }

#pragma unroll
    for (int qm = 0; qm < 2; qm++)
#pragma unroll
        for (int mi = 0; mi < 4; mi++)
#pragma unroll
            for (int qn = 0; qn < 2; qn++)
#pragma unroll
                for (int ni = 0; ni < 2; ni++)
#pragma unroll
                    for (int r = 0; r < 4; r++) {
                        int row = m0 + wm + qm * 64 + mi * 16 + quad * 4 + r;
                        int col = n0 + wn + qn * 32 + ni * 16 + l15;
                        float v = acc[qm][mi][qn][ni][r];
                        if (CF32) ((float*)Cv)[(long)row * ldc + col] = v;
                        else      ((short*)Cv)[(long)row * ldc + col] = f2bf(v);
                    }
}

// RoPE in-place on qkv cols [0,2560)
__global__ __launch_bounds__(256) void rope_kernel(short* __restrict__ qkv) {
    int tid = blockIdx.x * 256 + threadIdx.x;
    int p = tid % 1280;
    int row = tid / 1280;
    int head = p >> 5;
    int j = p & 31;
    int s = row & 2047;
    int c1 = head * 64 + j;
    float freq = exp2f(-(float)j * 0.4152410118609203f); // log2(10000)/32
    float ang = (float)s * freq;
    float sn, cs;
    __sincosf(ang, &sn, &cs);
    long base = (long)row * 3072;
    float x1 = bf2f(qkv[base + c1]);
    float x2 = bf2f(qkv[base + c1 + 32]);
    qkv[base + c1]      = f2bf(x1 * cs - x2 * sn);
    qkv[base + c1 + 32] = f2bf(x2 * cs + x1 * sn);
}

// V transpose (round-0 verified): qkv v-region -> Vt_g[(b*8+kvh)*64 + d][key] (ld 2048)
__global__ __launch_bounds__(256) void vtrans(const short* __restrict__ qkv,
                                              short* __restrict__ Vt_g) {
    __shared__ __align__(16) short tile[64 * 72];
    const int kt = blockIdx.x * 64;
    const int kvh = blockIdx.y;
    const int b = blockIdx.z;
    const int t = threadIdx.x;
#pragma unroll
    for (int cc = 0; cc < 2; cc++) {
        int ch = t + cc * 256;
        int key = ch >> 3, d0 = (ch & 7) * 8;
        s8v v = *(const s8v*)&qkv[(long)(b * 2048 + kt + key) * 3072 + 2560 + kvh * 64 + d0];
#pragma unroll
        for (int i = 0; i < 8; i++) tile[(d0 + i) * 72 + key] = v[i];
    }
    __syncthreads();
#pragma unroll
    for (int cc = 0; cc < 2; cc++) {
        int ch = t + cc * 256;
        int d = ch >> 3, kc = (ch & 7) * 8;
        *(s8v*)&Vt_g[(long)((b * 8 + kvh) * 64 + d) * 2048 + kt + kc] = *(const s8v*)&tile[d * 72 + kc];
    }
}

// Flash attention v4.2 (round-6 PASS, unchanged)
__global__ __launch_bounds__(256, 3) void attn4(short* __restrict__ qkv,
                                                const short* __restrict__ Vt_g) {
    __shared__ __align__(16) short KV[2][2][4096];   // [buf][K/V][64*64]
    __shared__ __align__(16) short Ps[4][2][16 * 72];
    __shared__ float rsb[4][32];

    const int tid = threadIdx.x;
    const int lane = tid & 63;
    const int wave = tid >> 6;
    const int quad = lane >> 4;
    const int l15 = lane & 15;

    int f = (blockIdx.z * 32 + blockIdx.y) * 16 + blockIdx.x;
    f = (f & 7) * 128 + (f >> 3);
    const int b = f >> 9;
    const int h = (f >> 4) & 31;
    const int kvh = h >> 2;
    const int q0 = (f & 15) * 128;

    const long kbase = ((long)b * 2048) * 3072 + 2048 + kvh * 64;
    const long vtbase = (long)(b * 8 + kvh) * 64 * 2048;

    const long qrow = (long)b * 2048 + q0 + wave * 32 + l15;
    const short* qp = qkv + qrow * 3072 + h * 64 + quad * 8;
    const s8v qf00 = *(const s8v*)(qp);
    const s8v qf01 = *(const s8v*)(qp + 32);
    const s8v qf10 = *(const s8v*)(qp + 16 * 3072);
    const s8v qf11 = *(const s8v*)(qp + 16 * 3072 + 32);

    const int rA = wave * 8 + (lane >> 3);
    const int sslot = (lane & 7) ^ (lane >> 3);
    const short* kA = qkv + kbase + (long)rA * 3072 + sslot * 8;
    const short* kB = kA + (long)32 * 3072;
    const short* vA = Vt_g + vtbase + (long)rA * 2048 + sslot * 8;
    const short* vB = vA + (long)32 * 2048;

    {
        char* kd = (char*)&KV[0][0][0] + wave * 1024;
        char* vd = (char*)&KV[0][1][0] + wave * 1024;
        __builtin_amdgcn_global_load_lds((gp1_t)kA, (lp3_t)kd, 16, 0, 0);
        __builtin_amdgcn_global_load_lds((gp1_t)kB, (lp3_t)(kd + 4096), 16, 0, 0);
        __builtin_amdgcn_global_load_lds((gp1_t)vA, (lp3_t)vd, 16, 0, 0);
        __builtin_amdgcn_global_load_lds((gp1_t)vB, (lp3_t)(vd + 4096), 16, 0, 0);
    }
    __syncthreads();

    const int ks0 = ((quad ^ (l15 & 7)) << 3);
    const int ks1 = ks0 ^ 32;

    f2v rs0v = (f2v){0.f, 0.f}, rs1v = (f2v){0.f, 0.f};
    f4v o0[4], o1[4];
#pragma unroll
    for (int ni = 0; ni < 4; ni++) { o0[ni] = (f4v){0.f, 0.f, 0.f, 0.f}; o1[ni] = (f4v){0.f, 0.f, 0.f, 0.f}; }

    short* Pw0 = &Ps[wave][0][0];
    short* Pw1 = &Ps[wave][1][0];

    for (int t = 0; t < 32; ++t) {
        const short* Kb = &KV[t & 1][0][0];
        const short* Vb = &KV[t & 1][1][0];

        if (t < 31) {
            const long ko = (long)(t + 1) * (64 * 3072);
            const long vo = (long)(t + 1) * 64;
            char* kd = (char*)&KV[(t + 1) & 1][0][0] + wave * 1024;
            char* vd = (char*)&KV[(t + 1) & 1][1][0] + wave * 1024;
            __builtin_amdgcn_global_load_lds((gp1_t)(kA + ko), (lp3_t)kd, 16, 0, 0);
            __builtin_amdgcn_global_load_lds((gp1_t)(kB + ko), (lp3_t)(kd + 4096), 16, 0, 0);
            __builtin_amdgcn_global_load_lds((gp1_t)(vA + vo), (lp3_t)vd, 16, 0, 0);
            __builtin_amdgcn_global_load_lds((gp1_t)(vB + vo), (lp3_t)(vd + 4096), 16, 0, 0);
        }

#pragma unroll
        for (int ni = 0; ni < 4; ni++) {
            const int ro = (ni * 16 + l15) * 64;
            const s8v kf0 = *(const s8v*)&Kb[ro + ks0];
            const s8v kf1 = *(const s8v*)&Kb[ro + ks1];
            f4v a = (f4v){-24.f, -24.f, -24.f, -24.f};
            a = __builtin_amdgcn_mfma_f32_16x16x32_bf16(kf0, qf00, a, 0, 0, 0);
            a = __builtin_amdgcn_mfma_f32_16x16x32_bf16(kf1, qf01, a, 0, 0, 0);
            {
                float p0 = exp2f(a[0]);
                float p1 = exp2f(a[1]);
                float p2 = exp2f(a[2]);
                float p3 = exp2f(a[3]);
                rs0v += (f2v){p0, p1};
                rs0v += (f2v){p2, p3};
                *(i2v*)&Pw0[l15 * 72 + ni * 16 + quad * 4] =
                    (i2v){(int)cvt_pk_bf16(p0, p1), (int)cvt_pk_bf16(p2, p3)};
            }
            f4v c = (f4v){-24.f, -24.f, -24.f, -24.f};
            c = __builtin_amdgcn_mfma_f32_16x16x32_bf16(kf0, qf10, c, 0, 0, 0);
            c = __builtin_amdgcn_mfma_f32_16x16x32_bf16(kf1, qf11, c, 0, 0, 0);
            {
                float p0 = exp2f(c[0]);
                float p1 = exp2f(c[1]);
                float p2 = exp2f(c[2]);
                float p3 = exp2f(c[3]);
                rs1v += (f2v){p0, p1};
                rs1v += (f2v){p2, p3};
                *(i2v*)&Pw1[l15 * 72 + ni * 16 + quad * 4] =
                    (i2v){(int)cvt_pk_bf16(p0, p1), (int)cvt_pk_bf16(p2, p3)};
            }
        }

        const s8v pf00 = *(const s8v*)&Pw0[l15 * 72 + quad * 8];
        const s8v pf01 = *(const s8v*)&Pw0[l15 * 72 + 32 + quad * 8];
        const s8v pf10 = *(const s8v*)&Pw1[l15 * 72 + quad * 8];
        const s8v pf11 = *(const s8v*)&Pw1[l15 * 72 + 32 + quad * 8];
#pragma unroll
        for (int ni = 0; ni < 4; ni++) {
            const int ro = (ni * 16 + l15) * 64;
            const s8v vf0 = *(const s8v*)&Vb[ro + ks0];
            const s8v vf1 = *(const s8v*)&Vb[ro + ks1];
            o0[ni] = __builtin_amdgcn_mfma_f32_16x16x32_bf16(pf00, vf0, o0[ni], 0, 0, 0);
            o0[ni] = __builtin_amdgcn_mfma_f32_16x16x32_bf16(pf01, vf1, o0[ni], 0, 0, 0);
            o1[ni] = __builtin_amdgcn_mfma_f32_16x16x32_bf16(pf10, vf0, o1[ni], 0, 0, 0);
            o1[ni] = __builtin_amdgcn_mfma_f32_16x16x32_bf16(pf11, vf1, o1[ni], 0, 0, 0);
        }
        __syncthreads();
    }

    float rs0 = rs0v[0] + rs0v[1];
    float rs1 = rs1v[0] + rs1v[1];
    rs0 += __shfl_xor(rs0, 16); rs0 += __shfl_xor(rs0, 32);
    rs1 += __shfl_xor(rs1, 16); rs1 += __shfl_xor(rs1, 32);
    if (quad == 0) { rsb[wave][l15] = rs0; rsb[wave][16 + l15] = rs1; }
    __syncthreads();

#pragma unroll
    for (int r = 0; r < 4; r++) {
        const float i0 = 1.0f / rsb[wave][quad * 4 + r];
        const float i1 = 1.0f / rsb[wave][16 + quad * 4 + r];
        const long ob0 = ((long)b * 2048 + q0 + wave * 32 + quad * 4 + r) * 3072 + h * 64;
        const long ob1 = ob0 + 16 * 3072;
#pragma unroll
        for (int ni = 0; ni < 4; ni++) {
            qkv[ob0 + ni * 16 + l15] = f2bf(o0[ni][r] * i0);
            qkv[ob1 + ni * 16 + l15] = f2bf(o1[ni][r] * i1);
        }
    }
}

// ======================= FALLBACK PATH (round-6, known-PASS) =======================

template <bool AF32, bool CF32>
__global__ __launch_bounds__(256) void gemm_bn(const void* __restrict__ Av,
                                               const float* __restrict__ B,
                                               void* __restrict__ Cv,
                                               int K, int N, int lda, int ldc) {
    __shared__ __align__(16) short As[128 * 40];
    __shared__ __align__(16) short Bs[128 * 40];
    const int tid = threadIdx.x;
    const int lane = tid & 63;
    const int wave = tid >> 6;
    const int quad = lane >> 4;
    const int l15 = lane & 15;
    const int m0 = blockIdx.y * 128;
    const int n0 = blockIdx.x * 128;
    const int wm = (wave & 1) * 64;
    const int wn = (wave >> 1) * 64;

    f4v acc[4][4];
#pragma unroll
    for (int i = 0; i < 4; i++)
#pragma unroll
        for (int j = 0; j < 4; j++) acc[i][j] = (f4v){0.f, 0.f, 0.f, 0.f};

    const int ar0 = tid >> 2, akc0 = (tid & 3) * 8;
    const int ar1 = (tid + 256) >> 2, akc1 = ((tid + 256) & 3) * 8;
    const int bk0 = tid >> 4, bnc0 = (tid & 15) * 8;
    const int bk1 = (tid + 256) >> 4, bnc1 = ((tid + 256) & 15) * 8;

    for (int k0 = 0; k0 < K; k0 += 32) {
        __syncthreads();
        if (AF32) {
            const float* A = (const float*)Av;
            *(s8v*)(&As[ar0 * 40 + akc0]) = cvt8(&A[(long)(m0 + ar0) * lda + k0 + akc0]);
            *(s8v*)(&As[ar1 * 40 + akc1]) = cvt8(&A[(long)(m0 + ar1) * lda + k0 + akc1]);
        } else {
            const short* A = (const short*)Av;
            *(s8v*)(&As[ar0 * 40 + akc0]) = *(const s8v*)(&A[(long)(m0 + ar0) * lda + k0 + akc0]);
            *(s8v*)(&As[ar1 * 40 + akc1]) = *(const s8v*)(&A[(long)(m0 + ar1) * lda + k0 + akc1]);
        }
        s8v b0 = cvt8(&B[(long)(k0 + bk0) * N + n0 + bnc0]);
        s8v b1 = cvt8(&B[(long)(k0 + bk1) * N + n0 + bnc1]);
#pragma unroll
        for (int i = 0; i < 8; i++) Bs[(bnc0 + i) * 40 + bk0] = b0[i];
#pragma unroll
        for (int i = 0; i < 8; i++) Bs[(bnc1 + i) * 40 + bk1] = b1[i];
        __syncthreads();
        s8v af[4], bfr[4];
#pragma unroll
        for (int mi = 0; mi < 4; mi++)
            af[mi] = *(const s8v*)(&As[(wm + mi * 16 + l15) * 40 + quad * 8]);
#pragma unroll
        for (int ni = 0; ni < 4; ni++)
            bfr[ni] = *(const s8v*)(&Bs[(wn + ni * 16 + l15) * 40 + quad * 8]);
#pragma unroll
        for (int mi = 0; mi < 4; mi++)
#pragma unroll
            for (int ni = 0; ni < 4; ni++)
                acc[mi][ni] = __builtin_amdgcn_mfma_f32_16x16x32_bf16(af[mi], bfr[ni], acc[mi][ni], 0, 0, 0);
    }
#pragma unroll
    for (int mi = 0; mi < 4; mi++)
#pragma unroll
        for (int ni = 0; ni < 4; ni++)
#pragma unroll
            for (int r = 0; r < 4; r++) {
                int row = m0 + wm + mi * 16 + quad * 4 + r;
                int col = n0 + wn + ni * 16 + l15;
                if (CF32) ((float*)Cv)[(long)row * ldc + col] = acc[mi][ni][r];
                else      ((short*)Cv)[(long)row * ldc + col] = f2bf(acc[mi][ni][r]);
            }
}

__global__ __launch_bounds__(256) void attn_kernel(short* __restrict__ qkv) {
    __shared__ __align__(16) short Qs[64 * 72];
    __shared__ __align__(16) short Ks[64 * 72];
    __shared__ __align__(16) short Vt[64 * 72];
    __shared__ __align__(16) short Ps[4][16 * 72];

    const int tid = threadIdx.x;
    const int lane = tid & 63;
    const int wave = tid >> 6;
    const int quad = lane >> 4;
    const int l15 = lane & 15;
    const int b = blockIdx.z;
    const int h = blockIdx.y;
    const int kvh = h >> 2;
    const int q0 = blockIdx.x * 64;

    const long qbase = ((long)b * 2048 + q0) * 3072 + h * 64;
    const long kbase = ((long)b * 2048) * 3072 + 2048 + kvh * 64;
    const long vbase = kbase + 512;

#pragma unroll
    for (int cc = 0; cc < 2; cc++) {
        int ch = tid + cc * 256;
        int r = ch >> 3, d0 = (ch & 7) * 8;
        *(s8v*)(&Qs[r * 72 + d0]) = *(const s8v*)(&qkv[qbase + (long)r * 3072 + d0]);
    }
    __syncthreads();
    s8v qf[2];
    qf[0] = *(const s8v*)(&Qs[(wave * 16 + l15) * 72 + quad * 8]);
    qf[1] = *(const s8v*)(&Qs[(wave * 16 + l15) * 72 + 32 + quad * 8]);

    float m_i[4], l_i[4];
    f4v o[4];
#pragma unroll
    for (int r = 0; r < 4; r++) { m_i[r] = -1e30f; l_i[r] = 0.0f; }
#pragma unroll
    for (int ni = 0; ni < 4; ni++) o[ni] = (f4v){0.f, 0.f, 0.f, 0.f};

    for (int kt = 0; kt < 2048; kt += 64) {
        __syncthreads();
#pragma unroll
        for (int cc = 0; cc < 2; cc++) {
            int ch = tid + cc * 256;
            int r = ch >> 3, d0 = (ch & 7) * 8;
            *(s8v*)(&Ks[r * 72 + d0]) = *(const s8v*)(&qkv[kbase + (long)(kt + r) * 3072 + d0]);
            s8v v = *(const s8v*)(&qkv[vbase + (long)(kt + r) * 3072 + d0]);
            int g = d0 >> 3;
            int chn = ((r >> 3) ^ g) * 8 + (r & 7);
#pragma unroll
            for (int i = 0; i < 8; i++) Vt[(d0 + i) * 72 + chn] = v[i];
        }
        __syncthreads();

        f4v sc[4];
#pragma unroll
        for (int ni = 0; ni < 4; ni++) {
            s8v kf0 = *(const s8v*)(&Ks[(ni * 16 + l15) * 72 + quad * 8]);
            s8v kf1 = *(const s8v*)(&Ks[(ni * 16 + l15) * 72 + 32 + quad * 8]);
            f4v a = (f4v){0.f, 0.f, 0.f, 0.f};
            a = __builtin_amdgcn_mfma_f32_16x16x32_bf16(qf[0], kf0, a, 0, 0, 0);
            a = __builtin_amdgcn_mfma_f32_16x16x32_bf16(qf[1], kf1, a, 0, 0, 0);
            sc[ni] = a * 0.125f;
        }
        float alpha[4], rs[4];
#pragma unroll
        for (int r = 0; r < 4; r++) {
            float v = fmaxf(fmaxf(sc[0][r], sc[1][r]), fmaxf(sc[2][r], sc[3][r]));
            v = fmaxf(v, __shfl_xor(v, 1));
            v = fmaxf(v, __shfl_xor(v, 2));
            v = fmaxf(v, __shfl_xor(v, 4));
            v = fmaxf(v, __shfl_xor(v, 8));
            float mn = fmaxf(m_i[r], v);
            alpha[r] = __expf(m_i[r] - mn);
            m_i[r] = mn;
            rs[r] = 0.f;
        }
#pragma unroll
        for (int ni = 0; ni < 4; ni++)
#pragma unroll
            for (int r = 0; r < 4; r++) {
                float pv = __expf(sc[ni][r] - m_i[r]);
                sc[ni][r] = pv;
                rs[r] += pv;
            }
#pragma unroll
        for (int r = 0; r < 4; r++) {
            float v = rs[r];
            v += __shfl_xor(v, 1);
            v += __shfl_xor(v, 2);
            v += __shfl_xor(v, 4);
            v += __shfl_xor(v, 8);
            l_i[r] = l_i[r] * alpha[r] + v;
        }
#pragma unroll
        for (int ni = 0; ni < 4; ni++)
#pragma unroll
            for (int r = 0; r < 4; r++) {
                int row = quad * 4 + r;
                int key = ni * 16 + l15;
                int chn = ((key >> 3) ^ (row >> 3)) * 8 + (key & 7);
                Ps[wave][row * 72 + chn] = f2bf(sc[ni][r]);
            }
        __syncthreads();
#pragma unroll
        for (int ni = 0; ni < 4; ni++) {
            f4v t = o[ni];
            t[0] *= alpha[0]; t[1] *= alpha[1]; t[2] *= alpha[2]; t[3] *= alpha[3];
            o[ni] = t;
        }
        s8v pf0 = *(const s8v*)(&Ps[wave][l15 * 72 + ((quad ^ (l15 >> 3)) * 8)]);
        s8v pf1 = *(const s8v*)(&Ps[wave][l15 * 72 + (((4 + quad) ^ (l15 >> 3)) * 8)]);
#pragma unroll
        for (int ni = 0; ni < 4; ni++) {
            int d = ni * 16 + l15;
            s8v vf0 = *(const s8v*)(&Vt[d * 72 + ((quad ^ (d >> 3)) * 8)]);
            s8v vf1 = *(const s8v*)(&Vt[d * 72 + (((4 + quad) ^ (d >> 3)) * 8)]);
            o[ni] = __builtin_amdgcn_mfma_f32_16x16x32_bf16(pf0, vf0, o[ni], 0, 0, 0);
            o[ni] = __builtin_amdgcn_mfma_f32_16x16x32_bf16(pf1, vf1, o[ni], 0, 0, 0);
        }
    }
#pragma unroll
    for (int r = 0; r < 4; r++) {
        float inv = 1.0f / l_i[r];
        int srow = q0 + wave * 16 + quad * 4 + r;
        long obase = ((long)b * 2048 + srow) * 3072 + h * 64;
#pragma unroll
        for (int ni = 0; ni < 4; ni++)
            qkv[obase + ni * 16 + l15] = f2bf(o[ni][r] * inv);
    }
}

extern "C" void kernel_launch(void* const* d_in, const int* in_sizes, int n_in,
                              void* d_out, int out_size, void* d_ws, size_t ws_size,
                              hipStream_t stream) {
    (void)in_sizes; (void)n_in; (void)out_size;
    const float* x  = (const float*)d_in[0];
    const float* Wq = (const float*)d_in[1];
    const float* Wk = (const float*)d_in[2];
    const float* Wv = (const float*)d_in[3];
    const float* Wo = (const float*)d_in[4];

    const float CS = 0.18033688011112042f;   // 0.125 * log2(e), folded into Wk
    const size_t need = 67108864ULL; // 64 MiB
    if (ws_size >= need) {
        short* xb    = (short*)d_ws;              // 4096x2048
        short* Wqkvt = xb + 8388608;              // 3072x2048
        short* Wot   = Wqkvt + 6291456;           // 2048x2048
        short* qkv   = Wot + 4194304;             // 4096x3072
        short* Vt_g  = qkv + 12582912;            // 16x64x2048

        cvt_x<<<4096, 256, 0, stream>>>(x, xb);
        cvt_wt<<<dim3(32, 32), 256, 0, stream>>>(Wq, Wqkvt, 2048, 0, 1.0f);
        cvt_wt<<<dim3(8, 32), 256, 0, stream>>>(Wk, Wqkvt, 512, 2048, CS);
        cvt_wt<<<dim3(8, 32), 256, 0, stream>>>(Wv, Wqkvt, 512, 2560, 1.0f);
        cvt_wt<<<dim3(32, 32), 256, 0, stream>>>(Wo, Wot, 2048, 0, 1.0f);
        gemm_bt8<false><<<dim3(12, 16), 512, 0, stream>>>(xb, Wqkvt, qkv, 2048, 2048, 2048, 3072);
        rope_kernel<<<dim3(20480), 256, 0, stream>>>(qkv);
        vtrans<<<dim3(32, 8, 2), 256, 0, stream>>>(qkv, Vt_g);
        attn4<<<dim3(16, 32, 2), 256, 0, stream>>>(qkv, Vt_g);
        gemm_bt8<true><<<dim3(8, 16), 512, 0, stream>>>(qkv, Wot, d_out, 2048, 3072, 2048, 2048);
    } else {
        short* qkv = (short*)d_ws;
        gemm_bn<true, false><<<dim3(16, 32), 256, 0, stream>>>(x, Wq, qkv,        2048, 2048, 2048, 3072);
        gemm_bn<true, false><<<dim3(4, 32), 256, 0, stream>>>(x, Wk, qkv + 2048, 2048,  512, 2048, 3072);
        gemm_bn<true, false><<<dim3(4, 32), 256, 0, stream>>>(x, Wv, qkv + 2560, 2048,  512, 2048, 3072);
        rope_kernel<<<dim3(20480), 256, 0, stream>>>(qkv);
        attn_kernel<<<dim3(32, 32, 2), 256, 0, stream>>>(qkv);
        gemm_bn<false, true><<<dim3(16, 32), 256, 0, stream>>>(qkv, Wo, d_out, 2048, 2048, 3072, 2048);
    }
}

// Round 9
// 333.491 us; speedup vs baseline: 1.3430x; 1.0713x over previous
//
#include <hip/hip_runtime.h>

typedef short s8v __attribute__((ext_vector_type(8)));
typedef int i2v __attribute__((ext_vector_type(2)));
typedef float f2v __attribute__((ext_vector_type(2)));
typedef float f4v __attribute__((ext_vector_type(4)));

typedef const __attribute__((address_space(1))) char* gp1_t;
typedef __attribute__((address_space(3))) char* lp3_t;

__device__ __forceinline__ float bf2f(short s) {
    union { unsigned u; float f; } c;
    c.u = ((unsigned)(unsigned short)s) << 16;
    return c.f;
}
__device__ __forceinline__ short f2bf(float f) {
    union { float f; unsigned u; } c; c.f = f;
    unsigned r = (c.u + 0x7FFFu + ((c.u >> 16) & 1u)) >> 16;
    return (short)r;
}
__device__ __forceinline__ unsigned cvt_pk_bf16(float a, float b) {
    unsigned r;
    asm("v_cvt_pk_bf16_f32 %0, %1, %2" : "=v"(r) : "v"(a), "v"(b));
    return r;
}
__device__ __forceinline__ s8v cvt8(const float* __restrict__ p) {
    f4v a = *(const f4v*)p;
    f4v b = *(const f4v*)(p + 4);
    s8v r;
    r[0] = f2bf(a[0]); r[1] = f2bf(a[1]); r[2] = f2bf(a[2]); r[3] = f2bf(a[3]);
    r[4] = f2bf(b[0]); r[5] = f2bf(b[1]); r[6] = f2bf(b[2]); r[7] = f2bf(b[3]);
    return r;
}

// ======================= FAST PATH (ws >= 64 MiB) =======================

// fp32 -> bf16 straight copy (x)
__global__ __launch_bounds__(256) void cvt_x(const float* __restrict__ x,
                                             short* __restrict__ xb) {
    long i = ((long)blockIdx.x * 256 + threadIdx.x) * 8;
    *(s8v*)&xb[i] = cvt8(&x[i]);
}

// W (2048 x N fp32) -> Wt rows [obase+n][k] bf16 (ld 2048), scaled by `scale`
__global__ __launch_bounds__(256) void cvt_wt(const float* __restrict__ W,
                                              short* __restrict__ Wt,
                                              int N, int obase, float scale) {
    __shared__ __align__(16) short tile[64 * 72];
    const int kt = blockIdx.y * 64, n0 = blockIdx.x * 64;
    const int t = threadIdx.x;
    const int r = t >> 4, c4 = (t & 15) * 4;
#pragma unroll
    for (int i = 0; i < 4; i++) {
        int kr = r + i * 16;
        f4v v = *(const f4v*)&W[(long)(kt + kr) * N + n0 + c4];
#pragma unroll
        for (int j = 0; j < 4; j++) tile[(c4 + j) * 72 + kr] = f2bf(v[j] * scale);
    }
    __syncthreads();
    const int nr = t >> 3, kc = (t & 7) * 8;
#pragma unroll
    for (int i = 0; i < 2; i++) {
        int n = nr + i * 32;
        *(s8v*)&Wt[(long)(obase + n0 + n) * 2048 + kt + kc] = *(const s8v*)&tile[n * 72 + kc];
    }
}

// ================== 256x256 4-phase GEMM (T2+T3+T4+T5) ==================
// (round-8 PASS) plus optional fused RoPE epilogue: a wave's 64 columns are
// one head; rotation pair (j, j+32) = (qn0, qn1) at same (ni,l15) is
// lane-local in acc. Applied in fp32 before the single bf16 rounding.
template <bool CF32, bool ROPE>
__global__ __launch_bounds__(512, 2) void gemm_bt8(const short* __restrict__ A,
                                                   const short* __restrict__ Bt,
                                                   void* __restrict__ Cv,
                                                   int K, int lda, int ldb, int ldc) {
    __shared__ __align__(16) short Ab[2][16384];   // [buf][256*64]
    __shared__ __align__(16) short Bb[2][16384];

    const int tid = threadIdx.x;
    const int lane = tid & 63;
    const int wave = tid >> 6;
    const int quad = lane >> 4;
    const int l15 = lane & 15;

    const int nwg = gridDim.x * gridDim.y;
    int f = blockIdx.y * gridDim.x + blockIdx.x;
    if ((nwg & 7) == 0) f = (f & 7) * (nwg >> 3) + (f >> 3);
    const int m0 = (f / gridDim.x) * 256;
    const int n0 = (f % gridDim.x) * 256;

    const int wm = (wave >> 2) * 128;
    const int wn = (wave & 3) * 64;

    const int rsub = lane >> 3;
    const int sslot = (lane & 7) ^ rsub;
    const short* aS[2][2];
    const short* bS[2][2];
#pragma unroll
    for (int h = 0; h < 2; h++)
#pragma unroll
        for (int i = 0; i < 2; i++) {
            int row = h * 128 + wave * 16 + i * 8 + rsub;
            aS[h][i] = A  + (long)(m0 + row) * lda + sslot * 8;
            bS[h][i] = Bt + (long)(n0 + row) * ldb + sslot * 8;
        }

    auto stageA = [&](int buf, int h, int kt) {
        char* d = (char*)&Ab[buf][0] + h * 16384 + wave * 2048;
        __builtin_amdgcn_global_load_lds((gp1_t)(aS[h][0] + (long)kt * 64), (lp3_t)d, 16, 0, 0);
        __builtin_amdgcn_global_load_lds((gp1_t)(aS[h][1] + (long)kt * 64), (lp3_t)(d + 1024), 16, 0, 0);
    };
    auto stageB = [&](int buf, int h, int kt) {
        char* d = (char*)&Bb[buf][0] + h * 16384 + wave * 2048;
        __builtin_amdgcn_global_load_lds((gp1_t)(bS[h][0] + (long)kt * 64), (lp3_t)d, 16, 0, 0);
        __builtin_amdgcn_global_load_lds((gp1_t)(bS[h][1] + (long)kt * 64), (lp3_t)(d + 1024), 16, 0, 0);
    };

    const int ks0 = (quad ^ (l15 & 7)) * 8;
    const int ks1 = ks0 ^ 32;

    f4v acc[2][4][2][2];   // [qm][mi][qn][ni]
#pragma unroll
    for (int a = 0; a < 2; a++)
#pragma unroll
        for (int b = 0; b < 4; b++)
#pragma unroll
            for (int c = 0; c < 2; c++)
#pragma unroll
                for (int d = 0; d < 2; d++) acc[a][b][c][d] = (f4v){0.f, 0.f, 0.f, 0.f};

    const int NT = K >> 6;

    stageB(0, 0, 0); stageB(0, 1, 0); stageA(0, 0, 0); stageA(0, 1, 0);
    stageB(1, 0, 1); stageB(1, 1, 1); stageA(1, 0, 1);
    asm volatile("s_waitcnt vmcnt(6)" ::: "memory");
    __builtin_amdgcn_s_barrier();

    for (int t = 0; t < NT; ++t) {
        const short* Ac = &Ab[t & 1][0];
        const short* Bc = &Bb[t & 1][0];
        const int nb = (t + 1) & 1;
        s8v af[4][2], bf0[2][2], bf1[2][2];

        // ---- phase 1
#pragma unroll
        for (int mi = 0; mi < 4; mi++) {
            const int row = wm + mi * 16 + l15;
            af[mi][0] = *(const s8v*)&Ac[row * 64 + ks0];
            af[mi][1] = *(const s8v*)&Ac[row * 64 + ks1];
        }
#pragma unroll
        for (int ni = 0; ni < 2; ni++) {
            const int row = wn + ni * 16 + l15;
            bf0[ni][0] = *(const s8v*)&Bc[row * 64 + ks0];
            bf0[ni][1] = *(const s8v*)&Bc[row * 64 + ks1];
        }
        if (t + 1 < NT) stageA(nb, 1, t + 1);
        __builtin_amdgcn_s_setprio(1);
#pragma unroll
        for (int mi = 0; mi < 4; mi++)
#pragma unroll
            for (int ni = 0; ni < 2; ni++) {
                acc[0][mi][0][ni] = __builtin_amdgcn_mfma_f32_16x16x32_bf16(af[mi][0], bf0[ni][0], acc[0][mi][0][ni], 0, 0, 0);
                acc[0][mi][0][ni] = __builtin_amdgcn_mfma_f32_16x16x32_bf16(af[mi][1], bf0[ni][1], acc[0][mi][0][ni], 0, 0, 0);
            }
        __builtin_amdgcn_s_setprio(0);
        __builtin_amdgcn_s_barrier();

        // ---- phase 2
#pragma unroll
        for (int ni = 0; ni < 2; ni++) {
            const int row = wn + 32 + ni * 16 + l15;
            bf1[ni][0] = *(const s8v*)&Bc[row * 64 + ks0];
            bf1[ni][1] = *(const s8v*)&Bc[row * 64 + ks1];
        }
        __builtin_amdgcn_s_setprio(1);
#pragma unroll
        for (int mi = 0; mi < 4; mi++)
#pragma unroll
            for (int ni = 0; ni < 2; ni++) {
                acc[0][mi][1][ni] = __builtin_amdgcn_mfma_f32_16x16x32_bf16(af[mi][0], bf1[ni][0], acc[0][mi][1][ni], 0, 0, 0);
                acc[0][mi][1][ni] = __builtin_amdgcn_mfma_f32_16x16x32_bf16(af[mi][1], bf1[ni][1], acc[0][mi][1][ni], 0, 0, 0);
            }
        __builtin_amdgcn_s_setprio(0);
        __builtin_amdgcn_s_barrier();

        // ---- phase 3
#pragma unroll
        for (int mi = 0; mi < 4; mi++) {
            const int row = wm + 64 + mi * 16 + l15;
            af[mi][0] = *(const s8v*)&Ac[row * 64 + ks0];
            af[mi][1] = *(const s8v*)&Ac[row * 64 + ks1];
        }
        if (t + 2 < NT) stageB(t & 1, 0, t + 2);
        __builtin_amdgcn_s_setprio(1);
#pragma unroll
        for (int mi = 0; mi < 4; mi++)
#pragma unroll
            for (int ni = 0; ni < 2; ni++) {
                acc[1][mi][0][ni] = __builtin_amdgcn_mfma_f32_16x16x32_bf16(af[mi][0], bf0[ni][0], acc[1][mi][0][ni], 0, 0, 0);
                acc[1][mi][0][ni] = __builtin_amdgcn_mfma_f32_16x16x32_bf16(af[mi][1], bf0[ni][1], acc[1][mi][0][ni], 0, 0, 0);
            }
        __builtin_amdgcn_s_setprio(0);
        __builtin_amdgcn_s_barrier();

        // ---- phase 4
        if (t + 2 < NT) { stageB(t & 1, 1, t + 2); stageA(t & 1, 0, t + 2); }
        __builtin_amdgcn_s_setprio(1);
#pragma unroll
        for (int mi = 0; mi < 4; mi++)
#pragma unroll
            for (int ni = 0; ni < 2; ni++) {
                acc[1][mi][1][ni] = __builtin_amdgcn_mfma_f32_16x16x32_bf16(af[mi][0], bf1[ni][0], acc[1][mi][1][ni], 0, 0, 0);
                acc[1][mi][1][ni] = __builtin_amdgcn_mfma_f32_16x16x32_bf16(af[mi][1], bf1[ni][1], acc[1][mi][1][ni], 0, 0, 0);
            }
        __builtin_amdgcn_s_setprio(0);
        if (t + 1 < NT) {
            if (t + 1 == NT - 1) asm volatile("s_waitcnt vmcnt(0)" ::: "memory");
            else                 asm volatile("s_waitcnt vmcnt(6)" ::: "memory");
            __builtin_amdgcn_s_barrier();
        }
    }

    // Fused RoPE (fp32, lane-local pairs), only for q/k heads (cols < 2560)
    if (ROPE && (n0 + wn) < 2560) {
        const float NLOG = -0.4152410118609203f;   // -log2(10000)/32
        const float fr0 = exp2f((float)l15 * NLOG);
        const float fr1 = exp2f((float)(16 + l15) * NLOG);
#pragma unroll
        for (int qm = 0; qm < 2; qm++)
#pragma unroll
            for (int mi = 0; mi < 4; mi++)
#pragma unroll
                for (int r = 0; r < 4; r++) {
                    const float s = (float)((m0 + wm + qm * 64 + mi * 16 + quad * 4 + r) & 2047);
#pragma unroll
                    for (int ni = 0; ni < 2; ni++) {
                        float sn, cs;
                        __sincosf(s * (ni ? fr1 : fr0), &sn, &cs);
                        float x1 = acc[qm][mi][0][ni][r];
                        float x2 = acc[qm][mi][1][ni][r];
                        acc[qm][mi][0][ni][r] = x1 * cs - x2 * sn;
                        acc[qm][mi][1][ni][r] = x2 * cs + x1 * sn;
                    }
                }
    }

#pragma unroll
    for (int qm = 0; qm < 2; qm++)
#pragma unroll
        for (int mi = 0; mi < 4; mi++)
#pragma unroll
            for (int qn = 0; qn < 2; qn++)
#pragma unroll
                for (int ni = 0; ni < 2; ni++)
#pragma unroll
                    for (int r = 0; r < 4; r++) {
                        int row = m0 + wm + qm * 64 + mi * 16 + quad * 4 + r;
                        int col = n0 + wn + qn * 32 + ni * 16 + l15;
                        float v = acc[qm][mi][qn][ni][r];
                        if (CF32) ((float*)Cv)[(long)row * ldc + col] = v;
                        else      ((short*)Cv)[(long)row * ldc + col] = f2bf(v);
                    }
}

// ================== 128x256 4-phase GEMM (full-chip variant) ==================
// Same T-stack, BM=128 so small-N GEMMs fill all 256 CUs.
// 8 waves (2M x 4N), per-wave 64x64 output. LDS 96 KiB.
// Per tile t (reads buf[t&1]): 6 stage-loads for t+2 into CUR buf:
//   ph1: ds_read A(mi0-1)+B0; MFMA (mi0-1,qn0); bar   [B0 LDS free]
//   ph2: ds_read B1; stage B-h0(t+2); MFMA (mi0-1,qn1); bar   [B1 free]
//   ph3: ds_read A(mi2-3); stage B-h1(t+2); MFMA (mi2-3,qn0); bar  [A free]
//   ph4: stage A(t+2); MFMA (mi2-3,qn1); vmcnt(6) [vmcnt(0) pre-last]; bar
// Prologue stages T0+T1 fully (12 loads), vmcnt(6) drains T0. NT >= 2.
template <bool CF32>
__global__ __launch_bounds__(512, 2) void gemm_bt2(const short* __restrict__ A,
                                                   const short* __restrict__ Bt,
                                                   void* __restrict__ Cv,
                                                   int K, int lda, int ldb, int ldc) {
    __shared__ __align__(16) short Ab[2][8192];    // [buf][128*64]
    __shared__ __align__(16) short Bb[2][16384];   // [buf][256*64]

    const int tid = threadIdx.x;
    const int lane = tid & 63;
    const int wave = tid >> 6;
    const int quad = lane >> 4;
    const int l15 = lane & 15;

    const int nwg = gridDim.x * gridDim.y;
    int f = blockIdx.y * gridDim.x + blockIdx.x;
    if ((nwg & 7) == 0) f = (f & 7) * (nwg >> 3) + (f >> 3);
    const int m0 = (f / gridDim.x) * 128;
    const int n0 = (f % gridDim.x) * 256;

    const int wm = (wave >> 2) * 64;    // 0 or 64
    const int wn = (wave & 3) * 64;     // 0..192

    const int rsub = lane >> 3;
    const int sslot = (lane & 7) ^ rsub;
    const short* aS[2];
    const short* bS[4];
#pragma unroll
    for (int i = 0; i < 2; i++)
        aS[i] = A + (long)(m0 + wave * 16 + i * 8 + rsub) * lda + sslot * 8;
#pragma unroll
    for (int i = 0; i < 4; i++)
        bS[i] = Bt + (long)(n0 + wave * 32 + i * 8 + rsub) * ldb + sslot * 8;

    auto stageA = [&](int buf, int kt) {
        char* d = (char*)&Ab[buf][0] + wave * 2048;
        __builtin_amdgcn_global_load_lds((gp1_t)(aS[0] + (long)kt * 64), (lp3_t)d, 16, 0, 0);
        __builtin_amdgcn_global_load_lds((gp1_t)(aS[1] + (long)kt * 64), (lp3_t)(d + 1024), 16, 0, 0);
    };
    auto stageBh = [&](int buf, int h, int kt) {   // h in {0,1}, 2 calls each
        char* d = (char*)&Bb[buf][0] + wave * 4096 + h * 2048;
        __builtin_amdgcn_global_load_lds((gp1_t)(bS[2 * h] + (long)kt * 64), (lp3_t)d, 16, 0, 0);
        __builtin_amdgcn_global_load_lds((gp1_t)(bS[2 * h + 1] + (long)kt * 64), (lp3_t)(d + 1024), 16, 0, 0);
    };

    const int ks0 = (quad ^ (l15 & 7)) * 8;
    const int ks1 = ks0 ^ 32;

    f4v acc[4][2][2];   // [mi][qn][ni]
#pragma unroll
    for (int a = 0; a < 4; a++)
#pragma unroll
        for (int b = 0; b < 2; b++)
#pragma unroll
            for (int c = 0; c < 2; c++) acc[a][b][c] = (f4v){0.f, 0.f, 0.f, 0.f};

    const int NT = K >> 6;

    stageA(0, 0); stageBh(0, 0, 0); stageBh(0, 1, 0);
    stageA(1, 1); stageBh(1, 0, 1); stageBh(1, 1, 1);
    asm volatile("s_waitcnt vmcnt(6)" ::: "memory");
    __builtin_amdgcn_s_barrier();

    for (int t = 0; t < NT; ++t) {
        const short* Ac = &Ab[t & 1][0];
        const short* Bc = &Bb[t & 1][0];
        s8v af01[2][2], af23[2][2], bf0[2][2], bf1[2][2];

        // ---- phase 1: A(mi0-1) + B0; MFMA (mi0-1, qn0)
#pragma unroll
        for (int mi = 0; mi < 2; mi++) {
            const int row = wm + mi * 16 + l15;
            af01[mi][0] = *(const s8v*)&Ac[row * 64 + ks0];
            af01[mi][1] = *(const s8v*)&Ac[row * 64 + ks1];
        }
#pragma unroll
        for (int ni = 0; ni < 2; ni++) {
            const int row = wn + ni * 16 + l15;
            bf0[ni][0] = *(const s8v*)&Bc[row * 64 + ks0];
            bf0[ni][1] = *(const s8v*)&Bc[row * 64 + ks1];
        }
        __builtin_amdgcn_s_setprio(1);
#pragma unroll
        for (int mi = 0; mi < 2; mi++)
#pragma unroll
            for (int ni = 0; ni < 2; ni++) {
                acc[mi][0][ni] = __builtin_amdgcn_mfma_f32_16x16x32_bf16(af01[mi][0], bf0[ni][0], acc[mi][0][ni], 0, 0, 0);
                acc[mi][0][ni] = __builtin_amdgcn_mfma_f32_16x16x32_bf16(af01[mi][1], bf0[ni][1], acc[mi][0][ni], 0, 0, 0);
            }
        __builtin_amdgcn_s_setprio(0);
        __builtin_amdgcn_s_barrier();

        // ---- phase 2: B1; stage B-h0(t+2) into cur (B0 region free); MFMA (mi0-1, qn1)
#pragma unroll
        for (int ni = 0; ni < 2; ni++) {
            const int row = wn + 32 + ni * 16 + l15;
            bf1[ni][0] = *(const s8v*)&Bc[row * 64 + ks0];
            bf1[ni][1] = *(const s8v*)&Bc[row * 64 + ks1];
        }
        if (t + 2 < NT) stageBh(t & 1, 0, t + 2);
        __builtin_amdgcn_s_setprio(1);
#pragma unroll
        for (int mi = 0; mi < 2; mi++)
#pragma unroll
            for (int ni = 0; ni < 2; ni++) {
                acc[mi][1][ni] = __builtin_amdgcn_mfma_f32_16x16x32_bf16(af01[mi][0], bf1[ni][0], acc[mi][1][ni], 0, 0, 0);
                acc[mi][1][ni] = __builtin_amdgcn_mfma_f32_16x16x32_bf16(af01[mi][1], bf1[ni][1], acc[mi][1][ni], 0, 0, 0);
            }
        __builtin_amdgcn_s_setprio(0);
        __builtin_amdgcn_s_barrier();

        // ---- phase 3: A(mi2-3); stage B-h1(t+2) (B1 region free); MFMA (mi2-3, qn0)
#pragma unroll
        for (int mi = 0; mi < 2; mi++) {
            const int row = wm + 32 + mi * 16 + l15;
            af23[mi][0] = *(const s8v*)&Ac[row * 64 + ks0];
            af23[mi][1] = *(const s8v*)&Ac[row * 64 + ks1];
        }
        if (t + 2 < NT) stageBh(t & 1, 1, t + 2);
        __builtin_amdgcn_s_setprio(1);
#pragma unroll
        for (int mi = 0; mi < 2; mi++)
#pragma unroll
            for (int ni = 0; ni < 2; ni++) {
                acc[2 + mi][0][ni] = __builtin_amdgcn_mfma_f32_16x16x32_bf16(af23[mi][0], bf0[ni][0], acc[2 + mi][0][ni], 0, 0, 0);
                acc[2 + mi][0][ni] = __builtin_amdgcn_mfma_f32_16x16x32_bf16(af23[mi][1], bf0[ni][1], acc[2 + mi][0][ni], 0, 0, 0);
            }
        __builtin_amdgcn_s_setprio(0);
        __builtin_amdgcn_s_barrier();

        // ---- phase 4: stage A(t+2) (A region free); MFMA (mi2-3, qn1); boundary
        if (t + 2 < NT) stageA(t & 1, t + 2);
        __builtin_amdgcn_s_setprio(1);
#pragma unroll
        for (int mi = 0; mi < 2; mi++)
#pragma unroll
            for (int ni = 0; ni < 2; ni++) {
                acc[2 + mi][1][ni] = __builtin_amdgcn_mfma_f32_16x16x32_bf16(af23[mi][0], bf1[ni][0], acc[2 + mi][1][ni], 0, 0, 0);
                acc[2 + mi][1][ni] = __builtin_amdgcn_mfma_f32_16x16x32_bf16(af23[mi][1], bf1[ni][1], acc[2 + mi][1][ni], 0, 0, 0);
            }
        __builtin_amdgcn_s_setprio(0);
        if (t + 1 < NT) {
            if (t + 1 == NT - 1) asm volatile("s_waitcnt vmcnt(0)" ::: "memory");
            else                 asm volatile("s_waitcnt vmcnt(6)" ::: "memory");
            __builtin_amdgcn_s_barrier();
        }
    }

#pragma unroll
    for (int mi = 0; mi < 4; mi++)
#pragma unroll
        for (int qn = 0; qn < 2; qn++)
#pragma unroll
            for (int ni = 0; ni < 2; ni++)
#pragma unroll
                for (int r = 0; r < 4; r++) {
                    int row = m0 + wm + mi * 16 + quad * 4 + r;
                    int col = n0 + wn + qn * 32 + ni * 16 + l15;
                    float v = acc[mi][qn][ni][r];
                    if (CF32) ((float*)Cv)[(long)row * ldc + col] = v;
                    else      ((short*)Cv)[(long)row * ldc + col] = f2bf(v);
                }
}

// RoPE in-place on qkv cols [0,2560)  (fallback path only)
__global__ __launch_bounds__(256) void rope_kernel(short* __restrict__ qkv) {
    int tid = blockIdx.x * 256 + threadIdx.x;
    int p = tid % 1280;
    int row = tid / 1280;
    int head = p >> 5;
    int j = p & 31;
    int s = row & 2047;
    int c1 = head * 64 + j;
    float freq = exp2f(-(float)j * 0.4152410118609203f); // log2(10000)/32
    float ang = (float)s * freq;
    float sn, cs;
    __sincosf(ang, &sn, &cs);
    long base = (long)row * 3072;
    float x1 = bf2f(qkv[base + c1]);
    float x2 = bf2f(qkv[base + c1 + 32]);
    qkv[base + c1]      = f2bf(x1 * cs - x2 * sn);
    qkv[base + c1 + 32] = f2bf(x2 * cs + x1 * sn);
}

// V transpose (round-0 verified): qkv v-region -> Vt_g[(b*8+kvh)*64 + d][key] (ld 2048)
__global__ __launch_bounds__(256) void vtrans(const short* __restrict__ qkv,
                                              short* __restrict__ Vt_g) {
    __shared__ __align__(16) short tile[64 * 72];
    const int kt = blockIdx.x * 64;
    const int kvh = blockIdx.y;
    const int b = blockIdx.z;
    const int t = threadIdx.x;
#pragma unroll
    for (int cc = 0; cc < 2; cc++) {
        int ch = t + cc * 256;
        int key = ch >> 3, d0 = (ch & 7) * 8;
        s8v v = *(const s8v*)&qkv[(long)(b * 2048 + kt + key) * 3072 + 2560 + kvh * 64 + d0];
#pragma unroll
        for (int i = 0; i < 8; i++) tile[(d0 + i) * 72 + key] = v[i];
    }
    __syncthreads();
#pragma unroll
    for (int cc = 0; cc < 2; cc++) {
        int ch = t + cc * 256;
        int d = ch >> 3, kc = (ch & 7) * 8;
        *(s8v*)&Vt_g[(long)((b * 8 + kvh) * 64 + d) * 2048 + kt + kc] = *(const s8v*)&tile[d * 72 + kc];
    }
}

// Flash attention v4.2 (round-6 PASS, unchanged)
__global__ __launch_bounds__(256, 3) void attn4(short* __restrict__ qkv,
                                                const short* __restrict__ Vt_g) {
    __shared__ __align__(16) short KV[2][2][4096];   // [buf][K/V][64*64]
    __shared__ __align__(16) short Ps[4][2][16 * 72];
    __shared__ float rsb[4][32];

    const int tid = threadIdx.x;
    const int lane = tid & 63;
    const int wave = tid >> 6;
    const int quad = lane >> 4;
    const int l15 = lane & 15;

    int f = (blockIdx.z * 32 + blockIdx.y) * 16 + blockIdx.x;
    f = (f & 7) * 128 + (f >> 3);
    const int b = f >> 9;
    const int h = (f >> 4) & 31;
    const int kvh = h >> 2;
    const int q0 = (f & 15) * 128;

    const long kbase = ((long)b * 2048) * 3072 + 2048 + kvh * 64;
    const long vtbase = (long)(b * 8 + kvh) * 64 * 2048;

    const long qrow = (long)b * 2048 + q0 + wave * 32 + l15;
    const short* qp = qkv + qrow * 3072 + h * 64 + quad * 8;
    const s8v qf00 = *(const s8v*)(qp);
    const s8v qf01 = *(const s8v*)(qp + 32);
    const s8v qf10 = *(const s8v*)(qp + 16 * 3072);
    const s8v qf11 = *(const s8v*)(qp + 16 * 3072 + 32);

    const int rA = wave * 8 + (lane >> 3);
    const int sslot = (lane & 7) ^ (lane >> 3);
    const short* kA = qkv + kbase + (long)rA * 3072 + sslot * 8;
    const short* kB = kA + (long)32 * 3072;
    const short* vA = Vt_g + vtbase + (long)rA * 2048 + sslot * 8;
    const short* vB = vA + (long)32 * 2048;

    {
        char* kd = (char*)&KV[0][0][0] + wave * 1024;
        char* vd = (char*)&KV[0][1][0] + wave * 1024;
        __builtin_amdgcn_global_load_lds((gp1_t)kA, (lp3_t)kd, 16, 0, 0);
        __builtin_amdgcn_global_load_lds((gp1_t)kB, (lp3_t)(kd + 4096), 16, 0, 0);
        __builtin_amdgcn_global_load_lds((gp1_t)vA, (lp3_t)vd, 16, 0, 0);
        __builtin_amdgcn_global_load_lds((gp1_t)vB, (lp3_t)(vd + 4096), 16, 0, 0);
    }
    __syncthreads();

    const int ks0 = ((quad ^ (l15 & 7)) << 3);
    const int ks1 = ks0 ^ 32;

    f2v rs0v = (f2v){0.f, 0.f}, rs1v = (f2v){0.f, 0.f};
    f4v o0[4], o1[4];
#pragma unroll
    for (int ni = 0; ni < 4; ni++) { o0[ni] = (f4v){0.f, 0.f, 0.f, 0.f}; o1[ni] = (f4v){0.f, 0.f, 0.f, 0.f}; }

    short* Pw0 = &Ps[wave][0][0];
    short* Pw1 = &Ps[wave][1][0];

    for (int t = 0; t < 32; ++t) {
        const short* Kb = &KV[t & 1][0][0];
        const short* Vb = &KV[t & 1][1][0];

        if (t < 31) {
            const long ko = (long)(t + 1) * (64 * 3072);
            const long vo = (long)(t + 1) * 64;
            char* kd = (char*)&KV[(t + 1) & 1][0][0] + wave * 1024;
            char* vd = (char*)&KV[(t + 1) & 1][1][0] + wave * 1024;
            __builtin_amdgcn_global_load_lds((gp1_t)(kA + ko), (lp3_t)kd, 16, 0, 0);
            __builtin_amdgcn_global_load_lds((gp1_t)(kB + ko), (lp3_t)(kd + 4096), 16, 0, 0);
            __builtin_amdgcn_global_load_lds((gp1_t)(vA + vo), (lp3_t)vd, 16, 0, 0);
            __builtin_amdgcn_global_load_lds((gp1_t)(vB + vo), (lp3_t)(vd + 4096), 16, 0, 0);
        }

#pragma unroll
        for (int ni = 0; ni < 4; ni++) {
            const int ro = (ni * 16 + l15) * 64;
            const s8v kf0 = *(const s8v*)&Kb[ro + ks0];
            const s8v kf1 = *(const s8v*)&Kb[ro + ks1];
            f4v a = (f4v){-24.f, -24.f, -24.f, -24.f};
            a = __builtin_amdgcn_mfma_f32_16x16x32_bf16(kf0, qf00, a, 0, 0, 0);
            a = __builtin_amdgcn_mfma_f32_16x16x32_bf16(kf1, qf01, a, 0, 0, 0);
            {
                float p0 = exp2f(a[0]);
                float p1 = exp2f(a[1]);
                float p2 = exp2f(a[2]);
                float p3 = exp2f(a[3]);
                rs0v += (f2v){p0, p1};
                rs0v += (f2v){p2, p3};
                *(i2v*)&Pw0[l15 * 72 + ni * 16 + quad * 4] =
                    (i2v){(int)cvt_pk_bf16(p0, p1), (int)cvt_pk_bf16(p2, p3)};
            }
            f4v c = (f4v){-24.f, -24.f, -24.f, -24.f};
            c = __builtin_amdgcn_mfma_f32_16x16x32_bf16(kf0, qf10, c, 0, 0, 0);
            c = __builtin_amdgcn_mfma_f32_16x16x32_bf16(kf1, qf11, c, 0, 0, 0);
            {
                float p0 = exp2f(c[0]);
                float p1 = exp2f(c[1]);
                float p2 = exp2f(c[2]);
                float p3 = exp2f(c[3]);
                rs1v += (f2v){p0, p1};
                rs1v += (f2v){p2, p3};
                *(i2v*)&Pw1[l15 * 72 + ni * 16 + quad * 4] =
                    (i2v){(int)cvt_pk_bf16(p0, p1), (int)cvt_pk_bf16(p2, p3)};
            }
        }

        const s8v pf00 = *(const s8v*)&Pw0[l15 * 72 + quad * 8];
        const s8v pf01 = *(const s8v*)&Pw0[l15 * 72 + 32 + quad * 8];
        const s8v pf10 = *(const s8v*)&Pw1[l15 * 72 + quad * 8];
        const s8v pf11 = *(const s8v*)&Pw1[l15 * 72 + 32 + quad * 8];
#pragma unroll
        for (int ni = 0; ni < 4; ni++) {
            const int ro = (ni * 16 + l15) * 64;
            const s8v vf0 = *(const s8v*)&Vb[ro + ks0];
            const s8v vf1 = *(const s8v*)&Vb[ro + ks1];
            o0[ni] = __builtin_amdgcn_mfma_f32_16x16x32_bf16(pf00, vf0, o0[ni], 0, 0, 0);
            o0[ni] = __builtin_amdgcn_mfma_f32_16x16x32_bf16(pf01, vf1, o0[ni], 0, 0, 0);
            o1[ni] = __builtin_amdgcn_mfma_f32_16x16x32_bf16(pf10, vf0, o1[ni], 0, 0, 0);
            o1[ni] = __builtin_amdgcn_mfma_f32_16x16x32_bf16(pf11, vf1, o1[ni], 0, 0, 0);
        }
        __syncthreads();
    }

    float rs0 = rs0v[0] + rs0v[1];
    float rs1 = rs1v[0] + rs1v[1];
    rs0 += __shfl_xor(rs0, 16); rs0 += __shfl_xor(rs0, 32);
    rs1 += __shfl_xor(rs1, 16); rs1 += __shfl_xor(rs1, 32);
    if (quad == 0) { rsb[wave][l15] = rs0; rsb[wave][16 + l15] = rs1; }
    __syncthreads();

#pragma unroll
    for (int r = 0; r < 4; r++) {
        const float i0 = 1.0f / rsb[wave][quad * 4 + r];
        const float i1 = 1.0f / rsb[wave][16 + quad * 4 + r];
        const long ob0 = ((long)b * 2048 + q0 + wave * 32 + quad * 4 + r) * 3072 + h * 64;
        const long ob1 = ob0 + 16 * 3072;
#pragma unroll
        for (int ni = 0; ni < 4; ni++) {
            qkv[ob0 + ni * 16 + l15] = f2bf(o0[ni][r] * i0);
            qkv[ob1 + ni * 16 + l15] = f2bf(o1[ni][r] * i1);
        }
    }
}

// ======================= FALLBACK PATH (round-6, known-PASS) =======================

template <bool AF32, bool CF32>
__global__ __launch_bounds__(256) void gemm_bn(const void* __restrict__ Av,
                                               const float* __restrict__ B,
                                               void* __restrict__ Cv,
                                               int K, int N, int lda, int ldc) {
    __shared__ __align__(16) short As[128 * 40];
    __shared__ __align__(16) short Bs[128 * 40];
    const int tid = threadIdx.x;
    const int lane = tid & 63;
    const int wave = tid >> 6;
    const int quad = lane >> 4;
    const int l15 = lane & 15;
    const int m0 = blockIdx.y * 128;
    const int n0 = blockIdx.x * 128;
    const int wm = (wave & 1) * 64;
    const int wn = (wave >> 1) * 64;

    f4v acc[4][4];
#pragma unroll
    for (int i = 0; i < 4; i++)
#pragma unroll
        for (int j = 0; j < 4; j++) acc[i][j] = (f4v){0.f, 0.f, 0.f, 0.f};

    const int ar0 = tid >> 2, akc0 = (tid & 3) * 8;
    const int ar1 = (tid + 256) >> 2, akc1 = ((tid + 256) & 3) * 8;
    const int bk0 = tid >> 4, bnc0 = (tid & 15) * 8;
    const int bk1 = (tid + 256) >> 4, bnc1 = ((tid + 256) & 15) * 8;

    for (int k0 = 0; k0 < K; k0 += 32) {
        __syncthreads();
        if (AF32) {
            const float* A = (const float*)Av;
            *(s8v*)(&As[ar0 * 40 + akc0]) = cvt8(&A[(long)(m0 + ar0) * lda + k0 + akc0]);
            *(s8v*)(&As[ar1 * 40 + akc1]) = cvt8(&A[(long)(m0 + ar1) * lda + k0 + akc1]);
        } else {
            const short* A = (const short*)Av;
            *(s8v*)(&As[ar0 * 40 + akc0]) = *(const s8v*)(&A[(long)(m0 + ar0) * lda + k0 + akc0]);
            *(s8v*)(&As[ar1 * 40 + akc1]) = *(const s8v*)(&A[(long)(m0 + ar1) * lda + k0 + akc1]);
        }
        s8v b0 = cvt8(&B[(long)(k0 + bk0) * N + n0 + bnc0]);
        s8v b1 = cvt8(&B[(long)(k0 + bk1) * N + n0 + bnc1]);
#pragma unroll
        for (int i = 0; i < 8; i++) Bs[(bnc0 + i) * 40 + bk0] = b0[i];
#pragma unroll
        for (int i = 0; i < 8; i++) Bs[(bnc1 + i) * 40 + bk1] = b1[i];
        __syncthreads();
        s8v af[4], bfr[4];
#pragma unroll
        for (int mi = 0; mi < 4; mi++)
            af[mi] = *(const s8v*)(&As[(wm + mi * 16 + l15) * 40 + quad * 8]);
#pragma unroll
        for (int ni = 0; ni < 4; ni++)
            bfr[ni] = *(const s8v*)(&Bs[(wn + ni * 16 + l15) * 40 + quad * 8]);
#pragma unroll
        for (int mi = 0; mi < 4; mi++)
#pragma unroll
            for (int ni = 0; ni < 4; ni++)
                acc[mi][ni] = __builtin_amdgcn_mfma_f32_16x16x32_bf16(af[mi], bfr[ni], acc[mi][ni], 0, 0, 0);
    }
#pragma unroll
    for (int mi = 0; mi < 4; mi++)
#pragma unroll
        for (int ni = 0; ni < 4; ni++)
#pragma unroll
            for (int r = 0; r < 4; r++) {
                int row = m0 + wm + mi * 16 + quad * 4 + r;
                int col = n0 + wn + ni * 16 + l15;
                if (CF32) ((float*)Cv)[(long)row * ldc + col] = acc[mi][ni][r];
                else      ((short*)Cv)[(long)row * ldc + col] = f2bf(acc[mi][ni][r]);
            }
}

__global__ __launch_bounds__(256) void attn_kernel(short* __restrict__ qkv) {
    __shared__ __align__(16) short Qs[64 * 72];
    __shared__ __align__(16) short Ks[64 * 72];
    __shared__ __align__(16) short Vt[64 * 72];
    __shared__ __align__(16) short Ps[4][16 * 72];

    const int tid = threadIdx.x;
    const int lane = tid & 63;
    const int wave = tid >> 6;
    const int quad = lane >> 4;
    const int l15 = lane & 15;
    const int b = blockIdx.z;
    const int h = blockIdx.y;
    const int kvh = h >> 2;
    const int q0 = blockIdx.x * 64;

    const long qbase = ((long)b * 2048 + q0) * 3072 + h * 64;
    const long kbase = ((long)b * 2048) * 3072 + 2048 + kvh * 64;
    const long vbase = kbase + 512;

#pragma unroll
    for (int cc = 0; cc < 2; cc++) {
        int ch = tid + cc * 256;
        int r = ch >> 3, d0 = (ch & 7) * 8;
        *(s8v*)(&Qs[r * 72 + d0]) = *(const s8v*)(&qkv[qbase + (long)r * 3072 + d0]);
    }
    __syncthreads();
    s8v qf[2];
    qf[0] = *(const s8v*)(&Qs[(wave * 16 + l15) * 72 + quad * 8]);
    qf[1] = *(const s8v*)(&Qs[(wave * 16 + l15) * 72 + 32 + quad * 8]);

    float m_i[4], l_i[4];
    f4v o[4];
#pragma unroll
    for (int r = 0; r < 4; r++) { m_i[r] = -1e30f; l_i[r] = 0.0f; }
#pragma unroll
    for (int ni = 0; ni < 4; ni++) o[ni] = (f4v){0.f, 0.f, 0.f, 0.f};

    for (int kt = 0; kt < 2048; kt += 64) {
        __syncthreads();
#pragma unroll
        for (int cc = 0; cc < 2; cc++) {
            int ch = tid + cc * 256;
            int r = ch >> 3, d0 = (ch & 7) * 8;
            *(s8v*)(&Ks[r * 72 + d0]) = *(const s8v*)(&qkv[kbase + (long)(kt + r) * 3072 + d0]);
            s8v v = *(const s8v*)(&qkv[vbase + (long)(kt + r) * 3072 + d0]);
            int g = d0 >> 3;
            int chn = ((r >> 3) ^ g) * 8 + (r & 7);
#pragma unroll
            for (int i = 0; i < 8; i++) Vt[(d0 + i) * 72 + chn] = v[i];
        }
        __syncthreads();

        f4v sc[4];
#pragma unroll
        for (int ni = 0; ni < 4; ni++) {
            s8v kf0 = *(const s8v*)(&Ks[(ni * 16 + l15) * 72 + quad * 8]);
            s8v kf1 = *(const s8v*)(&Ks[(ni * 16 + l15) * 72 + 32 + quad * 8]);
            f4v a = (f4v){0.f, 0.f, 0.f, 0.f};
            a = __builtin_amdgcn_mfma_f32_16x16x32_bf16(qf[0], kf0, a, 0, 0, 0);
            a = __builtin_amdgcn_mfma_f32_16x16x32_bf16(qf[1], kf1, a, 0, 0, 0);
            sc[ni] = a * 0.125f;
        }
        float alpha[4], rs[4];
#pragma unroll
        for (int r = 0; r < 4; r++) {
            float v = fmaxf(fmaxf(sc[0][r], sc[1][r]), fmaxf(sc[2][r], sc[3][r]));
            v = fmaxf(v, __shfl_xor(v, 1));
            v = fmaxf(v, __shfl_xor(v, 2));
            v = fmaxf(v, __shfl_xor(v, 4));
            v = fmaxf(v, __shfl_xor(v, 8));
            float mn = fmaxf(m_i[r], v);
            alpha[r] = __expf(m_i[r] - mn);
            m_i[r] = mn;
            rs[r] = 0.f;
        }
#pragma unroll
        for (int ni = 0; ni < 4; ni++)
#pragma unroll
            for (int r = 0; r < 4; r++) {
                float pv = __expf(sc[ni][r] - m_i[r]);
                sc[ni][r] = pv;
                rs[r] += pv;
            }
#pragma unroll
        for (int r = 0; r < 4; r++) {
            float v = rs[r];
            v += __shfl_xor(v, 1);
            v += __shfl_xor(v, 2);
            v += __shfl_xor(v, 4);
            v += __shfl_xor(v, 8);
            l_i[r] = l_i[r] * alpha[r] + v;
        }
#pragma unroll
        for (int ni = 0; ni < 4; ni++)
#pragma unroll
            for (int r = 0; r < 4; r++) {
                int row = quad * 4 + r;
                int key = ni * 16 + l15;
                int chn = ((key >> 3) ^ (row >> 3)) * 8 + (key & 7);
                Ps[wave][row * 72 + chn] = f2bf(sc[ni][r]);
            }
        __syncthreads();
#pragma unroll
        for (int ni = 0; ni < 4; ni++) {
            f4v t = o[ni];
            t[0] *= alpha[0]; t[1] *= alpha[1]; t[2] *= alpha[2]; t[3] *= alpha[3];
            o[ni] = t;
        }
        s8v pf0 = *(const s8v*)(&Ps[wave][l15 * 72 + ((quad ^ (l15 >> 3)) * 8)]);
        s8v pf1 = *(const s8v*)(&Ps[wave][l15 * 72 + (((4 + quad) ^ (l15 >> 3)) * 8)]);
#pragma unroll
        for (int ni = 0; ni < 4; ni++) {
            int d = ni * 16 + l15;
            s8v vf0 = *(const s8v*)(&Vt[d * 72 + ((quad ^ (d >> 3)) * 8)]);
            s8v vf1 = *(const s8v*)(&Vt[d * 72 + (((4 + quad) ^ (d >> 3)) * 8)]);
            o[ni] = __builtin_amdgcn_mfma_f32_16x16x32_bf16(pf0, vf0, o[ni], 0, 0, 0);
            o[ni] = __builtin_amdgcn_mfma_f32_16x16x32_bf16(pf1, vf1, o[ni], 0, 0, 0);
        }
    }
#pragma unroll
    for (int r = 0; r < 4; r++) {
        float inv = 1.0f / l_i[r];
        int srow = q0 + wave * 16 + quad * 4 + r;
        long obase = ((long)b * 2048 + srow) * 3072 + h * 64;
#pragma unroll
        for (int ni = 0; ni < 4; ni++)
            qkv[obase + ni * 16 + l15] = f2bf(o[ni][r] * inv);
    }
}

extern "C" void kernel_launch(void* const* d_in, const int* in_sizes, int n_in,
                              void* d_out, int out_size, void* d_ws, size_t ws_size,
                              hipStream_t stream) {
    (void)in_sizes; (void)n_in; (void)out_size;
    const float* x  = (const float*)d_in[0];
    const float* Wq = (const float*)d_in[1];
    const float* Wk = (const float*)d_in[2];
    const float* Wv = (const float*)d_in[3];
    const float* Wo = (const float*)d_in[4];

    const float CS = 0.18033688011112042f;   // 0.125 * log2(e), folded into Wk
    const size_t need = 67108864ULL; // 64 MiB
    if (ws_size >= need) {
        short* xb    = (short*)d_ws;              // 4096x2048
        short* Wqkvt = xb + 8388608;              // 3072x2048
        short* Wot   = Wqkvt + 6291456;           // 2048x2048
        short* qkv   = Wot + 4194304;             // 4096x3072
        short* Vt_g  = qkv + 12582912;            // 16x64x2048

        cvt_x<<<4096, 256, 0, stream>>>(x, xb);
        cvt_wt<<<dim3(32, 32), 256, 0, stream>>>(Wq, Wqkvt, 2048, 0, 1.0f);
        cvt_wt<<<dim3(8, 32), 256, 0, stream>>>(Wk, Wqkvt, 512, 2048, CS);
        cvt_wt<<<dim3(8, 32), 256, 0, stream>>>(Wv, Wqkvt, 512, 2560, 1.0f);
        cvt_wt<<<dim3(32, 32), 256, 0, stream>>>(Wo, Wot, 2048, 0, 1.0f);
        gemm_bt8<false, true><<<dim3(12, 16), 512, 0, stream>>>(xb, Wqkvt, qkv, 2048, 2048, 2048, 3072);
        vtrans<<<dim3(32, 8, 2), 256, 0, stream>>>(qkv, Vt_g);
        attn4<<<dim3(16, 32, 2), 256, 0, stream>>>(qkv, Vt_g);
        gemm_bt2<true><<<dim3(8, 32), 512, 0, stream>>>(qkv, Wot, d_out, 2048, 3072, 2048, 2048);
    } else {
        short* qkv = (short*)d_ws;
        gemm_bn<true, false><<<dim3(16, 32), 256, 0, stream>>>(x, Wq, qkv,        2048, 2048, 2048, 3072);
        gemm_bn<true, false><<<dim3(4, 32), 256, 0, stream>>>(x, Wk, qkv + 2048, 2048,  512, 2048, 3072);
        gemm_bn<true, false><<<dim3(4, 32), 256, 0, stream>>>(x, Wv, qkv + 2560, 2048,  512, 2048, 3072);
        rope_kernel<<<dim3(20480), 256, 0, stream>>>(qkv);
        attn_kernel<<<dim3(32, 32, 2), 256, 0, stream>>>(qkv);
        gemm_bn<false, true><<<dim3(16, 32), 256, 0, stream>>>(qkv, Wo, d_out, 2048, 2048, 3072, 2048);
    }
}

// Round 10
// 314.753 us; speedup vs baseline: 1.4229x; 1.0595x over previous
//
#include <hip/hip_runtime.h>

typedef short s8v __attribute__((ext_vector_type(8)));
typedef short s4v __attribute__((ext_vector_type(4)));
typedef unsigned u4v __attribute__((ext_vector_type(4)));
typedef int i2v __attribute__((ext_vector_type(2)));
typedef float f2v __attribute__((ext_vector_type(2)));
typedef float f4v __attribute__((ext_vector_type(4)));

typedef const __attribute__((address_space(1))) char* gp1_t;
typedef __attribute__((address_space(3))) char* lp3_t;

__device__ __forceinline__ float bf2f(short s) {
    union { unsigned u; float f; } c;
    c.u = ((unsigned)(unsigned short)s) << 16;
    return c.f;
}
__device__ __forceinline__ short f2bf(float f) {
    union { float f; unsigned u; } c; c.f = f;
    unsigned r = (c.u + 0x7FFFu + ((c.u >> 16) & 1u)) >> 16;
    return (short)r;
}
__device__ __forceinline__ unsigned cvt_pk_bf16(float a, float b) {
    unsigned r;
    asm("v_cvt_pk_bf16_f32 %0, %1, %2" : "=v"(r) : "v"(a), "v"(b));
    return r;
}
__device__ __forceinline__ s8v cvt8(const float* __restrict__ p) {
    f4v a = *(const f4v*)p;
    f4v b = *(const f4v*)(p + 4);
    s8v r;
    r[0] = f2bf(a[0]); r[1] = f2bf(a[1]); r[2] = f2bf(a[2]); r[3] = f2bf(a[3]);
    r[4] = f2bf(b[0]); r[5] = f2bf(b[1]); r[6] = f2bf(b[2]); r[7] = f2bf(b[3]);
    return r;
}

// ======================= FAST PATH (ws >= 64 MiB) =======================

// fp32 -> bf16 straight copy (x)
__global__ __launch_bounds__(256) void cvt_x(const float* __restrict__ x,
                                             short* __restrict__ xb) {
    long i = ((long)blockIdx.x * 256 + threadIdx.x) * 8;
    *(s8v*)&xb[i] = cvt8(&x[i]);
}

// W (2048 x N fp32) -> Wt rows [obase+n][k] bf16 (ld 2048), scaled by `scale`
__global__ __launch_bounds__(256) void cvt_wt(const float* __restrict__ W,
                                              short* __restrict__ Wt,
                                              int N, int obase, float scale) {
    __shared__ __align__(16) short tile[64 * 72];
    const int kt = blockIdx.y * 64, n0 = blockIdx.x * 64;
    const int t = threadIdx.x;
    const int r = t >> 4, c4 = (t & 15) * 4;
#pragma unroll
    for (int i = 0; i < 4; i++) {
        int kr = r + i * 16;
        f4v v = *(const f4v*)&W[(long)(kt + kr) * N + n0 + c4];
#pragma unroll
        for (int j = 0; j < 4; j++) tile[(c4 + j) * 72 + kr] = f2bf(v[j] * scale);
    }
    __syncthreads();
    const int nr = t >> 3, kc = (t & 7) * 8;
#pragma unroll
    for (int i = 0; i < 2; i++) {
        int n = nr + i * 32;
        *(s8v*)&Wt[(long)(obase + n0 + n) * 2048 + kt + kc] = *(const s8v*)&tile[n * 72 + kc];
    }
}

// ================== 256x256 4-phase GEMM (T2+T3+T4+T5) ==================
// (round-8 PASS) plus optional fused RoPE epilogue (round-9 PASS).
template <bool CF32, bool ROPE>
__global__ __launch_bounds__(512, 2) void gemm_bt8(const short* __restrict__ A,
                                                   const short* __restrict__ Bt,
                                                   void* __restrict__ Cv,
                                                   int K, int lda, int ldb, int ldc) {
    __shared__ __align__(16) short Ab[2][16384];   // [buf][256*64]
    __shared__ __align__(16) short Bb[2][16384];

    const int tid = threadIdx.x;
    const int lane = tid & 63;
    const int wave = tid >> 6;
    const int quad = lane >> 4;
    const int l15 = lane & 15;

    const int nwg = gridDim.x * gridDim.y;
    int f = blockIdx.y * gridDim.x + blockIdx.x;
    if ((nwg & 7) == 0) f = (f & 7) * (nwg >> 3) + (f >> 3);
    const int m0 = (f / gridDim.x) * 256;
    const int n0 = (f % gridDim.x) * 256;

    const int wm = (wave >> 2) * 128;
    const int wn = (wave & 3) * 64;

    const int rsub = lane >> 3;
    const int sslot = (lane & 7) ^ rsub;
    const short* aS[2][2];
    const short* bS[2][2];
#pragma unroll
    for (int h = 0; h < 2; h++)
#pragma unroll
        for (int i = 0; i < 2; i++) {
            int row = h * 128 + wave * 16 + i * 8 + rsub;
            aS[h][i] = A  + (long)(m0 + row) * lda + sslot * 8;
            bS[h][i] = Bt + (long)(n0 + row) * ldb + sslot * 8;
        }

    auto stageA = [&](int buf, int h, int kt) {
        char* d = (char*)&Ab[buf][0] + h * 16384 + wave * 2048;
        __builtin_amdgcn_global_load_lds((gp1_t)(aS[h][0] + (long)kt * 64), (lp3_t)d, 16, 0, 0);
        __builtin_amdgcn_global_load_lds((gp1_t)(aS[h][1] + (long)kt * 64), (lp3_t)(d + 1024), 16, 0, 0);
    };
    auto stageB = [&](int buf, int h, int kt) {
        char* d = (char*)&Bb[buf][0] + h * 16384 + wave * 2048;
        __builtin_amdgcn_global_load_lds((gp1_t)(bS[h][0] + (long)kt * 64), (lp3_t)d, 16, 0, 0);
        __builtin_amdgcn_global_load_lds((gp1_t)(bS[h][1] + (long)kt * 64), (lp3_t)(d + 1024), 16, 0, 0);
    };

    const int ks0 = (quad ^ (l15 & 7)) * 8;
    const int ks1 = ks0 ^ 32;

    f4v acc[2][4][2][2];   // [qm][mi][qn][ni]
#pragma unroll
    for (int a = 0; a < 2; a++)
#pragma unroll
        for (int b = 0; b < 4; b++)
#pragma unroll
            for (int c = 0; c < 2; c++)
#pragma unroll
                for (int d = 0; d < 2; d++) acc[a][b][c][d] = (f4v){0.f, 0.f, 0.f, 0.f};

    const int NT = K >> 6;

    stageB(0, 0, 0); stageB(0, 1, 0); stageA(0, 0, 0); stageA(0, 1, 0);
    stageB(1, 0, 1); stageB(1, 1, 1); stageA(1, 0, 1);
    asm volatile("s_waitcnt vmcnt(6)" ::: "memory");
    __builtin_amdgcn_s_barrier();

    for (int t = 0; t < NT; ++t) {
        const short* Ac = &Ab[t & 1][0];
        const short* Bc = &Bb[t & 1][0];
        const int nb = (t + 1) & 1;
        s8v af[4][2], bf0[2][2], bf1[2][2];

        // ---- phase 1
#pragma unroll
        for (int mi = 0; mi < 4; mi++) {
            const int row = wm + mi * 16 + l15;
            af[mi][0] = *(const s8v*)&Ac[row * 64 + ks0];
            af[mi][1] = *(const s8v*)&Ac[row * 64 + ks1];
        }
#pragma unroll
        for (int ni = 0; ni < 2; ni++) {
            const int row = wn + ni * 16 + l15;
            bf0[ni][0] = *(const s8v*)&Bc[row * 64 + ks0];
            bf0[ni][1] = *(const s8v*)&Bc[row * 64 + ks1];
        }
        if (t + 1 < NT) stageA(nb, 1, t + 1);
        __builtin_amdgcn_s_setprio(1);
#pragma unroll
        for (int mi = 0; mi < 4; mi++)
#pragma unroll
            for (int ni = 0; ni < 2; ni++) {
                acc[0][mi][0][ni] = __builtin_amdgcn_mfma_f32_16x16x32_bf16(af[mi][0], bf0[ni][0], acc[0][mi][0][ni], 0, 0, 0);
                acc[0][mi][0][ni] = __builtin_amdgcn_mfma_f32_16x16x32_bf16(af[mi][1], bf0[ni][1], acc[0][mi][0][ni], 0, 0, 0);
            }
        __builtin_amdgcn_s_setprio(0);
        __builtin_amdgcn_s_barrier();

        // ---- phase 2
#pragma unroll
        for (int ni = 0; ni < 2; ni++) {
            const int row = wn + 32 + ni * 16 + l15;
            bf1[ni][0] = *(const s8v*)&Bc[row * 64 + ks0];
            bf1[ni][1] = *(const s8v*)&Bc[row * 64 + ks1];
        }
        __builtin_amdgcn_s_setprio(1);
#pragma unroll
        for (int mi = 0; mi < 4; mi++)
#pragma unroll
            for (int ni = 0; ni < 2; ni++) {
                acc[0][mi][1][ni] = __builtin_amdgcn_mfma_f32_16x16x32_bf16(af[mi][0], bf1[ni][0], acc[0][mi][1][ni], 0, 0, 0);
                acc[0][mi][1][ni] = __builtin_amdgcn_mfma_f32_16x16x32_bf16(af[mi][1], bf1[ni][1], acc[0][mi][1][ni], 0, 0, 0);
            }
        __builtin_amdgcn_s_setprio(0);
        __builtin_amdgcn_s_barrier();

        // ---- phase 3
#pragma unroll
        for (int mi = 0; mi < 4; mi++) {
            const int row = wm + 64 + mi * 16 + l15;
            af[mi][0] = *(const s8v*)&Ac[row * 64 + ks0];
            af[mi][1] = *(const s8v*)&Ac[row * 64 + ks1];
        }
        if (t + 2 < NT) stageB(t & 1, 0, t + 2);
        __builtin_amdgcn_s_setprio(1);
#pragma unroll
        for (int mi = 0; mi < 4; mi++)
#pragma unroll
            for (int ni = 0; ni < 2; ni++) {
                acc[1][mi][0][ni] = __builtin_amdgcn_mfma_f32_16x16x32_bf16(af[mi][0], bf0[ni][0], acc[1][mi][0][ni], 0, 0, 0);
                acc[1][mi][0][ni] = __builtin_amdgcn_mfma_f32_16x16x32_bf16(af[mi][1], bf0[ni][1], acc[1][mi][0][ni], 0, 0, 0);
            }
        __builtin_amdgcn_s_setprio(0);
        __builtin_amdgcn_s_barrier();

        // ---- phase 4
        if (t + 2 < NT) { stageB(t & 1, 1, t + 2); stageA(t & 1, 0, t + 2); }
        __builtin_amdgcn_s_setprio(1);
#pragma unroll
        for (int mi = 0; mi < 4; mi++)
#pragma unroll
            for (int ni = 0; ni < 2; ni++) {
                acc[1][mi][1][ni] = __builtin_amdgcn_mfma_f32_16x16x32_bf16(af[mi][0], bf1[ni][0], acc[1][mi][1][ni], 0, 0, 0);
                acc[1][mi][1][ni] = __builtin_amdgcn_mfma_f32_16x16x32_bf16(af[mi][1], bf1[ni][1], acc[1][mi][1][ni], 0, 0, 0);
            }
        __builtin_amdgcn_s_setprio(0);
        if (t + 1 < NT) {
            if (t + 1 == NT - 1) asm volatile("s_waitcnt vmcnt(0)" ::: "memory");
            else                 asm volatile("s_waitcnt vmcnt(6)" ::: "memory");
            __builtin_amdgcn_s_barrier();
        }
    }

    // Fused RoPE (fp32, lane-local pairs), only for q/k heads (cols < 2560)
    if (ROPE && (n0 + wn) < 2560) {
        const float NLOG = -0.4152410118609203f;   // -log2(10000)/32
        const float fr0 = exp2f((float)l15 * NLOG);
        const float fr1 = exp2f((float)(16 + l15) * NLOG);
#pragma unroll
        for (int qm = 0; qm < 2; qm++)
#pragma unroll
            for (int mi = 0; mi < 4; mi++)
#pragma unroll
                for (int r = 0; r < 4; r++) {
                    const float s = (float)((m0 + wm + qm * 64 + mi * 16 + quad * 4 + r) & 2047);
#pragma unroll
                    for (int ni = 0; ni < 2; ni++) {
                        float sn, cs;
                        __sincosf(s * (ni ? fr1 : fr0), &sn, &cs);
                        float x1 = acc[qm][mi][0][ni][r];
                        float x2 = acc[qm][mi][1][ni][r];
                        acc[qm][mi][0][ni][r] = x1 * cs - x2 * sn;
                        acc[qm][mi][1][ni][r] = x2 * cs + x1 * sn;
                    }
                }
    }

#pragma unroll
    for (int qm = 0; qm < 2; qm++)
#pragma unroll
        for (int mi = 0; mi < 4; mi++)
#pragma unroll
            for (int qn = 0; qn < 2; qn++)
#pragma unroll
                for (int ni = 0; ni < 2; ni++)
#pragma unroll
                    for (int r = 0; r < 4; r++) {
                        int row = m0 + wm + qm * 64 + mi * 16 + quad * 4 + r;
                        int col = n0 + wn + qn * 32 + ni * 16 + l15;
                        float v = acc[qm][mi][qn][ni][r];
                        if (CF32) ((float*)Cv)[(long)row * ldc + col] = v;
                        else      ((short*)Cv)[(long)row * ldc + col] = f2bf(v);
                    }
}

// ================== 128x256 4-phase GEMM (full-chip variant, round-9 PASS) ==================
template <bool CF32>
__global__ __launch_bounds__(512, 2) void gemm_bt2(const short* __restrict__ A,
                                                   const short* __restrict__ Bt,
                                                   void* __restrict__ Cv,
                                                   int K, int lda, int ldb, int ldc) {
    __shared__ __align__(16) short Ab[2][8192];    // [buf][128*64]
    __shared__ __align__(16) short Bb[2][16384];   // [buf][256*64]

    const int tid = threadIdx.x;
    const int lane = tid & 63;
    const int wave = tid >> 6;
    const int quad = lane >> 4;
    const int l15 = lane & 15;

    const int nwg = gridDim.x * gridDim.y;
    int f = blockIdx.y * gridDim.x + blockIdx.x;
    if ((nwg & 7) == 0) f = (f & 7) * (nwg >> 3) + (f >> 3);
    const int m0 = (f / gridDim.x) * 128;
    const int n0 = (f % gridDim.x) * 256;

    const int wm = (wave >> 2) * 64;    // 0 or 64
    const int wn = (wave & 3) * 64;     // 0..192

    const int rsub = lane >> 3;
    const int sslot = (lane & 7) ^ rsub;
    const short* aS[2];
    const short* bS[4];
#pragma unroll
    for (int i = 0; i < 2; i++)
        aS[i] = A + (long)(m0 + wave * 16 + i * 8 + rsub) * lda + sslot * 8;
#pragma unroll
    for (int i = 0; i < 4; i++)
        bS[i] = Bt + (long)(n0 + wave * 32 + i * 8 + rsub) * ldb + sslot * 8;

    auto stageA = [&](int buf, int kt) {
        char* d = (char*)&Ab[buf][0] + wave * 2048;
        __builtin_amdgcn_global_load_lds((gp1_t)(aS[0] + (long)kt * 64), (lp3_t)d, 16, 0, 0);
        __builtin_amdgcn_global_load_lds((gp1_t)(aS[1] + (long)kt * 64), (lp3_t)(d + 1024), 16, 0, 0);
    };
    auto stageBh = [&](int buf, int h, int kt) {
        char* d = (char*)&Bb[buf][0] + wave * 4096 + h * 2048;
        __builtin_amdgcn_global_load_lds((gp1_t)(bS[2 * h] + (long)kt * 64), (lp3_t)d, 16, 0, 0);
        __builtin_amdgcn_global_load_lds((gp1_t)(bS[2 * h + 1] + (long)kt * 64), (lp3_t)(d + 1024), 16, 0, 0);
    };

    const int ks0 = (quad ^ (l15 & 7)) * 8;
    const int ks1 = ks0 ^ 32;

    f4v acc[4][2][2];   // [mi][qn][ni]
#pragma unroll
    for (int a = 0; a < 4; a++)
#pragma unroll
        for (int b = 0; b < 2; b++)
#pragma unroll
            for (int c = 0; c < 2; c++) acc[a][b][c] = (f4v){0.f, 0.f, 0.f, 0.f};

    const int NT = K >> 6;

    stageA(0, 0); stageBh(0, 0, 0); stageBh(0, 1, 0);
    stageA(1, 1); stageBh(1, 0, 1); stageBh(1, 1, 1);
    asm volatile("s_waitcnt vmcnt(6)" ::: "memory");
    __builtin_amdgcn_s_barrier();

    for (int t = 0; t < NT; ++t) {
        const short* Ac = &Ab[t & 1][0];
        const short* Bc = &Bb[t & 1][0];
        s8v af01[2][2], af23[2][2], bf0[2][2], bf1[2][2];

        // ---- phase 1
#pragma unroll
        for (int mi = 0; mi < 2; mi++) {
            const int row = wm + mi * 16 + l15;
            af01[mi][0] = *(const s8v*)&Ac[row * 64 + ks0];
            af01[mi][1] = *(const s8v*)&Ac[row * 64 + ks1];
        }
#pragma unroll
        for (int ni = 0; ni < 2; ni++) {
            const int row = wn + ni * 16 + l15;
            bf0[ni][0] = *(const s8v*)&Bc[row * 64 + ks0];
            bf0[ni][1] = *(const s8v*)&Bc[row * 64 + ks1];
        }
        __builtin_amdgcn_s_setprio(1);
#pragma unroll
        for (int mi = 0; mi < 2; mi++)
#pragma unroll
            for (int ni = 0; ni < 2; ni++) {
                acc[mi][0][ni] = __builtin_amdgcn_mfma_f32_16x16x32_bf16(af01[mi][0], bf0[ni][0], acc[mi][0][ni], 0, 0, 0);
                acc[mi][0][ni] = __builtin_amdgcn_mfma_f32_16x16x32_bf16(af01[mi][1], bf0[ni][1], acc[mi][0][ni], 0, 0, 0);
            }
        __builtin_amdgcn_s_setprio(0);
        __builtin_amdgcn_s_barrier();

        // ---- phase 2
#pragma unroll
        for (int ni = 0; ni < 2; ni++) {
            const int row = wn + 32 + ni * 16 + l15;
            bf1[ni][0] = *(const s8v*)&Bc[row * 64 + ks0];
            bf1[ni][1] = *(const s8v*)&Bc[row * 64 + ks1];
        }
        if (t + 2 < NT) stageBh(t & 1, 0, t + 2);
        __builtin_amdgcn_s_setprio(1);
#pragma unroll
        for (int mi = 0; mi < 2; mi++)
#pragma unroll
            for (int ni = 0; ni < 2; ni++) {
                acc[mi][1][ni] = __builtin_amdgcn_mfma_f32_16x16x32_bf16(af01[mi][0], bf1[ni][0], acc[mi][1][ni], 0, 0, 0);
                acc[mi][1][ni] = __builtin_amdgcn_mfma_f32_16x16x32_bf16(af01[mi][1], bf1[ni][1], acc[mi][1][ni], 0, 0, 0);
            }
        __builtin_amdgcn_s_setprio(0);
        __builtin_amdgcn_s_barrier();

        // ---- phase 3
#pragma unroll
        for (int mi = 0; mi < 2; mi++) {
            const int row = wm + 32 + mi * 16 + l15;
            af23[mi][0] = *(const s8v*)&Ac[row * 64 + ks0];
            af23[mi][1] = *(const s8v*)&Ac[row * 64 + ks1];
        }
        if (t + 2 < NT) stageBh(t & 1, 1, t + 2);
        __builtin_amdgcn_s_setprio(1);
#pragma unroll
        for (int mi = 0; mi < 2; mi++)
#pragma unroll
            for (int ni = 0; ni < 2; ni++) {
                acc[2 + mi][0][ni] = __builtin_amdgcn_mfma_f32_16x16x32_bf16(af23[mi][0], bf0[ni][0], acc[2 + mi][0][ni], 0, 0, 0);
                acc[2 + mi][0][ni] = __builtin_amdgcn_mfma_f32_16x16x32_bf16(af23[mi][1], bf0[ni][1], acc[2 + mi][0][ni], 0, 0, 0);
            }
        __builtin_amdgcn_s_setprio(0);
        __builtin_amdgcn_s_barrier();

        // ---- phase 4
        if (t + 2 < NT) stageA(t & 1, t + 2);
        __builtin_amdgcn_s_setprio(1);
#pragma unroll
        for (int mi = 0; mi < 2; mi++)
#pragma unroll
            for (int ni = 0; ni < 2; ni++) {
                acc[2 + mi][1][ni] = __builtin_amdgcn_mfma_f32_16x16x32_bf16(af23[mi][0], bf1[ni][0], acc[2 + mi][1][ni], 0, 0, 0);
                acc[2 + mi][1][ni] = __builtin_amdgcn_mfma_f32_16x16x32_bf16(af23[mi][1], bf1[ni][1], acc[2 + mi][1][ni], 0, 0, 0);
            }
        __builtin_amdgcn_s_setprio(0);
        if (t + 1 < NT) {
            if (t + 1 == NT - 1) asm volatile("s_waitcnt vmcnt(0)" ::: "memory");
            else                 asm volatile("s_waitcnt vmcnt(6)" ::: "memory");
            __builtin_amdgcn_s_barrier();
        }
    }

#pragma unroll
    for (int mi = 0; mi < 4; mi++)
#pragma unroll
        for (int qn = 0; qn < 2; qn++)
#pragma unroll
            for (int ni = 0; ni < 2; ni++)
#pragma unroll
                for (int r = 0; r < 4; r++) {
                    int row = m0 + wm + mi * 16 + quad * 4 + r;
                    int col = n0 + wn + qn * 32 + ni * 16 + l15;
                    float v = acc[mi][qn][ni][r];
                    if (CF32) ((float*)Cv)[(long)row * ldc + col] = v;
                    else      ((short*)Cv)[(long)row * ldc + col] = f2bf(v);
                }
}

// RoPE in-place on qkv cols [0,2560)  (fallback path only)
__global__ __launch_bounds__(256) void rope_kernel(short* __restrict__ qkv) {
    int tid = blockIdx.x * 256 + threadIdx.x;
    int p = tid % 1280;
    int row = tid / 1280;
    int head = p >> 5;
    int j = p & 31;
    int s = row & 2047;
    int c1 = head * 64 + j;
    float freq = exp2f(-(float)j * 0.4152410118609203f); // log2(10000)/32
    float ang = (float)s * freq;
    float sn, cs;
    __sincosf(ang, &sn, &cs);
    long base = (long)row * 3072;
    float x1 = bf2f(qkv[base + c1]);
    float x2 = bf2f(qkv[base + c1 + 32]);
    qkv[base + c1]      = f2bf(x1 * cs - x2 * sn);
    qkv[base + c1 + 32] = f2bf(x2 * cs + x1 * sn);
}

// V transpose with key-permutation pi applied per 64-key tile:
// Vt_g[(b*8+kvh)*64 + d][kt + s] = V[kt + pi(s)][d], s = 8c+j:
//   pi(s) = 32*(c>>2) + 16*(j>>2) + 4*(c&3) + (j&3)
// Makes the attn PV A-fragment in-lane after swapped QK^T.
__global__ __launch_bounds__(256) void vtrans(const short* __restrict__ qkv,
                                              short* __restrict__ Vt_g) {
    __shared__ __align__(16) short tile[64 * 72];
    const int kt = blockIdx.x * 64;
    const int kvh = blockIdx.y;
    const int b = blockIdx.z;
    const int t = threadIdx.x;
#pragma unroll
    for (int cc = 0; cc < 2; cc++) {
        int ch = t + cc * 256;
        int key = ch >> 3, d0 = (ch & 7) * 8;
        s8v v = *(const s8v*)&qkv[(long)(b * 2048 + kt + key) * 3072 + 2560 + kvh * 64 + d0];
#pragma unroll
        for (int i = 0; i < 8; i++) tile[(d0 + i) * 72 + key] = v[i];
    }
    __syncthreads();
#pragma unroll
    for (int cc = 0; cc < 2; cc++) {
        int ch = t + cc * 256;
        int d = ch >> 3, c = ch & 7;
        int base1 = 32 * (c >> 2) + 4 * (c & 3);
        s4v lo = *(const s4v*)&tile[d * 72 + base1];
        s4v hi = *(const s4v*)&tile[d * 72 + base1 + 16];
        s8v w;
        w[0] = lo[0]; w[1] = lo[1]; w[2] = lo[2]; w[3] = lo[3];
        w[4] = hi[0]; w[5] = hi[1]; w[6] = hi[2]; w[7] = hi[3];
        *(s8v*)&Vt_g[(long)((b * 8 + kvh) * 64 + d) * 2048 + kt + c * 8] = w;
    }
}

// Flash attention v5: round-9 attn4 base (PASS) with the P LDS round-trip
// replaced by in-lane register A-fragments (pi_v-permuted V). No Ps buffer:
// LDS 33.3 KB -> 4 blocks/CU. Everything else identical to round 9.
__global__ __launch_bounds__(256, 4) void attn5(short* __restrict__ qkv,
                                                const short* __restrict__ Vt_g) {
    __shared__ __align__(16) short KV[2][2][4096];   // [buf][K/V][64*64]
    __shared__ float rsb[4][32];

    const int tid = threadIdx.x;
    const int lane = tid & 63;
    const int wave = tid >> 6;
    const int quad = lane >> 4;
    const int l15 = lane & 15;

    int f = (blockIdx.z * 32 + blockIdx.y) * 16 + blockIdx.x;
    f = (f & 7) * 128 + (f >> 3);
    const int b = f >> 9;
    const int h = (f >> 4) & 31;
    const int kvh = h >> 2;
    const int q0 = (f & 15) * 128;

    const long kbase = ((long)b * 2048) * 3072 + 2048 + kvh * 64;
    const long vtbase = (long)(b * 8 + kvh) * 64 * 2048;

    const long qrow = (long)b * 2048 + q0 + wave * 32 + l15;
    const short* qp = qkv + qrow * 3072 + h * 64 + quad * 8;
    const s8v qf00 = *(const s8v*)(qp);
    const s8v qf01 = *(const s8v*)(qp + 32);
    const s8v qf10 = *(const s8v*)(qp + 16 * 3072);
    const s8v qf11 = *(const s8v*)(qp + 16 * 3072 + 32);

    const int rA = wave * 8 + (lane >> 3);
    const int sslot = (lane & 7) ^ (lane >> 3);
    const short* kA = qkv + kbase + (long)rA * 3072 + sslot * 8;
    const short* kB = kA + (long)32 * 3072;
    const short* vA = Vt_g + vtbase + (long)rA * 2048 + sslot * 8;
    const short* vB = vA + (long)32 * 2048;

    {
        char* kd = (char*)&KV[0][0][0] + wave * 1024;
        char* vd = (char*)&KV[0][1][0] + wave * 1024;
        __builtin_amdgcn_global_load_lds((gp1_t)kA, (lp3_t)kd, 16, 0, 0);
        __builtin_amdgcn_global_load_lds((gp1_t)kB, (lp3_t)(kd + 4096), 16, 0, 0);
        __builtin_amdgcn_global_load_lds((gp1_t)vA, (lp3_t)vd, 16, 0, 0);
        __builtin_amdgcn_global_load_lds((gp1_t)vB, (lp3_t)(vd + 4096), 16, 0, 0);
    }
    __syncthreads();

    const int ks0 = ((quad ^ (l15 & 7)) << 3);
    const int ks1 = ks0 ^ 32;

    f2v rs0v = (f2v){0.f, 0.f}, rs1v = (f2v){0.f, 0.f};
    f4v o0[4], o1[4];
#pragma unroll
    for (int ni = 0; ni < 4; ni++) { o0[ni] = (f4v){0.f, 0.f, 0.f, 0.f}; o1[ni] = (f4v){0.f, 0.f, 0.f, 0.f}; }

    for (int t = 0; t < 32; ++t) {
        const short* Kb = &KV[t & 1][0][0];
        const short* Vb = &KV[t & 1][1][0];

        if (t < 31) {
            const long ko = (long)(t + 1) * (64 * 3072);
            const long vo = (long)(t + 1) * 64;
            char* kd = (char*)&KV[(t + 1) & 1][0][0] + wave * 1024;
            char* vd = (char*)&KV[(t + 1) & 1][1][0] + wave * 1024;
            __builtin_amdgcn_global_load_lds((gp1_t)(kA + ko), (lp3_t)kd, 16, 0, 0);
            __builtin_amdgcn_global_load_lds((gp1_t)(kB + ko), (lp3_t)(kd + 4096), 16, 0, 0);
            __builtin_amdgcn_global_load_lds((gp1_t)(vA + vo), (lp3_t)vd, 16, 0, 0);
            __builtin_amdgcn_global_load_lds((gp1_t)(vB + vo), (lp3_t)(vd + 4096), 16, 0, 0);
        }

        // QK^T swapped: lane (quad,l15) reg r holds score-24 for
        // key = ni*16+quad*4+r, q = l15
        unsigned pk0[4][2], pk1[4][2];
#pragma unroll
        for (int ni = 0; ni < 4; ni++) {
            const int ro = (ni * 16 + l15) * 64;
            const s8v kf0 = *(const s8v*)&Kb[ro + ks0];
            const s8v kf1 = *(const s8v*)&Kb[ro + ks1];
            f4v a = (f4v){-24.f, -24.f, -24.f, -24.f};
            a = __builtin_amdgcn_mfma_f32_16x16x32_bf16(kf0, qf00, a, 0, 0, 0);
            a = __builtin_amdgcn_mfma_f32_16x16x32_bf16(kf1, qf01, a, 0, 0, 0);
            {
                float p0 = exp2f(a[0]);
                float p1 = exp2f(a[1]);
                float p2 = exp2f(a[2]);
                float p3 = exp2f(a[3]);
                rs0v += (f2v){p0, p1};
                rs0v += (f2v){p2, p3};
                pk0[ni][0] = cvt_pk_bf16(p0, p1);
                pk0[ni][1] = cvt_pk_bf16(p2, p3);
            }
            f4v c = (f4v){-24.f, -24.f, -24.f, -24.f};
            c = __builtin_amdgcn_mfma_f32_16x16x32_bf16(kf0, qf10, c, 0, 0, 0);
            c = __builtin_amdgcn_mfma_f32_16x16x32_bf16(kf1, qf11, c, 0, 0, 0);
            {
                float p0 = exp2f(c[0]);
                float p1 = exp2f(c[1]);
                float p2 = exp2f(c[2]);
                float p3 = exp2f(c[3]);
                rs1v += (f2v){p0, p1};
                rs1v += (f2v){p2, p3};
                pk1[ni][0] = cvt_pk_bf16(p0, p1);
                pk1[ni][1] = cvt_pk_bf16(p2, p3);
            }
        }

        // In-lane PV A-fragments (pi_v-permuted V):
        // pa0 elem j = P[key (j>>2)*16 + quad*4 + (j&3)]  (ni 0,1)
        // pa1 elem j = P[key 32 + ...]                    (ni 2,3)
        union PU { u4v u; s8v s; };
        PU pa0, pa1, pb0, pb1;
        pa0.u = (u4v){pk0[0][0], pk0[0][1], pk0[1][0], pk0[1][1]};
        pa1.u = (u4v){pk0[2][0], pk0[2][1], pk0[3][0], pk0[3][1]};
        pb0.u = (u4v){pk1[0][0], pk1[0][1], pk1[1][0], pk1[1][1]};
        pb1.u = (u4v){pk1[2][0], pk1[2][1], pk1[3][0], pk1[3][1]};

#pragma unroll
        for (int ni = 0; ni < 4; ni++) {
            const int ro = (ni * 16 + l15) * 64;
            const s8v vf0 = *(const s8v*)&Vb[ro + ks0];
            const s8v vf1 = *(const s8v*)&Vb[ro + ks1];
            o0[ni] = __builtin_amdgcn_mfma_f32_16x16x32_bf16(pa0.s, vf0, o0[ni], 0, 0, 0);
            o0[ni] = __builtin_amdgcn_mfma_f32_16x16x32_bf16(pa1.s, vf1, o0[ni], 0, 0, 0);
            o1[ni] = __builtin_amdgcn_mfma_f32_16x16x32_bf16(pb0.s, vf0, o1[ni], 0, 0, 0);
            o1[ni] = __builtin_amdgcn_mfma_f32_16x16x32_bf16(pb1.s, vf1, o1[ni], 0, 0, 0);
        }
        __syncthreads();
    }

    float rs0 = rs0v[0] + rs0v[1];
    float rs1 = rs1v[0] + rs1v[1];
    rs0 += __shfl_xor(rs0, 16); rs0 += __shfl_xor(rs0, 32);
    rs1 += __shfl_xor(rs1, 16); rs1 += __shfl_xor(rs1, 32);
    if (quad == 0) { rsb[wave][l15] = rs0; rsb[wave][16 + l15] = rs1; }
    __syncthreads();

#pragma unroll
    for (int r = 0; r < 4; r++) {
        const float i0 = 1.0f / rsb[wave][quad * 4 + r];
        const float i1 = 1.0f / rsb[wave][16 + quad * 4 + r];
        const long ob0 = ((long)b * 2048 + q0 + wave * 32 + quad * 4 + r) * 3072 + h * 64;
        const long ob1 = ob0 + 16 * 3072;
#pragma unroll
        for (int ni = 0; ni < 4; ni++) {
            qkv[ob0 + ni * 16 + l15] = f2bf(o0[ni][r] * i0);
            qkv[ob1 + ni * 16 + l15] = f2bf(o1[ni][r] * i1);
        }
    }
}

// ======================= FALLBACK PATH (round-6, known-PASS) =======================

template <bool AF32, bool CF32>
__global__ __launch_bounds__(256) void gemm_bn(const void* __restrict__ Av,
                                               const float* __restrict__ B,
                                               void* __restrict__ Cv,
                                               int K, int N, int lda, int ldc) {
    __shared__ __align__(16) short As[128 * 40];
    __shared__ __align__(16) short Bs[128 * 40];
    const int tid = threadIdx.x;
    const int lane = tid & 63;
    const int wave = tid >> 6;
    const int quad = lane >> 4;
    const int l15 = lane & 15;
    const int m0 = blockIdx.y * 128;
    const int n0 = blockIdx.x * 128;
    const int wm = (wave & 1) * 64;
    const int wn = (wave >> 1) * 64;

    f4v acc[4][4];
#pragma unroll
    for (int i = 0; i < 4; i++)
#pragma unroll
        for (int j = 0; j < 4; j++) acc[i][j] = (f4v){0.f, 0.f, 0.f, 0.f};

    const int ar0 = tid >> 2, akc0 = (tid & 3) * 8;
    const int ar1 = (tid + 256) >> 2, akc1 = ((tid + 256) & 3) * 8;
    const int bk0 = tid >> 4, bnc0 = (tid & 15) * 8;
    const int bk1 = (tid + 256) >> 4, bnc1 = ((tid + 256) & 15) * 8;

    for (int k0 = 0; k0 < K; k0 += 32) {
        __syncthreads();
        if (AF32) {
            const float* A = (const float*)Av;
            *(s8v*)(&As[ar0 * 40 + akc0]) = cvt8(&A[(long)(m0 + ar0) * lda + k0 + akc0]);
            *(s8v*)(&As[ar1 * 40 + akc1]) = cvt8(&A[(long)(m0 + ar1) * lda + k0 + akc1]);
        } else {
            const short* A = (const short*)Av;
            *(s8v*)(&As[ar0 * 40 + akc0]) = *(const s8v*)(&A[(long)(m0 + ar0) * lda + k0 + akc0]);
            *(s8v*)(&As[ar1 * 40 + akc1]) = *(const s8v*)(&A[(long)(m0 + ar1) * lda + k0 + akc1]);
        }
        s8v b0 = cvt8(&B[(long)(k0 + bk0) * N + n0 + bnc0]);
        s8v b1 = cvt8(&B[(long)(k0 + bk1) * N + n0 + bnc1]);
#pragma unroll
        for (int i = 0; i < 8; i++) Bs[(bnc0 + i) * 40 + bk0] = b0[i];
#pragma unroll
        for (int i = 0; i < 8; i++) Bs[(bnc1 + i) * 40 + bk1] = b1[i];
        __syncthreads();
        s8v af[4], bfr[4];
#pragma unroll
        for (int mi = 0; mi < 4; mi++)
            af[mi] = *(const s8v*)(&As[(wm + mi * 16 + l15) * 40 + quad * 8]);
#pragma unroll
        for (int ni = 0; ni < 4; ni++)
            bfr[ni] = *(const s8v*)(&Bs[(wn + ni * 16 + l15) * 40 + quad * 8]);
#pragma unroll
        for (int mi = 0; mi < 4; mi++)
#pragma unroll
            for (int ni = 0; ni < 4; ni++)
                acc[mi][ni] = __builtin_amdgcn_mfma_f32_16x16x32_bf16(af[mi], bfr[ni], acc[mi][ni], 0, 0, 0);
    }
#pragma unroll
    for (int mi = 0; mi < 4; mi++)
#pragma unroll
        for (int ni = 0; ni < 4; ni++)
#pragma unroll
            for (int r = 0; r < 4; r++) {
                int row = m0 + wm + mi * 16 + quad * 4 + r;
                int col = n0 + wn + ni * 16 + l15;
                if (CF32) ((float*)Cv)[(long)row * ldc + col] = acc[mi][ni][r];
                else      ((short*)Cv)[(long)row * ldc + col] = f2bf(acc[mi][ni][r]);
            }
}

__global__ __launch_bounds__(256) void attn_kernel(short* __restrict__ qkv) {
    __shared__ __align__(16) short Qs[64 * 72];
    __shared__ __align__(16) short Ks[64 * 72];
    __shared__ __align__(16) short Vt[64 * 72];
    __shared__ __align__(16) short Ps[4][16 * 72];

    const int tid = threadIdx.x;
    const int lane = tid & 63;
    const int wave = tid >> 6;
    const int quad = lane >> 4;
    const int l15 = lane & 15;
    const int b = blockIdx.z;
    const int h = blockIdx.y;
    const int kvh = h >> 2;
    const int q0 = blockIdx.x * 64;

    const long qbase = ((long)b * 2048 + q0) * 3072 + h * 64;
    const long kbase = ((long)b * 2048) * 3072 + 2048 + kvh * 64;
    const long vbase = kbase + 512;

#pragma unroll
    for (int cc = 0; cc < 2; cc++) {
        int ch = tid + cc * 256;
        int r = ch >> 3, d0 = (ch & 7) * 8;
        *(s8v*)(&Qs[r * 72 + d0]) = *(const s8v*)(&qkv[qbase + (long)r * 3072 + d0]);
    }
    __syncthreads();
    s8v qf[2];
    qf[0] = *(const s8v*)(&Qs[(wave * 16 + l15) * 72 + quad * 8]);
    qf[1] = *(const s8v*)(&Qs[(wave * 16 + l15) * 72 + 32 + quad * 8]);

    float m_i[4], l_i[4];
    f4v o[4];
#pragma unroll
    for (int r = 0; r < 4; r++) { m_i[r] = -1e30f; l_i[r] = 0.0f; }
#pragma unroll
    for (int ni = 0; ni < 4; ni++) o[ni] = (f4v){0.f, 0.f, 0.f, 0.f};

    for (int kt = 0; kt < 2048; kt += 64) {
        __syncthreads();
#pragma unroll
        for (int cc = 0; cc < 2; cc++) {
            int ch = tid + cc * 256;
            int r = ch >> 3, d0 = (ch & 7) * 8;
            *(s8v*)(&Ks[r * 72 + d0]) = *(const s8v*)(&qkv[kbase + (long)(kt + r) * 3072 + d0]);
            s8v v = *(const s8v*)(&qkv[vbase + (long)(kt + r) * 3072 + d0]);
            int g = d0 >> 3;
            int chn = ((r >> 3) ^ g) * 8 + (r & 7);
#pragma unroll
            for (int i = 0; i < 8; i++) Vt[(d0 + i) * 72 + chn] = v[i];
        }
        __syncthreads();

        f4v sc[4];
#pragma unroll
        for (int ni = 0; ni < 4; ni++) {
            s8v kf0 = *(const s8v*)(&Ks[(ni * 16 + l15) * 72 + quad * 8]);
            s8v kf1 = *(const s8v*)(&Ks[(ni * 16 + l15) * 72 + 32 + quad * 8]);
            f4v a = (f4v){0.f, 0.f, 0.f, 0.f};
            a = __builtin_amdgcn_mfma_f32_16x16x32_bf16(qf[0], kf0, a, 0, 0, 0);
            a = __builtin_amdgcn_mfma_f32_16x16x32_bf16(qf[1], kf1, a, 0, 0, 0);
            sc[ni] = a * 0.125f;
        }
        float alpha[4], rs[4];
#pragma unroll
        for (int r = 0; r < 4; r++) {
            float v = fmaxf(fmaxf(sc[0][r], sc[1][r]), fmaxf(sc[2][r], sc[3][r]));
            v = fmaxf(v, __shfl_xor(v, 1));
            v = fmaxf(v, __shfl_xor(v, 2));
            v = fmaxf(v, __shfl_xor(v, 4));
            v = fmaxf(v, __shfl_xor(v, 8));
            float mn = fmaxf(m_i[r], v);
            alpha[r] = __expf(m_i[r] - mn);
            m_i[r] = mn;
            rs[r] = 0.f;
        }
#pragma unroll
        for (int ni = 0; ni < 4; ni++)
#pragma unroll
            for (int r = 0; r < 4; r++) {
                float pv = __expf(sc[ni][r] - m_i[r]);
                sc[ni][r] = pv;
                rs[r] += pv;
            }
#pragma unroll
        for (int r = 0; r < 4; r++) {
            float v = rs[r];
            v += __shfl_xor(v, 1);
            v += __shfl_xor(v, 2);
            v += __shfl_xor(v, 4);
            v += __shfl_xor(v, 8);
            l_i[r] = l_i[r] * alpha[r] + v;
        }
#pragma unroll
        for (int ni = 0; ni < 4; ni++)
#pragma unroll
            for (int r = 0; r < 4; r++) {
                int row = quad * 4 + r;
                int key = ni * 16 + l15;
                int chn = ((key >> 3) ^ (row >> 3)) * 8 + (key & 7);
                Ps[wave][row * 72 + chn] = f2bf(sc[ni][r]);
            }
        __syncthreads();
#pragma unroll
        for (int ni = 0; ni < 4; ni++) {
            f4v t = o[ni];
            t[0] *= alpha[0]; t[1] *= alpha[1]; t[2] *= alpha[2]; t[3] *= alpha[3];
            o[ni] = t;
        }
        s8v pf0 = *(const s8v*)(&Ps[wave][l15 * 72 + ((quad ^ (l15 >> 3)) * 8)]);
        s8v pf1 = *(const s8v*)(&Ps[wave][l15 * 72 + (((4 + quad) ^ (l15 >> 3)) * 8)]);
#pragma unroll
        for (int ni = 0; ni < 4; ni++) {
            int d = ni * 16 + l15;
            s8v vf0 = *(const s8v*)(&Vt[d * 72 + ((quad ^ (d >> 3)) * 8)]);
            s8v vf1 = *(const s8v*)(&Vt[d * 72 + (((4 + quad) ^ (d >> 3)) * 8)]);
            o[ni] = __builtin_amdgcn_mfma_f32_16x16x32_bf16(pf0, vf0, o[ni], 0, 0, 0);
            o[ni] = __builtin_amdgcn_mfma_f32_16x16x32_bf16(pf1, vf1, o[ni], 0, 0, 0);
        }
    }
#pragma unroll
    for (int r = 0; r < 4; r++) {
        float inv = 1.0f / l_i[r];
        int srow = q0 + wave * 16 + quad * 4 + r;
        long obase = ((long)b * 2048 + srow) * 3072 + h * 64;
#pragma unroll
        for (int ni = 0; ni < 4; ni++)
            qkv[obase + ni * 16 + l15] = f2bf(o[ni][r] * inv);
    }
}

extern "C" void kernel_launch(void* const* d_in, const int* in_sizes, int n_in,
                              void* d_out, int out_size, void* d_ws, size_t ws_size,
                              hipStream_t stream) {
    (void)in_sizes; (void)n_in; (void)out_size;
    const float* x  = (const float*)d_in[0];
    const float* Wq = (const float*)d_in[1];
    const float* Wk = (const float*)d_in[2];
    const float* Wv = (const float*)d_in[3];
    const float* Wo = (const float*)d_in[4];

    const float CS = 0.18033688011112042f;   // 0.125 * log2(e), folded into Wk
    const size_t need = 67108864ULL; // 64 MiB
    if (ws_size >= need) {
        short* xb    = (short*)d_ws;              // 4096x2048
        short* Wqkvt = xb + 8388608;              // 3072x2048
        short* Wot   = Wqkvt + 6291456;           // 2048x2048
        short* qkv   = Wot + 4194304;             // 4096x3072
        short* Vt_g  = qkv + 12582912;            // 16x64x2048

        cvt_x<<<4096, 256, 0, stream>>>(x, xb);
        cvt_wt<<<dim3(32, 32), 256, 0, stream>>>(Wq, Wqkvt, 2048, 0, 1.0f);
        cvt_wt<<<dim3(8, 32), 256, 0, stream>>>(Wk, Wqkvt, 512, 2048, CS);
        cvt_wt<<<dim3(8, 32), 256, 0, stream>>>(Wv, Wqkvt, 512, 2560, 1.0f);
        cvt_wt<<<dim3(32, 32), 256, 0, stream>>>(Wo, Wot, 2048, 0, 1.0f);
        gemm_bt8<false, true><<<dim3(12, 16), 512, 0, stream>>>(xb, Wqkvt, qkv, 2048, 2048, 2048, 3072);
        vtrans<<<dim3(32, 8, 2), 256, 0, stream>>>(qkv, Vt_g);
        attn5<<<dim3(16, 32, 2), 256, 0, stream>>>(qkv, Vt_g);
        gemm_bt2<true><<<dim3(8, 32), 512, 0, stream>>>(qkv, Wot, d_out, 2048, 3072, 2048, 2048);
    } else {
        short* qkv = (short*)d_ws;
        gemm_bn<true, false><<<dim3(16, 32), 256, 0, stream>>>(x, Wq, qkv,        2048, 2048, 2048, 3072);
        gemm_bn<true, false><<<dim3(4, 32), 256, 0, stream>>>(x, Wk, qkv + 2048, 2048,  512, 2048, 3072);
        gemm_bn<true, false><<<dim3(4, 32), 256, 0, stream>>>(x, Wv, qkv + 2560, 2048,  512, 2048, 3072);
        rope_kernel<<<dim3(20480), 256, 0, stream>>>(qkv);
        attn_kernel<<<dim3(32, 32, 2), 256, 0, stream>>>(qkv);
        gemm_bn<false, true><<<dim3(16, 32), 256, 0, stream>>>(qkv, Wo, d_out, 2048, 2048, 3072, 2048);
    }
}